// Round 2
// baseline (1996.851 us; speedup 1.0000x reference)
//
#include <hip/hip_runtime.h>
#include <hip/hip_bf16.h>

#define NEG_SLOPE 0.2f
#define BN_EPS 1e-5f

// ---- monotone float<->uint encoding for atomicMax on floats ----
__device__ __forceinline__ unsigned int enc_f(float x) {
    unsigned int u = __float_as_uint(x);
    return (u & 0x80000000u) ? ~u : (u | 0x80000000u);
}
__device__ __forceinline__ float dec_f(unsigned int u) {
    unsigned int b = (u & 0x80000000u) ? (u ^ 0x80000000u) : ~u;
    return __uint_as_float(b);
}

__device__ __forceinline__ float ld_as_f(const float* p) { return *p; }
__device__ __forceinline__ float ld_as_f(const __hip_bfloat16* p) { return __bfloat162float(*p); }
__device__ __forceinline__ void st_from_f(float* p, float v) { *p = v; }
__device__ __forceinline__ void st_from_f(__hip_bfloat16* p, float v) { *p = __float2bfloat16(v); }

// ---------------- GEMM: C[M,N] = act(affine(A) @ B^T + bias) ----------------
// A: [M,K] row-major (TA), B: [N,K] row-major fp32, C: [M,N] (TC).
// a_scale/a_shift (optional, [K]): per-k-column affine transform of A (fused BN).
template <typename TA, typename TC>
__global__ __launch_bounds__(256)
void gemm_tn(const TA* __restrict__ A, const float* __restrict__ B,
             TC* __restrict__ C, int M, int N, int K,
             const float* __restrict__ a_scale, const float* __restrict__ a_shift,
             const float* __restrict__ bias, int relu)
{
    __shared__ float As[16][68];
    __shared__ float Bs[16][68];
    const int bm = blockIdx.x * 64;
    const int bn = blockIdx.y * 64;
    const int tid = threadIdx.x;
    const int tx = tid & 15, ty = tid >> 4;
    const int lk = tid & 15, lr0 = tid >> 4;
    float acc[4][4] = {};
    for (int k0 = 0; k0 < K; k0 += 16) {
        #pragma unroll
        for (int i = 0; i < 4; ++i) {
            int r = lr0 + i * 16;
            int gm = bm + r;
            float v = (gm < M) ? ld_as_f(&A[(size_t)gm * K + k0 + lk]) : 0.f;
            if (a_scale) v = fmaf(v, a_scale[k0 + lk], a_shift[k0 + lk]);
            As[lk][r] = v;
        }
        #pragma unroll
        for (int i = 0; i < 4; ++i) {
            int r = lr0 + i * 16;
            int gn = bn + r;
            Bs[lk][r] = (gn < N) ? B[(size_t)gn * K + k0 + lk] : 0.f;
        }
        __syncthreads();
        #pragma unroll
        for (int k = 0; k < 16; ++k) {
            float4 a4 = *(const float4*)&As[k][ty * 4];
            float4 b4 = *(const float4*)&Bs[k][tx * 4];
            float a[4] = {a4.x, a4.y, a4.z, a4.w};
            float b[4] = {b4.x, b4.y, b4.z, b4.w};
            #pragma unroll
            for (int i = 0; i < 4; ++i)
                #pragma unroll
                for (int j = 0; j < 4; ++j)
                    acc[i][j] = fmaf(a[i], b[j], acc[i][j]);
        }
        __syncthreads();
    }
    #pragma unroll
    for (int i = 0; i < 4; ++i) {
        int gm = bm + ty * 4 + i;
        if (gm >= M) continue;
        #pragma unroll
        for (int j = 0; j < 4; ++j) {
            int gn = bn + tx * 4 + j;
            if (gn >= N) continue;
            float v = acc[i][j];
            if (bias) v += bias[gn];
            if (relu) v = fmaxf(v, 0.f);
            st_from_f(&C[(size_t)gm * N + gn], v);
        }
    }
}

// ---------------- attention logits el/er: [N,8] each ----------------
__global__ __launch_bounds__(256)
void el_er_kernel(const float* __restrict__ feat,
                  const float* __restrict__ attn_l, const float* __restrict__ attn_r,
                  float* __restrict__ el, float* __restrict__ er, int NH)
{
    int idx = blockIdx.x * 256 + threadIdx.x; // n*8 + h
    if (idx >= NH) return;
    int h = idx & 7;
    const float4* f  = (const float4*)(feat + (size_t)idx * 64);
    const float4* al = (const float4*)(attn_l + h * 64);
    const float4* ar = (const float4*)(attn_r + h * 64);
    float sl = 0.f, sr = 0.f;
    #pragma unroll
    for (int i = 0; i < 16; ++i) {
        float4 fv = f[i], lv = al[i], rv = ar[i];
        sl += fv.x * lv.x + fv.y * lv.y + fv.z * lv.z + fv.w * lv.w;
        sr += fv.x * rv.x + fv.y * rv.y + fv.z * rv.z + fv.w * rv.w;
    }
    el[idx] = sl;
    er[idx] = sr;
}

// ---------------- inits ----------------
__global__ void init_h_bias(float* __restrict__ h, const float* __restrict__ bias, int total) {
    int idx = blockIdx.x * 256 + threadIdx.x;
    if (idx < total) h[idx] = bias[idx & 511];
}
__global__ void init_emax(unsigned int* __restrict__ emax, int total) {
    int idx = blockIdx.x * 256 + threadIdx.x;
    if (idx < total) emax[idx] = 0x007FFFFFu; // enc(-inf)
}

// ---------------- edge kernels ----------------
__global__ __launch_bounds__(256)
void edge_logits(const int* __restrict__ src, const int* __restrict__ dst,
                 const float* __restrict__ el, const float* __restrict__ er,
                 float* __restrict__ ebuf, unsigned int* __restrict__ emax, int E8)
{
    int idx = blockIdx.x * 256 + threadIdx.x; // e*8 + h
    if (idx >= E8) return;
    int e = idx >> 3, h = idx & 7;
    float v = el[src[e] * 8 + h] + er[dst[e] * 8 + h];
    v = (v > 0.f) ? v : NEG_SLOPE * v;
    ebuf[idx] = v;
    atomicMax(&emax[dst[e] * 8 + h], enc_f(v));
}

__global__ void decode_emax(unsigned int* __restrict__ buf, int total) {
    int idx = blockIdx.x * 256 + threadIdx.x;
    if (idx >= total) return;
    float f = dec_f(buf[idx]);
    if (!isfinite(f)) f = 0.f;
    ((float*)buf)[idx] = f;
}

__global__ __launch_bounds__(256)
void edge_exp(const int* __restrict__ dst, float* __restrict__ ebuf,
              const float* __restrict__ emax_f, float* __restrict__ denom, int E8)
{
    int idx = blockIdx.x * 256 + threadIdx.x;
    if (idx >= E8) return;
    int e = idx >> 3, h = idx & 7;
    float z = __expf(ebuf[idx] - emax_f[dst[e] * 8 + h]);
    ebuf[idx] = z;
    atomicAdd(&denom[dst[e] * 8 + h], z);
}

__global__ __launch_bounds__(256)
void edge_alpha(const int* __restrict__ dst, float* __restrict__ ebuf,
                const float* __restrict__ denom, int E8)
{
    int idx = blockIdx.x * 256 + threadIdx.x;
    if (idx >= E8) return;
    ebuf[idx] = ebuf[idx] / denom[dst[idx >> 3] * 8 + (idx & 7)];
}

// one lane per (edge, head, d); 64 lanes = one (edge,head) row
__global__ __launch_bounds__(256)
void scatter_msg(const int* __restrict__ src, const int* __restrict__ dst,
                 const float* __restrict__ alpha, const float* __restrict__ feat,
                 float* __restrict__ hout, int total)
{
    int gtid = blockIdx.x * 256 + threadIdx.x;
    if (gtid >= total) return;
    int pair = gtid >> 6;   // e*8 + h
    int d = gtid & 63;
    int e = pair >> 3, h = pair & 7;
    float a = alpha[pair];
    float val = a * feat[((size_t)src[e] * 8 + h) * 64 + d];
    atomicAdd(&hout[((size_t)dst[e] * 8 + h) * 64 + d], val);
}

// ---------------- batchnorm ----------------
__global__ __launch_bounds__(256)
void bn_stats(const float* __restrict__ X, int M, int C, float* __restrict__ sums,
              int rows_per_block)
{
    int rbeg = blockIdx.x * rows_per_block;
    int rend = min(M, rbeg + rows_per_block);
    for (int c = threadIdx.x; c < C; c += 256) {
        float s = 0.f, q = 0.f;
        for (int r = rbeg; r < rend; ++r) {
            float v = X[(size_t)r * C + c];
            s += v; q += v * v;
        }
        atomicAdd(&sums[c], s);
        atomicAdd(&sums[C + c], q);
    }
}

__global__ void bn_finalize(const float* __restrict__ sums, const float* __restrict__ gamma,
                            const float* __restrict__ beta, float* __restrict__ ab,
                            int C, float invM)
{
    int c = blockIdx.x * blockDim.x + threadIdx.x;
    if (c >= C) return;
    float mu = sums[c] * invM;
    float var = sums[C + c] * invM - mu * mu;
    float a = gamma[c] * rsqrtf(var + BN_EPS);
    ab[c] = a;
    ab[C + c] = beta[c] - a * mu;
}

__global__ __launch_bounds__(256)
void bn_apply64(float* __restrict__ X, const float* __restrict__ ab, int total)
{
    int idx = blockIdx.x * 256 + threadIdx.x;
    if (idx >= total) return;
    int c = idx & 63;
    X[idx] = fmaf(ab[c], X[idx], ab[64 + c]);
}

extern "C" void kernel_launch(void* const* d_in, const int* in_sizes, int n_in,
                              void* d_out, int out_size, void* d_ws, size_t ws_size,
                              hipStream_t stream)
{
    const float* x         = (const float*)d_in[0];
    const int*   src       = (const int*)d_in[1];
    const int*   dst       = (const int*)d_in[2];
    const float* fc_w      = (const float*)d_in[3];
    const float* attn_l    = (const float*)d_in[4];
    const float* attn_r    = (const float*)d_in[5];
    const float* gat_bias  = (const float*)d_in[6];
    const float* bn1_gamma = (const float*)d_in[7];
    const float* bn1_beta  = (const float*)d_in[8];
    const float* w1        = (const float*)d_in[9];
    const float* b1        = (const float*)d_in[10];
    const float* w2        = (const float*)d_in[11];
    const float* b2        = (const float*)d_in[12];
    const float* bn2_gamma = (const float*)d_in[13];
    const float* bn2_beta  = (const float*)d_in[14];
    float* out = (float*)d_out;

    const int D = 64, HD = 512, HID = 1024;
    const int N = in_sizes[0] / D;   // 50000
    const int E = in_sizes[1];       // 400000
    const int E8 = E * 8;
    const int NH = N * 8;

    // ---- workspace layout (total ~214 MiB) ----
    size_t off = 0;
    auto alloc = [&](size_t bytes) -> void* {
        void* p = (char*)d_ws + off;
        off += (bytes + 255) & ~(size_t)255;
        return p;
    };
    // Region A: feat fp32 [N,512] (dead after scatter_msg), reused as h1 bf16 [N,1024]
    void* regionA = alloc((size_t)N * HD * 4);          // == N*HID*2 bytes
    float* feat = (float*)regionA;
    __hip_bfloat16* h1 = (__hip_bfloat16*)regionA;
    float* hbuf  = (float*)alloc((size_t)N * HD * 4);
    float* ebuf  = (float*)alloc((size_t)E8 * 4);
    float* el    = (float*)alloc((size_t)NH * 4);
    float* er    = (float*)alloc((size_t)NH * 4);
    unsigned int* emax = (unsigned int*)alloc((size_t)NH * 4);
    float* denom = (float*)alloc((size_t)NH * 4);
    float* sums1 = (float*)alloc(2 * 512 * 4);
    float* ab1   = (float*)alloc(2 * 512 * 4);
    float* sums2 = (float*)alloc(2 * 64 * 4);
    float* ab2   = (float*)alloc(2 * 64 * 4);
    (void)ws_size; (void)n_in; (void)out_size;

    // ---- GEMM1: feat = x @ fc_w^T   [N,64]x[64,512] ----
    {
        dim3 grid((N + 63) / 64, HD / 64);
        gemm_tn<float, float><<<grid, 256, 0, stream>>>(x, fc_w, feat, N, HD, D,
                                                        nullptr, nullptr, nullptr, 0);
    }
    // ---- el/er ----
    el_er_kernel<<<(NH + 255) / 256, 256, 0, stream>>>(feat, attn_l, attn_r, el, er, NH);

    // ---- inits ----
    init_h_bias<<<((N * HD) + 255) / 256, 256, 0, stream>>>(hbuf, gat_bias, N * HD);
    init_emax<<<(NH + 255) / 256, 256, 0, stream>>>(emax, NH);
    hipMemsetAsync(denom, 0, (size_t)NH * 4, stream);
    hipMemsetAsync(sums1, 0, 2 * 512 * 4, stream);
    hipMemsetAsync(sums2, 0, 2 * 64 * 4, stream);

    // ---- edge softmax ----
    edge_logits<<<(E8 + 255) / 256, 256, 0, stream>>>(src, dst, el, er, ebuf, emax, E8);
    decode_emax<<<(NH + 255) / 256, 256, 0, stream>>>(emax, NH);
    edge_exp<<<(E8 + 255) / 256, 256, 0, stream>>>(dst, ebuf, (const float*)emax, denom, E8);
    edge_alpha<<<(E8 + 255) / 256, 256, 0, stream>>>(dst, ebuf, denom, E8);

    // ---- message scatter-aggregate ----
    {
        int total = E8 * 64; // 204.8M lanes
        scatter_msg<<<(total + 255) / 256, 256, 0, stream>>>(src, dst, ebuf, feat, hbuf, total);
    }

    // ---- BN1 stats -> fused into GEMM2 A-load ----
    {
        int rpb = 128;
        bn_stats<<<(N + rpb - 1) / rpb, 256, 0, stream>>>(hbuf, N, HD, sums1, rpb);
        bn_finalize<<<2, 256, 0, stream>>>(sums1, bn1_gamma, bn1_beta, ab1, HD, 1.f / N);
    }

    // ---- GEMM2: h1 = relu(bn1(h) @ w1^T + b1)   [N,512]x[512,1024], bf16 out ----
    // (writes into regionA; feat fp32 is dead by now)
    {
        dim3 grid((N + 63) / 64, HID / 64);
        gemm_tn<float, __hip_bfloat16><<<grid, 256, 0, stream>>>(hbuf, w1, h1, N, HID, HD,
                                                                 ab1, ab1 + 512, b1, 1);
    }
    // ---- GEMM3: out = h1 @ w2^T + b2   [N,1024]x[1024,64] ----
    {
        dim3 grid((N + 63) / 64, 1);
        gemm_tn<__hip_bfloat16, float><<<grid, 256, 0, stream>>>(h1, w2, out, N, D, HID,
                                                                 nullptr, nullptr, b2, 0);
    }
    // ---- BN2 ----
    {
        int rpb = 128;
        bn_stats<<<(N + rpb - 1) / rpb, 256, 0, stream>>>(out, N, D, sums2, rpb);
        bn_finalize<<<1, 64, 0, stream>>>(sums2, bn2_gamma, bn2_beta, ab2, D, 1.f / N);
        bn_apply64<<<((N * D) + 255) / 256, 256, 0, stream>>>(out, ab2, N * D);
    }
}

// Round 4
// 1257.807 us; speedup vs baseline: 1.5876x; 1.5876x over previous
//
#include <hip/hip_runtime.h>

#define NEG_SLOPE 0.2f
#define BN_EPS 1e-5f

typedef __bf16 bf16x8 __attribute__((ext_vector_type(8)));
typedef float  f32x4  __attribute__((ext_vector_type(4)));

// ---- helpers ----
__device__ __forceinline__ unsigned int enc_f(float x) {
    unsigned int u = __float_as_uint(x);
    return (u & 0x80000000u) ? ~u : (u | 0x80000000u);
}
__device__ __forceinline__ float dec_f(unsigned int u) {
    unsigned int b = (u & 0x80000000u) ? (u ^ 0x80000000u) : ~u;
    return __uint_as_float(b);
}
__device__ __forceinline__ unsigned short f2bf(float f) {  // RNE f32->bf16
    unsigned int u = __float_as_uint(f);
    unsigned int r = u + 0x7FFFu + ((u >> 16) & 1u);
    return (unsigned short)(r >> 16);
}

// ---------------- GEMM1 (fp32 vector, small): C = A @ B^T ----------------
__global__ __launch_bounds__(256)
void gemm_tn(const float* __restrict__ A, const float* __restrict__ B,
             float* __restrict__ C, int M, int N, int K)
{
    __shared__ float As[16][68];
    __shared__ float Bs[16][68];
    const int bm = blockIdx.x * 64;
    const int bn = blockIdx.y * 64;
    const int tid = threadIdx.x;
    const int tx = tid & 15, ty = tid >> 4;
    const int lk = tid & 15, lr0 = tid >> 4;
    float acc[4][4] = {};
    for (int k0 = 0; k0 < K; k0 += 16) {
        #pragma unroll
        for (int i = 0; i < 4; ++i) {
            int r = lr0 + i * 16;
            int gm = bm + r;
            As[lk][r] = (gm < M) ? A[(size_t)gm * K + k0 + lk] : 0.f;
        }
        #pragma unroll
        for (int i = 0; i < 4; ++i) {
            int r = lr0 + i * 16;
            int gn = bn + r;
            Bs[lk][r] = (gn < N) ? B[(size_t)gn * K + k0 + lk] : 0.f;
        }
        __syncthreads();
        #pragma unroll
        for (int k = 0; k < 16; ++k) {
            float4 a4 = *(const float4*)&As[k][ty * 4];
            float4 b4 = *(const float4*)&Bs[k][tx * 4];
            float a[4] = {a4.x, a4.y, a4.z, a4.w};
            float b[4] = {b4.x, b4.y, b4.z, b4.w};
            #pragma unroll
            for (int i = 0; i < 4; ++i)
                #pragma unroll
                for (int j = 0; j < 4; ++j)
                    acc[i][j] = fmaf(a[i], b[j], acc[i][j]);
        }
        __syncthreads();
    }
    #pragma unroll
    for (int i = 0; i < 4; ++i) {
        int gm = bm + ty * 4 + i;
        if (gm >= M) continue;
        #pragma unroll
        for (int j = 0; j < 4; ++j) {
            int gn = bn + tx * 4 + j;
            if (gn < N) C[(size_t)gm * N + gn] = acc[i][j];
        }
    }
}

// ---------------- GEMM2 (MFMA): h1_bf16[M,1024] = relu(bn1(hbuf) @ w1bf^T + b1) ----
// A: hbuf fp32 [M,512] (BN affine fused at stage), B: w1 bf16 [1024,512].
__global__ __launch_bounds__(256)
void gemm2_mfma(const float* __restrict__ A, const unsigned short* __restrict__ Bw,
                unsigned short* __restrict__ C, int M,
                const float* __restrict__ ab, const float* __restrict__ bias)
{
    __shared__ alignas(16) char Asm[128 * 64 * 2];
    __shared__ alignas(16) char Bsm[128 * 64 * 2];
    const int tid = threadIdx.x;
    const int lane = tid & 63;
    const int wave = tid >> 6;
    const int wr = wave >> 1, wc = wave & 1;

    // XCD-coherent bijective swizzle: nwg=3128=8*391
    int bid = blockIdx.x;
    int wgid = (bid & 7) * 391 + (bid >> 3);
    const int bm = (wgid >> 3) * 128;
    const int bn = (wgid & 7) * 128;

    f32x4 acc[4][4] = {};

    for (int k0 = 0; k0 < 512; k0 += 64) {
        __syncthreads();
        // stage A: fp32 -> BN affine -> bf16. 128 rows x 8 subs = 1024 segs of 16B.
        #pragma unroll
        for (int it = 0; it < 4; ++it) {
            int seg = wave * 256 + it * 64 + lane;
            int row = seg >> 3, sub = seg & 7;
            int gm = bm + row;
            int kc = k0 + sub * 8;
            float4 v0 = {0.f, 0.f, 0.f, 0.f}, v1 = {0.f, 0.f, 0.f, 0.f};
            if (gm < M) {
                v0 = *(const float4*)&A[(size_t)gm * 512 + kc];
                v1 = *(const float4*)&A[(size_t)gm * 512 + kc + 4];
            }
            float4 s0 = *(const float4*)&ab[kc];
            float4 s1 = *(const float4*)&ab[kc + 4];
            float4 t0 = *(const float4*)&ab[512 + kc];
            float4 t1 = *(const float4*)&ab[512 + kc + 4];
            unsigned int p0 = f2bf(fmaf(v0.x, s0.x, t0.x)) | ((unsigned int)f2bf(fmaf(v0.y, s0.y, t0.y)) << 16);
            unsigned int p1 = f2bf(fmaf(v0.z, s0.z, t0.z)) | ((unsigned int)f2bf(fmaf(v0.w, s0.w, t0.w)) << 16);
            unsigned int p2 = f2bf(fmaf(v1.x, s1.x, t1.x)) | ((unsigned int)f2bf(fmaf(v1.y, s1.y, t1.y)) << 16);
            unsigned int p3 = f2bf(fmaf(v1.z, s1.z, t1.z)) | ((unsigned int)f2bf(fmaf(v1.w, s1.w, t1.w)) << 16);
            uint4 w = {p0, p1, p2, p3};
            *(uint4*)(Asm + row * 128 + ((sub ^ (row & 7)) << 4)) = w;
        }
        // stage B: bf16 copy, same swizzle. 128 rows x 8 subs.
        #pragma unroll
        for (int it = 0; it < 4; ++it) {
            int seg = wave * 256 + it * 64 + lane;
            int row = seg >> 3, sub = seg & 7;
            uint4 w = *(const uint4*)&Bw[(size_t)(bn + row) * 512 + k0 + sub * 8];
            *(uint4*)(Bsm + row * 128 + ((sub ^ (row & 7)) << 4)) = w;
        }
        __syncthreads();
        #pragma unroll
        for (int kk = 0; kk < 2; ++kk) {
            int kg = kk * 4 + (lane >> 4);
            bf16x8 a[4], b[4];
            #pragma unroll
            for (int i = 0; i < 4; ++i) {
                int row = wr * 64 + i * 16 + (lane & 15);
                a[i] = *(const bf16x8*)(Asm + row * 128 + ((kg ^ (row & 7)) << 4));
            }
            #pragma unroll
            for (int j = 0; j < 4; ++j) {
                int row = wc * 64 + j * 16 + (lane & 15);
                b[j] = *(const bf16x8*)(Bsm + row * 128 + ((kg ^ (row & 7)) << 4));
            }
            #pragma unroll
            for (int i = 0; i < 4; ++i)
                #pragma unroll
                for (int j = 0; j < 4; ++j)
                    acc[i][j] = __builtin_amdgcn_mfma_f32_16x16x32_bf16(a[i], b[j], acc[i][j], 0, 0, 0);
        }
    }

    // epilogue: +bias, relu, bf16 store. D: row=(lane>>4)*4+r, col=lane&15
    #pragma unroll
    for (int j = 0; j < 4; ++j) {
        int gn = bn + wc * 64 + j * 16 + (lane & 15);
        float bs = bias[gn];
        #pragma unroll
        for (int i = 0; i < 4; ++i) {
            #pragma unroll
            for (int r = 0; r < 4; ++r) {
                int gm = bm + wr * 64 + i * 16 + (lane >> 4) * 4 + r;
                if (gm < M) {
                    float v = fmaxf(acc[i][j][r] + bs, 0.f);
                    C[(size_t)gm * 1024 + gn] = f2bf(v);
                }
            }
        }
    }
}

// ---------------- GEMM3 (MFMA, split-K): out += h1_bf16 @ w2bf^T ----------------
// grid (391, 4); K-chunk 256. out pre-initialized with b2.
__global__ __launch_bounds__(256)
void gemm3_mfma(const unsigned short* __restrict__ A, const unsigned short* __restrict__ Bw,
                float* __restrict__ Cout, int M)
{
    __shared__ alignas(16) char Asm[128 * 64 * 2];
    __shared__ alignas(16) char Bsm[64 * 64 * 2];
    const int tid = threadIdx.x;
    const int lane = tid & 63;
    const int wave = tid >> 6;
    const int wr = wave >> 1, wc = wave & 1;
    const int bm = blockIdx.x * 128;
    const int kbase = blockIdx.y * 256;

    f32x4 acc[4][2] = {};

    for (int k0 = kbase; k0 < kbase + 256; k0 += 64) {
        __syncthreads();
        // A tile: 128 rows x 8 subs = 1024 segs
        #pragma unroll
        for (int it = 0; it < 4; ++it) {
            int seg = wave * 256 + it * 64 + lane;
            int row = seg >> 3, sub = seg & 7;
            int gm = bm + row;
            uint4 w = {0u, 0u, 0u, 0u};
            if (gm < M) w = *(const uint4*)&A[(size_t)gm * 1024 + k0 + sub * 8];
            *(uint4*)(Asm + row * 128 + ((sub ^ (row & 7)) << 4)) = w;
        }
        // B tile: 64 rows x 8 subs = 512 segs
        #pragma unroll
        for (int it = 0; it < 2; ++it) {
            int seg = it * 256 + tid;
            int row = seg >> 3, sub = seg & 7;
            uint4 w = *(const uint4*)&Bw[(size_t)row * 1024 + k0 + sub * 8];
            *(uint4*)(Bsm + row * 128 + ((sub ^ (row & 7)) << 4)) = w;
        }
        __syncthreads();
        #pragma unroll
        for (int kk = 0; kk < 2; ++kk) {
            int kg = kk * 4 + (lane >> 4);
            bf16x8 a[4], b[2];
            #pragma unroll
            for (int i = 0; i < 4; ++i) {
                int row = wr * 64 + i * 16 + (lane & 15);
                a[i] = *(const bf16x8*)(Asm + row * 128 + ((kg ^ (row & 7)) << 4));
            }
            #pragma unroll
            for (int j = 0; j < 2; ++j) {
                int row = wc * 32 + j * 16 + (lane & 15);
                b[j] = *(const bf16x8*)(Bsm + row * 128 + ((kg ^ (row & 7)) << 4));
            }
            #pragma unroll
            for (int i = 0; i < 4; ++i)
                #pragma unroll
                for (int j = 0; j < 2; ++j)
                    acc[i][j] = __builtin_amdgcn_mfma_f32_16x16x32_bf16(a[i], b[j], acc[i][j], 0, 0, 0);
        }
    }
    #pragma unroll
    for (int i = 0; i < 4; ++i)
        #pragma unroll
        for (int j = 0; j < 2; ++j)
            #pragma unroll
            for (int r = 0; r < 4; ++r) {
                int gm = bm + wr * 64 + i * 16 + (lane >> 4) * 4 + r;
                int gn = wc * 32 + j * 16 + (lane & 15);
                if (gm < M) atomicAdd(&Cout[(size_t)gm * 64 + gn], acc[i][j][r]);
            }
}

// ---------------- attention logits el/er: [N,8] each ----------------
__global__ __launch_bounds__(256)
void el_er_kernel(const float* __restrict__ feat,
                  const float* __restrict__ attn_l, const float* __restrict__ attn_r,
                  float* __restrict__ el, float* __restrict__ er, int NH)
{
    int idx = blockIdx.x * 256 + threadIdx.x;
    if (idx >= NH) return;
    int h = idx & 7;
    const float4* f  = (const float4*)(feat + (size_t)idx * 64);
    const float4* al = (const float4*)(attn_l + h * 64);
    const float4* ar = (const float4*)(attn_r + h * 64);
    float sl = 0.f, sr = 0.f;
    #pragma unroll
    for (int i = 0; i < 16; ++i) {
        float4 fv = f[i], lv = al[i], rv = ar[i];
        sl += fv.x * lv.x + fv.y * lv.y + fv.z * lv.z + fv.w * lv.w;
        sr += fv.x * rv.x + fv.y * rv.y + fv.z * rv.z + fv.w * rv.w;
    }
    el[idx] = sl;
    er[idx] = sr;
}

// ---------------- inits / conversions ----------------
__global__ void init_h_bias(float* __restrict__ h, const float* __restrict__ bias, int total) {
    int idx = blockIdx.x * 256 + threadIdx.x;
    if (idx < total) h[idx] = bias[idx & 511];
}
__global__ void init_emax(unsigned int* __restrict__ emax, int total) {
    int idx = blockIdx.x * 256 + threadIdx.x;
    if (idx < total) emax[idx] = 0x007FFFFFu; // enc(-inf)
}
__global__ void init_out_bias(float* __restrict__ o, const float* __restrict__ b, int total) {
    int idx = blockIdx.x * 256 + threadIdx.x;
    if (idx < total) o[idx] = b[idx & 63];
}
__global__ void cvt_f32_bf16(const float* __restrict__ s, unsigned short* __restrict__ d, int n) {
    int i = blockIdx.x * 256 + threadIdx.x;
    if (i < n) d[i] = f2bf(s[i]);
}

// ---------------- edge kernels ----------------
__global__ __launch_bounds__(256)
void edge_logits(const int* __restrict__ src, const int* __restrict__ dst,
                 const float* __restrict__ el, const float* __restrict__ er,
                 float* __restrict__ ebuf, unsigned int* __restrict__ emax, int E8)
{
    int idx = blockIdx.x * 256 + threadIdx.x;
    if (idx >= E8) return;
    int e = idx >> 3, h = idx & 7;
    float v = el[src[e] * 8 + h] + er[dst[e] * 8 + h];
    v = (v > 0.f) ? v : NEG_SLOPE * v;
    ebuf[idx] = v;
    atomicMax(&emax[dst[e] * 8 + h], enc_f(v));
}

__global__ void decode_emax(unsigned int* __restrict__ buf, int total) {
    int idx = blockIdx.x * 256 + threadIdx.x;
    if (idx >= total) return;
    float f = dec_f(buf[idx]);
    if (!isfinite(f)) f = 0.f;
    ((float*)buf)[idx] = f;
}

__global__ __launch_bounds__(256)
void edge_exp(const int* __restrict__ dst, float* __restrict__ ebuf,
              const float* __restrict__ emax_f, float* __restrict__ denom, int E8)
{
    int idx = blockIdx.x * 256 + threadIdx.x;
    if (idx >= E8) return;
    int e = idx >> 3, h = idx & 7;
    float z = __expf(ebuf[idx] - emax_f[dst[e] * 8 + h]);
    ebuf[idx] = z;
    atomicAdd(&denom[dst[e] * 8 + h], z);
}

__global__ __launch_bounds__(256)
void edge_alpha(const int* __restrict__ dst, float* __restrict__ ebuf,
                const float* __restrict__ denom, int E8)
{
    int idx = blockIdx.x * 256 + threadIdx.x;
    if (idx >= E8) return;
    ebuf[idx] = ebuf[idx] / denom[dst[idx >> 3] * 8 + (idx & 7)];
}

__global__ __launch_bounds__(256)
void scatter_msg(const int* __restrict__ src, const int* __restrict__ dst,
                 const float* __restrict__ alpha, const float* __restrict__ feat,
                 float* __restrict__ hout, int total)
{
    int gtid = blockIdx.x * 256 + threadIdx.x;
    if (gtid >= total) return;
    int pair = gtid >> 6;
    int d = gtid & 63;
    int e = pair >> 3, h = pair & 7;
    float a = alpha[pair];
    float val = a * feat[((size_t)src[e] * 8 + h) * 64 + d];
    atomicAdd(&hout[((size_t)dst[e] * 8 + h) * 64 + d], val);
}

// ---------------- batchnorm ----------------
__global__ __launch_bounds__(256)
void bn_stats(const float* __restrict__ X, int M, int C, float* __restrict__ sums,
              int rows_per_block)
{
    int rbeg = blockIdx.x * rows_per_block;
    int rend = min(M, rbeg + rows_per_block);
    for (int c = threadIdx.x; c < C; c += 256) {
        float s = 0.f, q = 0.f;
        for (int r = rbeg; r < rend; ++r) {
            float v = X[(size_t)r * C + c];
            s += v; q += v * v;
        }
        atomicAdd(&sums[c], s);
        atomicAdd(&sums[C + c], q);
    }
}

__global__ void bn_finalize(const float* __restrict__ sums, const float* __restrict__ gamma,
                            const float* __restrict__ beta, float* __restrict__ ab,
                            int C, float invM)
{
    int c = blockIdx.x * blockDim.x + threadIdx.x;
    if (c >= C) return;
    float mu = sums[c] * invM;
    float var = sums[C + c] * invM - mu * mu;
    float a = gamma[c] * rsqrtf(var + BN_EPS);
    ab[c] = a;
    ab[C + c] = beta[c] - a * mu;
}

__global__ __launch_bounds__(256)
void bn_apply64(float* __restrict__ X, const float* __restrict__ ab, int total)
{
    int idx = blockIdx.x * 256 + threadIdx.x;
    if (idx >= total) return;
    int c = idx & 63;
    X[idx] = fmaf(ab[c], X[idx], ab[64 + c]);
}

extern "C" void kernel_launch(void* const* d_in, const int* in_sizes, int n_in,
                              void* d_out, int out_size, void* d_ws, size_t ws_size,
                              hipStream_t stream)
{
    const float* x         = (const float*)d_in[0];
    const int*   src       = (const int*)d_in[1];
    const int*   dst       = (const int*)d_in[2];
    const float* fc_w      = (const float*)d_in[3];
    const float* attn_l    = (const float*)d_in[4];
    const float* attn_r    = (const float*)d_in[5];
    const float* gat_bias  = (const float*)d_in[6];
    const float* bn1_gamma = (const float*)d_in[7];
    const float* bn1_beta  = (const float*)d_in[8];
    const float* w1        = (const float*)d_in[9];
    const float* b1        = (const float*)d_in[10];
    const float* w2        = (const float*)d_in[11];
    const float* b2        = (const float*)d_in[12];
    const float* bn2_gamma = (const float*)d_in[13];
    const float* bn2_beta  = (const float*)d_in[14];
    float* out = (float*)d_out;

    const int D = 64, HD = 512, HID = 1024;
    const int N = in_sizes[0] / D;   // 50000
    const int E = in_sizes[1];       // 400000
    const int E8 = E * 8;
    const int NH = N * 8;

    size_t off = 0;
    auto alloc = [&](size_t bytes) -> void* {
        void* p = (char*)d_ws + off;
        off += (bytes + 255) & ~(size_t)255;
        return p;
    };
    // Region A: feat fp32 [N,512] (dead after scatter_msg), reused as h1 bf16 [N,1024]
    void* regionA = alloc((size_t)N * HD * 4);
    float* feat = (float*)regionA;
    unsigned short* h1 = (unsigned short*)regionA;
    float* hbuf  = (float*)alloc((size_t)N * HD * 4);
    float* ebuf  = (float*)alloc((size_t)E8 * 4);
    float* el    = (float*)alloc((size_t)NH * 4);
    float* er    = (float*)alloc((size_t)NH * 4);
    unsigned int* emax = (unsigned int*)alloc((size_t)NH * 4);
    float* denom = (float*)alloc((size_t)NH * 4);
    unsigned short* w1bf = (unsigned short*)alloc((size_t)HID * HD * 2);
    unsigned short* w2bf = (unsigned short*)alloc((size_t)D * HID * 2);
    float* sums1 = (float*)alloc(2 * 512 * 4);
    float* ab1   = (float*)alloc(2 * 512 * 4);
    float* sums2 = (float*)alloc(2 * 64 * 4);
    float* ab2   = (float*)alloc(2 * 64 * 4);
    (void)ws_size; (void)n_in; (void)out_size;

    // ---- weight conversions ----
    cvt_f32_bf16<<<(HID * HD + 255) / 256, 256, 0, stream>>>(w1, w1bf, HID * HD);
    cvt_f32_bf16<<<(D * HID + 255) / 256, 256, 0, stream>>>(w2, w2bf, D * HID);

    // ---- GEMM1: feat = x @ fc_w^T   [N,64]x[64,512] ----
    {
        dim3 grid((N + 63) / 64, HD / 64);
        gemm_tn<<<grid, 256, 0, stream>>>(x, fc_w, feat, N, HD, D);
    }
    el_er_kernel<<<(NH + 255) / 256, 256, 0, stream>>>(feat, attn_l, attn_r, el, er, NH);

    // ---- inits ----
    init_h_bias<<<((N * HD) + 255) / 256, 256, 0, stream>>>(hbuf, gat_bias, N * HD);
    init_emax<<<(NH + 255) / 256, 256, 0, stream>>>(emax, NH);
    hipMemsetAsync(denom, 0, (size_t)NH * 4, stream);
    hipMemsetAsync(sums1, 0, 2 * 512 * 4, stream);
    hipMemsetAsync(sums2, 0, 2 * 64 * 4, stream);

    // ---- edge softmax ----
    edge_logits<<<(E8 + 255) / 256, 256, 0, stream>>>(src, dst, el, er, ebuf, emax, E8);
    decode_emax<<<(NH + 255) / 256, 256, 0, stream>>>(emax, NH);
    edge_exp<<<(E8 + 255) / 256, 256, 0, stream>>>(dst, ebuf, (const float*)emax, denom, E8);
    edge_alpha<<<(E8 + 255) / 256, 256, 0, stream>>>(dst, ebuf, denom, E8);

    // ---- message scatter-aggregate ----
    {
        int total = E8 * 64;
        scatter_msg<<<(total + 255) / 256, 256, 0, stream>>>(src, dst, ebuf, feat, hbuf, total);
    }

    // ---- BN1 stats (fused into GEMM2 A-stage) ----
    {
        int rpb = 128;
        bn_stats<<<(N + rpb - 1) / rpb, 256, 0, stream>>>(hbuf, N, HD, sums1, rpb);
        bn_finalize<<<2, 256, 0, stream>>>(sums1, bn1_gamma, bn1_beta, ab1, HD, 1.f / N);
    }

    // ---- GEMM2 (MFMA): h1 = relu(bn1(hbuf) @ w1bf^T + b1) -> bf16 ----
    {
        int nwg = ((N + 127) / 128) * (HID / 128);  // 391*8 = 3128
        gemm2_mfma<<<nwg, 256, 0, stream>>>(hbuf, w1bf, h1, N, ab1, b1);
    }

    // ---- GEMM3 (MFMA, split-K): out = h1 @ w2bf^T + b2 ----
    init_out_bias<<<((N * D) + 255) / 256, 256, 0, stream>>>(out, b2, N * D);
    {
        dim3 grid((N + 127) / 128, 4);
        gemm3_mfma<<<grid, 256, 0, stream>>>(h1, w2bf, out, N);
    }

    // ---- BN2 ----
    {
        int rpb = 128;
        bn_stats<<<(N + rpb - 1) / rpb, 256, 0, stream>>>(out, N, D, sums2, rpb);
        bn_finalize<<<1, 64, 0, stream>>>(sums2, bn2_gamma, bn2_beta, ab2, D, 1.f / N);
        bn_apply64<<<((N * D) + 255) / 256, 256, 0, stream>>>(out, ab2, N * D);
    }
}

// Round 5
// 649.869 us; speedup vs baseline: 3.0727x; 1.9355x over previous
//
#include <hip/hip_runtime.h>

#define NEG_SLOPE 0.2f
#define BN_EPS 1e-5f

typedef __bf16 bf16x8 __attribute__((ext_vector_type(8)));
typedef float  f32x4  __attribute__((ext_vector_type(4)));

__device__ __forceinline__ unsigned short f2bf(float f) {  // RNE f32->bf16
    unsigned int u = __float_as_uint(f);
    unsigned int r = u + 0x7FFFu + ((u >> 16) & 1u);
    return (unsigned short)(r >> 16);
}

// ---------------- GEMM1 (fp32 vector, small K=64): C = A @ B^T ----------------
__global__ __launch_bounds__(256)
void gemm_tn(const float* __restrict__ A, const float* __restrict__ B,
             float* __restrict__ C, int M, int N, int K)
{
    __shared__ float As[16][68];
    __shared__ float Bs[16][68];
    const int bm = blockIdx.x * 64;
    const int bn = blockIdx.y * 64;
    const int tid = threadIdx.x;
    const int tx = tid & 15, ty = tid >> 4;
    const int lk = tid & 15, lr0 = tid >> 4;
    float acc[4][4] = {};
    for (int k0 = 0; k0 < K; k0 += 16) {
        #pragma unroll
        for (int i = 0; i < 4; ++i) {
            int r = lr0 + i * 16;
            int gm = bm + r;
            As[lk][r] = (gm < M) ? A[(size_t)gm * K + k0 + lk] : 0.f;
        }
        #pragma unroll
        for (int i = 0; i < 4; ++i) {
            int r = lr0 + i * 16;
            int gn = bn + r;
            Bs[lk][r] = (gn < N) ? B[(size_t)gn * K + k0 + lk] : 0.f;
        }
        __syncthreads();
        #pragma unroll
        for (int k = 0; k < 16; ++k) {
            float4 a4 = *(const float4*)&As[k][ty * 4];
            float4 b4 = *(const float4*)&Bs[k][tx * 4];
            float a[4] = {a4.x, a4.y, a4.z, a4.w};
            float b[4] = {b4.x, b4.y, b4.z, b4.w};
            #pragma unroll
            for (int i = 0; i < 4; ++i)
                #pragma unroll
                for (int j = 0; j < 4; ++j)
                    acc[i][j] = fmaf(a[i], b[j], acc[i][j]);
        }
        __syncthreads();
    }
    #pragma unroll
    for (int i = 0; i < 4; ++i) {
        int gm = bm + ty * 4 + i;
        if (gm >= M) continue;
        #pragma unroll
        for (int j = 0; j < 4; ++j) {
            int gn = bn + tx * 4 + j;
            if (gn < N) C[(size_t)gm * N + gn] = acc[i][j];
        }
    }
}

// ---------------- GEMM2 (MFMA): h1_bf16[M,1024] = relu(bn1(hbuf) @ w1bf^T + b1) ----
__global__ __launch_bounds__(256)
void gemm2_mfma(const float* __restrict__ A, const unsigned short* __restrict__ Bw,
                unsigned short* __restrict__ C, int M,
                const float* __restrict__ ab, const float* __restrict__ bias)
{
    __shared__ alignas(16) char Asm[128 * 64 * 2];
    __shared__ alignas(16) char Bsm[128 * 64 * 2];
    const int tid = threadIdx.x;
    const int lane = tid & 63;
    const int wave = tid >> 6;
    const int wr = wave >> 1, wc = wave & 1;

    int bid = blockIdx.x;
    int wgid = (bid & 7) * 391 + (bid >> 3);   // nwg = 3128 = 8*391, bijective
    const int bm = (wgid >> 3) * 128;
    const int bn = (wgid & 7) * 128;

    f32x4 acc[4][4] = {};

    for (int k0 = 0; k0 < 512; k0 += 64) {
        __syncthreads();
        #pragma unroll
        for (int it = 0; it < 4; ++it) {
            int seg = wave * 256 + it * 64 + lane;
            int row = seg >> 3, sub = seg & 7;
            int gm = bm + row;
            int kc = k0 + sub * 8;
            float4 v0 = {0.f, 0.f, 0.f, 0.f}, v1 = {0.f, 0.f, 0.f, 0.f};
            if (gm < M) {
                v0 = *(const float4*)&A[(size_t)gm * 512 + kc];
                v1 = *(const float4*)&A[(size_t)gm * 512 + kc + 4];
            }
            float4 s0 = *(const float4*)&ab[kc];
            float4 s1 = *(const float4*)&ab[kc + 4];
            float4 t0 = *(const float4*)&ab[512 + kc];
            float4 t1 = *(const float4*)&ab[512 + kc + 4];
            unsigned int p0 = f2bf(fmaf(v0.x, s0.x, t0.x)) | ((unsigned int)f2bf(fmaf(v0.y, s0.y, t0.y)) << 16);
            unsigned int p1 = f2bf(fmaf(v0.z, s0.z, t0.z)) | ((unsigned int)f2bf(fmaf(v0.w, s0.w, t0.w)) << 16);
            unsigned int p2 = f2bf(fmaf(v1.x, s1.x, t1.x)) | ((unsigned int)f2bf(fmaf(v1.y, s1.y, t1.y)) << 16);
            unsigned int p3 = f2bf(fmaf(v1.z, s1.z, t1.z)) | ((unsigned int)f2bf(fmaf(v1.w, s1.w, t1.w)) << 16);
            uint4 w = {p0, p1, p2, p3};
            *(uint4*)(Asm + row * 128 + ((sub ^ (row & 7)) << 4)) = w;
        }
        #pragma unroll
        for (int it = 0; it < 4; ++it) {
            int seg = wave * 256 + it * 64 + lane;
            int row = seg >> 3, sub = seg & 7;
            uint4 w = *(const uint4*)&Bw[(size_t)(bn + row) * 512 + k0 + sub * 8];
            *(uint4*)(Bsm + row * 128 + ((sub ^ (row & 7)) << 4)) = w;
        }
        __syncthreads();
        #pragma unroll
        for (int kk = 0; kk < 2; ++kk) {
            int kg = kk * 4 + (lane >> 4);
            bf16x8 a[4], b[4];
            #pragma unroll
            for (int i = 0; i < 4; ++i) {
                int row = wr * 64 + i * 16 + (lane & 15);
                a[i] = *(const bf16x8*)(Asm + row * 128 + ((kg ^ (row & 7)) << 4));
            }
            #pragma unroll
            for (int j = 0; j < 4; ++j) {
                int row = wc * 64 + j * 16 + (lane & 15);
                b[j] = *(const bf16x8*)(Bsm + row * 128 + ((kg ^ (row & 7)) << 4));
            }
            #pragma unroll
            for (int i = 0; i < 4; ++i)
                #pragma unroll
                for (int j = 0; j < 4; ++j)
                    acc[i][j] = __builtin_amdgcn_mfma_f32_16x16x32_bf16(a[i], b[j], acc[i][j], 0, 0, 0);
        }
    }

    #pragma unroll
    for (int j = 0; j < 4; ++j) {
        int gn = bn + wc * 64 + j * 16 + (lane & 15);
        float bs = bias[gn];
        #pragma unroll
        for (int i = 0; i < 4; ++i) {
            #pragma unroll
            for (int r = 0; r < 4; ++r) {
                int gm = bm + wr * 64 + i * 16 + (lane >> 4) * 4 + r;
                if (gm < M) {
                    float v = fmaxf(acc[i][j][r] + bs, 0.f);
                    C[(size_t)gm * 1024 + gn] = f2bf(v);
                }
            }
        }
    }
}

// ---------------- GEMM3 (MFMA, split-K): out += h1_bf16 @ w2bf^T ----------------
__global__ __launch_bounds__(256)
void gemm3_mfma(const unsigned short* __restrict__ A, const unsigned short* __restrict__ Bw,
                float* __restrict__ Cout, int M)
{
    __shared__ alignas(16) char Asm[128 * 64 * 2];
    __shared__ alignas(16) char Bsm[64 * 64 * 2];
    const int tid = threadIdx.x;
    const int lane = tid & 63;
    const int wave = tid >> 6;
    const int wr = wave >> 1, wc = wave & 1;
    const int bm = blockIdx.x * 128;
    const int kbase = blockIdx.y * 256;

    f32x4 acc[4][2] = {};

    for (int k0 = kbase; k0 < kbase + 256; k0 += 64) {
        __syncthreads();
        #pragma unroll
        for (int it = 0; it < 4; ++it) {
            int seg = wave * 256 + it * 64 + lane;
            int row = seg >> 3, sub = seg & 7;
            int gm = bm + row;
            uint4 w = {0u, 0u, 0u, 0u};
            if (gm < M) w = *(const uint4*)&A[(size_t)gm * 1024 + k0 + sub * 8];
            *(uint4*)(Asm + row * 128 + ((sub ^ (row & 7)) << 4)) = w;
        }
        #pragma unroll
        for (int it = 0; it < 2; ++it) {
            int seg = it * 256 + tid;
            int row = seg >> 3, sub = seg & 7;
            uint4 w = *(const uint4*)&Bw[(size_t)row * 1024 + k0 + sub * 8];
            *(uint4*)(Bsm + row * 128 + ((sub ^ (row & 7)) << 4)) = w;
        }
        __syncthreads();
        #pragma unroll
        for (int kk = 0; kk < 2; ++kk) {
            int kg = kk * 4 + (lane >> 4);
            bf16x8 a[4], b[2];
            #pragma unroll
            for (int i = 0; i < 4; ++i) {
                int row = wr * 64 + i * 16 + (lane & 15);
                a[i] = *(const bf16x8*)(Asm + row * 128 + ((kg ^ (row & 7)) << 4));
            }
            #pragma unroll
            for (int j = 0; j < 2; ++j) {
                int row = wc * 32 + j * 16 + (lane & 15);
                b[j] = *(const bf16x8*)(Bsm + row * 128 + ((kg ^ (row & 7)) << 4));
            }
            #pragma unroll
            for (int i = 0; i < 4; ++i)
                #pragma unroll
                for (int j = 0; j < 2; ++j)
                    acc[i][j] = __builtin_amdgcn_mfma_f32_16x16x32_bf16(a[i], b[j], acc[i][j], 0, 0, 0);
        }
    }
    #pragma unroll
    for (int i = 0; i < 4; ++i)
        #pragma unroll
        for (int j = 0; j < 2; ++j)
            #pragma unroll
            for (int r = 0; r < 4; ++r) {
                int gm = bm + wr * 64 + i * 16 + (lane >> 4) * 4 + r;
                int gn = wc * 32 + j * 16 + (lane & 15);
                if (gm < M) atomicAdd(&Cout[(size_t)gm * 64 + gn], acc[i][j][r]);
            }
}

// ---------------- attention logits el/er ----------------
__global__ __launch_bounds__(256)
void el_er_kernel(const float* __restrict__ feat,
                  const float* __restrict__ attn_l, const float* __restrict__ attn_r,
                  float* __restrict__ el, float* __restrict__ er, int NH)
{
    int idx = blockIdx.x * 256 + threadIdx.x;
    if (idx >= NH) return;
    int h = idx & 7;
    const float4* f  = (const float4*)(feat + (size_t)idx * 64);
    const float4* al = (const float4*)(attn_l + h * 64);
    const float4* ar = (const float4*)(attn_r + h * 64);
    float sl = 0.f, sr = 0.f;
    #pragma unroll
    for (int i = 0; i < 16; ++i) {
        float4 fv = f[i], lv = al[i], rv = ar[i];
        sl += fv.x * lv.x + fv.y * lv.y + fv.z * lv.z + fv.w * lv.w;
        sr += fv.x * rv.x + fv.y * rv.y + fv.z * rv.z + fv.w * rv.w;
    }
    el[idx] = sl;
    er[idx] = sr;
}

// ---------------- CSR build ----------------
__global__ void hist_kernel(const int* __restrict__ dst, int* __restrict__ counts, int E) {
    int i = blockIdx.x * 256 + threadIdx.x;
    if (i < E) atomicAdd(&counts[dst[i]], 1);
}
__global__ void scan1(const int* __restrict__ counts, int* __restrict__ incl,
                      int* __restrict__ bsum, int N) {
    __shared__ int sm[256];
    int i = blockIdx.x * 256 + threadIdx.x;
    int v = (i < N) ? counts[i] : 0;
    sm[threadIdx.x] = v;
    __syncthreads();
    #pragma unroll
    for (int d = 1; d < 256; d <<= 1) {
        int t = (threadIdx.x >= d) ? sm[threadIdx.x - d] : 0;
        __syncthreads();
        sm[threadIdx.x] += t;
        __syncthreads();
    }
    if (i < N) incl[i] = sm[threadIdx.x];
    if (threadIdx.x == 255) bsum[blockIdx.x] = sm[255];
}
__global__ void scan2(int* __restrict__ bsum, int nb) {  // nb <= 256, one block
    __shared__ int sm[256];
    int v = (threadIdx.x < nb) ? bsum[threadIdx.x] : 0;
    sm[threadIdx.x] = v;
    __syncthreads();
    #pragma unroll
    for (int d = 1; d < 256; d <<= 1) {
        int t = (threadIdx.x >= d) ? sm[threadIdx.x - d] : 0;
        __syncthreads();
        sm[threadIdx.x] += t;
        __syncthreads();
    }
    if (threadIdx.x < nb) bsum[threadIdx.x] = sm[threadIdx.x] - v;  // exclusive
}
__global__ void scan3(const int* __restrict__ incl, const int* __restrict__ bsum,
                      int* __restrict__ row_ptr, int N) {
    int i = blockIdx.x * 256 + threadIdx.x;
    if (i < N) row_ptr[i + 1] = incl[i] + bsum[blockIdx.x];
    if (i == 0) row_ptr[0] = 0;
}
__global__ void scatter_edges(const int* __restrict__ src, const int* __restrict__ dst,
                              int* __restrict__ cursor, int* __restrict__ esrc, int E) {
    int e = blockIdx.x * 256 + threadIdx.x;
    if (e < E) {
        int p = atomicAdd(&cursor[dst[e]], 1);
        esrc[p] = src[e];
    }
}

// ---------------- fused GAT: softmax + weighted aggregate, one wave per node ----
__global__ __launch_bounds__(256)
void gat_aggregate(const int* __restrict__ row_ptr, const int* __restrict__ esrc,
                   const float* __restrict__ el, const float* __restrict__ er,
                   const float* __restrict__ feat, const float* __restrict__ gat_bias,
                   float* __restrict__ hout, int N)
{
    int node = blockIdx.x * 4 + (threadIdx.x >> 6);
    if (node >= N) return;
    const int lane = threadIdx.x & 63;
    const int h = lane >> 3, j = lane & 7;
    const int beg = row_ptr[node], end = row_ptr[node + 1];
    const float er_n = er[node * 8 + h];

    // pass 1: per-head max (8 lanes per head each take every 8th edge)
    float m = -INFINITY;
    for (int k = beg + j; k < end; k += 8) {
        int s = esrc[k];
        float v = el[s * 8 + h] + er_n;
        v = (v > 0.f) ? v : NEG_SLOPE * v;
        m = fmaxf(m, v);
    }
    m = fmaxf(m, __shfl_xor(m, 1));
    m = fmaxf(m, __shfl_xor(m, 2));
    m = fmaxf(m, __shfl_xor(m, 4));

    // pass 2: accumulate z*feat[src] and denom
    float denom = 0.f;
    float4 a0 = {0.f, 0.f, 0.f, 0.f}, a1 = {0.f, 0.f, 0.f, 0.f};
    for (int k = beg; k < end; ++k) {
        int s = esrc[k];
        float v = el[s * 8 + h] + er_n;
        v = (v > 0.f) ? v : NEG_SLOPE * v;
        float z = __expf(v - m);
        denom += z;
        const float4* f = (const float4*)(feat + (size_t)s * 512 + lane * 8);
        float4 f0 = f[0], f1 = f[1];
        a0.x = fmaf(z, f0.x, a0.x); a0.y = fmaf(z, f0.y, a0.y);
        a0.z = fmaf(z, f0.z, a0.z); a0.w = fmaf(z, f0.w, a0.w);
        a1.x = fmaf(z, f1.x, a1.x); a1.y = fmaf(z, f1.y, a1.y);
        a1.z = fmaf(z, f1.z, a1.z); a1.w = fmaf(z, f1.w, a1.w);
    }
    float inv = (end > beg) ? 1.f / denom : 0.f;
    const float4* bb = (const float4*)(gat_bias + lane * 8);
    float4 b0 = bb[0], b1 = bb[1];
    float4 o0, o1;
    o0.x = fmaf(a0.x, inv, b0.x); o0.y = fmaf(a0.y, inv, b0.y);
    o0.z = fmaf(a0.z, inv, b0.z); o0.w = fmaf(a0.w, inv, b0.w);
    o1.x = fmaf(a1.x, inv, b1.x); o1.y = fmaf(a1.y, inv, b1.y);
    o1.z = fmaf(a1.z, inv, b1.z); o1.w = fmaf(a1.w, inv, b1.w);
    float4* op = (float4*)(hout + (size_t)node * 512 + lane * 8);
    op[0] = o0; op[1] = o1;
}

// ---------------- inits / conversions ----------------
__global__ void init_out_bias(float* __restrict__ o, const float* __restrict__ b, int total) {
    int idx = blockIdx.x * 256 + threadIdx.x;
    if (idx < total) o[idx] = b[idx & 63];
}
__global__ void cvt_f32_bf16(const float* __restrict__ s, unsigned short* __restrict__ d, int n) {
    int i = blockIdx.x * 256 + threadIdx.x;
    if (i < n) d[i] = f2bf(s[i]);
}

// ---------------- batchnorm ----------------
// C=512: 256 blocks grid-stride rows; thread covers cols tid and tid+256.
__global__ __launch_bounds__(256)
void bn_stats512(const float* __restrict__ X, int M, float* __restrict__ sums)
{
    int c0 = threadIdx.x, c1 = threadIdx.x + 256;
    float s0 = 0.f, q0 = 0.f, s1 = 0.f, q1 = 0.f;
    for (int r = blockIdx.x; r < M; r += gridDim.x) {
        float v0 = X[(size_t)r * 512 + c0];
        float v1 = X[(size_t)r * 512 + c1];
        s0 += v0; q0 += v0 * v0;
        s1 += v1; q1 += v1 * v1;
    }
    atomicAdd(&sums[c0], s0);
    atomicAdd(&sums[512 + c0], q0);
    atomicAdd(&sums[c1], s1);
    atomicAdd(&sums[512 + c1], q1);
}
// C=64: block processes 4 rows/iter; LDS-reduce the 4 row-groups then 64 atomics.
__global__ __launch_bounds__(256)
void bn_stats64(const float* __restrict__ X, int M, float* __restrict__ sums)
{
    __shared__ float ls[256], lq[256];
    int c = threadIdx.x & 63, g = threadIdx.x >> 6;
    float s = 0.f, q = 0.f;
    for (int r = blockIdx.x * 4 + g; r < M; r += gridDim.x * 4) {
        float v = X[(size_t)r * 64 + c];
        s += v; q += v * v;
    }
    ls[threadIdx.x] = s; lq[threadIdx.x] = q;
    __syncthreads();
    if (g == 0) {
        s = ls[c] + ls[64 + c] + ls[128 + c] + ls[192 + c];
        q = lq[c] + lq[64 + c] + lq[128 + c] + lq[192 + c];
        atomicAdd(&sums[c], s);
        atomicAdd(&sums[64 + c], q);
    }
}

__global__ void bn_finalize(const float* __restrict__ sums, const float* __restrict__ gamma,
                            const float* __restrict__ beta, float* __restrict__ ab,
                            int C, float invM)
{
    int c = blockIdx.x * blockDim.x + threadIdx.x;
    if (c >= C) return;
    float mu = sums[c] * invM;
    float var = sums[C + c] * invM - mu * mu;
    float a = gamma[c] * rsqrtf(var + BN_EPS);
    ab[c] = a;
    ab[C + c] = beta[c] - a * mu;
}

__global__ __launch_bounds__(256)
void bn_apply64(float* __restrict__ X, const float* __restrict__ ab, int total)
{
    int idx = blockIdx.x * 256 + threadIdx.x;
    if (idx >= total) return;
    int c = idx & 63;
    X[idx] = fmaf(ab[c], X[idx], ab[64 + c]);
}

extern "C" void kernel_launch(void* const* d_in, const int* in_sizes, int n_in,
                              void* d_out, int out_size, void* d_ws, size_t ws_size,
                              hipStream_t stream)
{
    const float* x         = (const float*)d_in[0];
    const int*   src       = (const int*)d_in[1];
    const int*   dst       = (const int*)d_in[2];
    const float* fc_w      = (const float*)d_in[3];
    const float* attn_l    = (const float*)d_in[4];
    const float* attn_r    = (const float*)d_in[5];
    const float* gat_bias  = (const float*)d_in[6];
    const float* bn1_gamma = (const float*)d_in[7];
    const float* bn1_beta  = (const float*)d_in[8];
    const float* w1        = (const float*)d_in[9];
    const float* b1        = (const float*)d_in[10];
    const float* w2        = (const float*)d_in[11];
    const float* b2        = (const float*)d_in[12];
    const float* bn2_gamma = (const float*)d_in[13];
    const float* bn2_beta  = (const float*)d_in[14];
    float* out = (float*)d_out;

    const int D = 64, HD = 512, HID = 1024;
    const int N = in_sizes[0] / D;   // 50000
    const int E = in_sizes[1];       // 400000
    const int NH = N * 8;
    const int NB = (N + 255) / 256;  // scan blocks (196)

    size_t off = 0;
    auto alloc = [&](size_t bytes) -> void* {
        void* p = (char*)d_ws + off;
        off += (bytes + 255) & ~(size_t)255;
        return p;
    };
    // Region A: feat fp32 [N,512] (dead after gat_aggregate), reused as h1 bf16 [N,1024]
    void* regionA = alloc((size_t)N * HD * 4);
    float* feat = (float*)regionA;
    unsigned short* h1 = (unsigned short*)regionA;
    float* hbuf  = (float*)alloc((size_t)N * HD * 4);
    float* el    = (float*)alloc((size_t)NH * 4);
    float* er    = (float*)alloc((size_t)NH * 4);
    int* counts  = (int*)alloc((size_t)N * 4);
    int* incl    = (int*)alloc((size_t)N * 4);
    int* row_ptr = (int*)alloc((size_t)(N + 1) * 4);
    int* cursor  = (int*)alloc((size_t)N * 4);
    int* bsum    = (int*)alloc(256 * 4);
    int* esrc    = (int*)alloc((size_t)E * 4);
    unsigned short* w1bf = (unsigned short*)alloc((size_t)HID * HD * 2);
    unsigned short* w2bf = (unsigned short*)alloc((size_t)D * HID * 2);
    float* sums1 = (float*)alloc(2 * 512 * 4);
    float* ab1   = (float*)alloc(2 * 512 * 4);
    float* sums2 = (float*)alloc(2 * 64 * 4);
    float* ab2   = (float*)alloc(2 * 64 * 4);
    (void)ws_size; (void)n_in; (void)out_size;

    // ---- CSR build (independent of GEMM1) ----
    hipMemsetAsync(counts, 0, (size_t)N * 4, stream);
    hist_kernel<<<(E + 255) / 256, 256, 0, stream>>>(dst, counts, E);
    scan1<<<NB, 256, 0, stream>>>(counts, incl, bsum, N);
    scan2<<<1, 256, 0, stream>>>(bsum, NB);
    scan3<<<NB, 256, 0, stream>>>(incl, bsum, row_ptr, N);
    hipMemcpyAsync(cursor, row_ptr, (size_t)N * 4, hipMemcpyDeviceToDevice, stream);
    scatter_edges<<<(E + 255) / 256, 256, 0, stream>>>(src, dst, cursor, esrc, E);

    // ---- weight conversions ----
    cvt_f32_bf16<<<(HID * HD + 255) / 256, 256, 0, stream>>>(w1, w1bf, HID * HD);
    cvt_f32_bf16<<<(D * HID + 255) / 256, 256, 0, stream>>>(w2, w2bf, D * HID);

    // ---- GEMM1: feat = x @ fc_w^T ----
    {
        dim3 grid((N + 63) / 64, HD / 64);
        gemm_tn<<<grid, 256, 0, stream>>>(x, fc_w, feat, N, HD, D);
    }
    el_er_kernel<<<(NH + 255) / 256, 256, 0, stream>>>(feat, attn_l, attn_r, el, er, NH);

    // ---- fused GAT softmax + aggregate ----
    gat_aggregate<<<(N + 3) / 4, 256, 0, stream>>>(row_ptr, esrc, el, er, feat,
                                                   gat_bias, hbuf, N);

    // ---- BN1 stats (applied inside GEMM2 A-stage) ----
    hipMemsetAsync(sums1, 0, 2 * 512 * 4, stream);
    bn_stats512<<<256, 256, 0, stream>>>(hbuf, N, sums1);
    bn_finalize<<<2, 256, 0, stream>>>(sums1, bn1_gamma, bn1_beta, ab1, HD, 1.f / N);

    // ---- GEMM2 (MFMA): h1 = relu(bn1(hbuf) @ w1bf^T + b1) -> bf16 (into regionA) ----
    {
        int nwg = ((N + 127) / 128) * (HID / 128);  // 3128
        gemm2_mfma<<<nwg, 256, 0, stream>>>(hbuf, w1bf, h1, N, ab1, b1);
    }

    // ---- GEMM3 (MFMA, split-K): out = h1 @ w2bf^T + b2 ----
    init_out_bias<<<((N * D) + 255) / 256, 256, 0, stream>>>(out, b2, N * D);
    {
        dim3 grid((N + 127) / 128, 4);
        gemm3_mfma<<<grid, 256, 0, stream>>>(h1, w2bf, out, N);
    }

    // ---- BN2 ----
    hipMemsetAsync(sums2, 0, 2 * 64 * 4, stream);
    bn_stats64<<<256, 256, 0, stream>>>(out, N, sums2);
    bn_finalize<<<1, 64, 0, stream>>>(sums2, bn2_gamma, bn2_beta, ab2, D, 1.f / N);
    bn_apply64<<<((N * D) + 255) / 256, 256, 0, stream>>>(out, ab2, N * D);
}

// Round 6
// 478.841 us; speedup vs baseline: 4.1702x; 1.3572x over previous
//
#include <hip/hip_runtime.h>

#define NEG_SLOPE 0.2f
#define BN_EPS 1e-5f

typedef __bf16 bf16x8 __attribute__((ext_vector_type(8)));
typedef float  f32x4  __attribute__((ext_vector_type(4)));
typedef unsigned short ushort8_t __attribute__((ext_vector_type(8)));

__device__ __forceinline__ unsigned short f2bf(float f) {  // RNE f32->bf16
    unsigned int u = __float_as_uint(f);
    unsigned int r = u + 0x7FFFu + ((u >> 16) & 1u);
    return (unsigned short)(r >> 16);
}
__device__ __forceinline__ float bf2f(unsigned short u) {
    return __uint_as_float(((unsigned int)u) << 16);
}
__device__ __forceinline__ void gload16(const void* g, void* l) {
    __builtin_amdgcn_global_load_lds(
        (const __attribute__((address_space(1))) unsigned int*)g,
        (__attribute__((address_space(3))) unsigned int*)l, 16, 0, 0);
}

// ---------------- GEMM1 (MFMA): feat_bf16[M,512] = x_bf @ fc_w_bf^T, K=64 ----
__global__ __launch_bounds__(256)
void gemm1_mfma(const unsigned short* __restrict__ Ax, const unsigned short* __restrict__ Bw,
                unsigned short* __restrict__ C, int M)
{
    __shared__ alignas(16) char Asm[128 * 64 * 2];
    __shared__ alignas(16) char Bsm[128 * 64 * 2];
    const int tid = threadIdx.x, lane = tid & 63, wave = tid >> 6;
    const int wr = wave >> 1, wc = wave & 1;
    const int bm = blockIdx.x * 128, bn = blockIdx.y * 128;
    const int lr = lane >> 3, lk = ((lane & 7) ^ (lane >> 3)) * 8; // inverse-swizzled src col

    #pragma unroll
    for (int it = 0; it < 4; ++it) {
        int seg = wave * 4 + it;
        gload16(Ax + (size_t)(bm + seg * 8 + lr) * 64 + lk, Asm + seg * 1024);
        gload16(Bw + (size_t)(bn + seg * 8 + lr) * 64 + lk, Bsm + seg * 1024);
    }
    __syncthreads();

    f32x4 acc[4][4] = {};
    #pragma unroll
    for (int kk = 0; kk < 2; ++kk) {
        int kg = kk * 4 + (lane >> 4);
        bf16x8 a[4], b[4];
        #pragma unroll
        for (int i = 0; i < 4; ++i) {
            int row = wr * 64 + i * 16 + (lane & 15);
            a[i] = *(const bf16x8*)(Asm + row * 128 + ((kg ^ (row & 7)) << 4));
        }
        #pragma unroll
        for (int j = 0; j < 4; ++j) {
            int row = wc * 64 + j * 16 + (lane & 15);
            b[j] = *(const bf16x8*)(Bsm + row * 128 + ((kg ^ (row & 7)) << 4));
        }
        #pragma unroll
        for (int i = 0; i < 4; ++i)
            #pragma unroll
            for (int j = 0; j < 4; ++j)
                acc[i][j] = __builtin_amdgcn_mfma_f32_16x16x32_bf16(a[i], b[j], acc[i][j], 0, 0, 0);
    }
    #pragma unroll
    for (int j = 0; j < 4; ++j) {
        int gn = bn + wc * 64 + j * 16 + (lane & 15);
        #pragma unroll
        for (int i = 0; i < 4; ++i)
            #pragma unroll
            for (int r = 0; r < 4; ++r) {
                int gm = bm + wr * 64 + i * 16 + (lane >> 4) * 4 + r;
                if (gm < M) C[(size_t)gm * 512 + gn] = f2bf(acc[i][j][r]);
            }
    }
}

// ---------------- GEMM2 (MFMA, pure bf16): h1[M,1024] = relu(hbf @ w1p^T + b1p) ----
__global__ __launch_bounds__(256)
void gemm2_mfma(const unsigned short* __restrict__ A, const unsigned short* __restrict__ B,
                unsigned short* __restrict__ C, int M, const float* __restrict__ b1p)
{
    __shared__ alignas(16) char Asm[128 * 64 * 2];
    __shared__ alignas(16) char Bsm[128 * 64 * 2];
    const int tid = threadIdx.x, lane = tid & 63, wave = tid >> 6;
    const int wr = wave >> 1, wc = wave & 1;
    const int lr = lane >> 3, lk = ((lane & 7) ^ (lane >> 3)) * 8;

    int bid = blockIdx.x;
    int wgid = (bid & 7) * 391 + (bid >> 3);   // nwg = 3128 = 8*391, bijective
    const int bm = (wgid >> 3) * 128;
    const int bn = (wgid & 7) * 128;

    f32x4 acc[4][4] = {};
    for (int k0 = 0; k0 < 512; k0 += 64) {
        __syncthreads();
        #pragma unroll
        for (int it = 0; it < 4; ++it) {
            int seg = wave * 4 + it;
            gload16(A + (size_t)(bm + seg * 8 + lr) * 512 + k0 + lk, Asm + seg * 1024);
            gload16(B + (size_t)(bn + seg * 8 + lr) * 512 + k0 + lk, Bsm + seg * 1024);
        }
        __syncthreads();
        #pragma unroll
        for (int kk = 0; kk < 2; ++kk) {
            int kg = kk * 4 + (lane >> 4);
            bf16x8 a[4], b[4];
            #pragma unroll
            for (int i = 0; i < 4; ++i) {
                int row = wr * 64 + i * 16 + (lane & 15);
                a[i] = *(const bf16x8*)(Asm + row * 128 + ((kg ^ (row & 7)) << 4));
            }
            #pragma unroll
            for (int j = 0; j < 4; ++j) {
                int row = wc * 64 + j * 16 + (lane & 15);
                b[j] = *(const bf16x8*)(Bsm + row * 128 + ((kg ^ (row & 7)) << 4));
            }
            #pragma unroll
            for (int i = 0; i < 4; ++i)
                #pragma unroll
                for (int j = 0; j < 4; ++j)
                    acc[i][j] = __builtin_amdgcn_mfma_f32_16x16x32_bf16(a[i], b[j], acc[i][j], 0, 0, 0);
        }
    }
    #pragma unroll
    for (int j = 0; j < 4; ++j) {
        int gn = bn + wc * 64 + j * 16 + (lane & 15);
        float bs = b1p[gn];
        #pragma unroll
        for (int i = 0; i < 4; ++i)
            #pragma unroll
            for (int r = 0; r < 4; ++r) {
                int gm = bm + wr * 64 + i * 16 + (lane >> 4) * 4 + r;
                if (gm < M) C[(size_t)gm * 1024 + gn] = f2bf(fmaxf(acc[i][j][r] + bs, 0.f));
            }
    }
}

// ---------------- GEMM3 (MFMA, split-K): out += h1_bf16 @ w2bf^T ----------------
__global__ __launch_bounds__(256)
void gemm3_mfma(const unsigned short* __restrict__ A, const unsigned short* __restrict__ Bw,
                float* __restrict__ Cout, int M)
{
    __shared__ alignas(16) char Asm[128 * 64 * 2];
    __shared__ alignas(16) char Bsm[64 * 64 * 2];
    const int tid = threadIdx.x;
    const int lane = tid & 63;
    const int wave = tid >> 6;
    const int wr = wave >> 1, wc = wave & 1;
    const int bm = blockIdx.x * 128;
    const int kbase = blockIdx.y * 256;

    f32x4 acc[4][2] = {};

    for (int k0 = kbase; k0 < kbase + 256; k0 += 64) {
        __syncthreads();
        #pragma unroll
        for (int it = 0; it < 4; ++it) {
            int seg = wave * 256 + it * 64 + lane;
            int row = seg >> 3, sub = seg & 7;
            int gm = bm + row;
            uint4 w = {0u, 0u, 0u, 0u};
            if (gm < M) w = *(const uint4*)&A[(size_t)gm * 1024 + k0 + sub * 8];
            *(uint4*)(Asm + row * 128 + ((sub ^ (row & 7)) << 4)) = w;
        }
        #pragma unroll
        for (int it = 0; it < 2; ++it) {
            int seg = it * 256 + tid;
            int row = seg >> 3, sub = seg & 7;
            uint4 w = *(const uint4*)&Bw[(size_t)row * 1024 + k0 + sub * 8];
            *(uint4*)(Bsm + row * 128 + ((sub ^ (row & 7)) << 4)) = w;
        }
        __syncthreads();
        #pragma unroll
        for (int kk = 0; kk < 2; ++kk) {
            int kg = kk * 4 + (lane >> 4);
            bf16x8 a[4], b[2];
            #pragma unroll
            for (int i = 0; i < 4; ++i) {
                int row = wr * 64 + i * 16 + (lane & 15);
                a[i] = *(const bf16x8*)(Asm + row * 128 + ((kg ^ (row & 7)) << 4));
            }
            #pragma unroll
            for (int j = 0; j < 2; ++j) {
                int row = wc * 32 + j * 16 + (lane & 15);
                b[j] = *(const bf16x8*)(Bsm + row * 128 + ((kg ^ (row & 7)) << 4));
            }
            #pragma unroll
            for (int i = 0; i < 4; ++i)
                #pragma unroll
                for (int j = 0; j < 2; ++j)
                    acc[i][j] = __builtin_amdgcn_mfma_f32_16x16x32_bf16(a[i], b[j], acc[i][j], 0, 0, 0);
        }
    }
    #pragma unroll
    for (int i = 0; i < 4; ++i)
        #pragma unroll
        for (int j = 0; j < 2; ++j)
            #pragma unroll
            for (int r = 0; r < 4; ++r) {
                int gm = bm + wr * 64 + i * 16 + (lane >> 4) * 4 + r;
                int gn = wc * 32 + j * 16 + (lane & 15);
                if (gm < M) atomicAdd(&Cout[(size_t)gm * 64 + gn], acc[i][j][r]);
            }
}

// ---------------- attention logits el/er (bf16 feat) ----------------
__global__ __launch_bounds__(256)
void el_er_kernel(const unsigned short* __restrict__ feat,
                  const float* __restrict__ attn_l, const float* __restrict__ attn_r,
                  float* __restrict__ el, float* __restrict__ er, int NH)
{
    int idx = blockIdx.x * 256 + threadIdx.x;
    if (idx >= NH) return;
    int h = idx & 7;
    const ushort8_t* f = (const ushort8_t*)(feat + (size_t)idx * 64);
    const float* al = attn_l + h * 64;
    const float* ar = attn_r + h * 64;
    float sl = 0.f, sr = 0.f;
    #pragma unroll
    for (int i = 0; i < 8; ++i) {
        ushort8_t v = f[i];
        #pragma unroll
        for (int t = 0; t < 8; ++t) {
            float fv = bf2f(v[t]);
            sl = fmaf(fv, al[i * 8 + t], sl);
            sr = fmaf(fv, ar[i * 8 + t], sr);
        }
    }
    el[idx] = sl;
    er[idx] = sr;
}

// ---------------- CSR build ----------------
__global__ void hist_kernel(const int* __restrict__ dst, int* __restrict__ counts, int E) {
    int i = blockIdx.x * 256 + threadIdx.x;
    if (i < E) atomicAdd(&counts[dst[i]], 1);
}
__global__ void scan1(const int* __restrict__ counts, int* __restrict__ incl,
                      int* __restrict__ bsum, int N) {
    __shared__ int sm[256];
    int i = blockIdx.x * 256 + threadIdx.x;
    int v = (i < N) ? counts[i] : 0;
    sm[threadIdx.x] = v;
    __syncthreads();
    #pragma unroll
    for (int d = 1; d < 256; d <<= 1) {
        int t = (threadIdx.x >= d) ? sm[threadIdx.x - d] : 0;
        __syncthreads();
        sm[threadIdx.x] += t;
        __syncthreads();
    }
    if (i < N) incl[i] = sm[threadIdx.x];
    if (threadIdx.x == 255) bsum[blockIdx.x] = sm[255];
}
__global__ void scan2(int* __restrict__ bsum, int nb) {
    __shared__ int sm[256];
    int v = (threadIdx.x < nb) ? bsum[threadIdx.x] : 0;
    sm[threadIdx.x] = v;
    __syncthreads();
    #pragma unroll
    for (int d = 1; d < 256; d <<= 1) {
        int t = (threadIdx.x >= d) ? sm[threadIdx.x - d] : 0;
        __syncthreads();
        sm[threadIdx.x] += t;
        __syncthreads();
    }
    if (threadIdx.x < nb) bsum[threadIdx.x] = sm[threadIdx.x] - v;
}
__global__ void scan3(const int* __restrict__ incl, const int* __restrict__ bsum,
                      int* __restrict__ row_ptr, int N) {
    int i = blockIdx.x * 256 + threadIdx.x;
    if (i < N) row_ptr[i + 1] = incl[i] + bsum[blockIdx.x];
    if (i == 0) row_ptr[0] = 0;
}
__global__ void scatter_edges(const int* __restrict__ src, const int* __restrict__ dst,
                              int* __restrict__ cursor, int* __restrict__ esrc, int E) {
    int e = blockIdx.x * 256 + threadIdx.x;
    if (e < E) {
        int p = atomicAdd(&cursor[dst[e]], 1);
        esrc[p] = src[e];
    }
}

// ---------------- fused GAT: softmax + weighted aggregate -> bf16 h ----------------
__global__ __launch_bounds__(256)
void gat_aggregate(const int* __restrict__ row_ptr, const int* __restrict__ esrc,
                   const float* __restrict__ el, const float* __restrict__ er,
                   const unsigned short* __restrict__ feat, const float* __restrict__ gat_bias,
                   unsigned short* __restrict__ hout, int N)
{
    int node = blockIdx.x * 4 + (threadIdx.x >> 6);
    if (node >= N) return;
    const int lane = threadIdx.x & 63;
    const int h = lane >> 3, j = lane & 7;
    const int beg = row_ptr[node], end = row_ptr[node + 1];
    const float er_n = er[node * 8 + h];

    float m = -INFINITY;
    for (int k = beg + j; k < end; k += 8) {
        int s = esrc[k];
        float v = el[s * 8 + h] + er_n;
        v = (v > 0.f) ? v : NEG_SLOPE * v;
        m = fmaxf(m, v);
    }
    m = fmaxf(m, __shfl_xor(m, 1));
    m = fmaxf(m, __shfl_xor(m, 2));
    m = fmaxf(m, __shfl_xor(m, 4));

    float denom = 0.f;
    float a[8] = {};
    for (int k = beg; k < end; ++k) {
        int s = esrc[k];
        float v = el[s * 8 + h] + er_n;
        v = (v > 0.f) ? v : NEG_SLOPE * v;
        float z = __expf(v - m);
        denom += z;
        ushort8_t fv = *(const ushort8_t*)(feat + (size_t)s * 512 + lane * 8);
        #pragma unroll
        for (int t = 0; t < 8; ++t) a[t] = fmaf(z, bf2f(fv[t]), a[t]);
    }
    float inv = (end > beg) ? 1.f / denom : 0.f;
    ushort8_t o;
    #pragma unroll
    for (int t = 0; t < 8; ++t) o[t] = f2bf(fmaf(a[t], inv, gat_bias[lane * 8 + t]));
    *(ushort8_t*)(hout + (size_t)node * 512 + lane * 8) = o;
}

// ---------------- BN1 stats over bf16 h ----------------
__global__ __launch_bounds__(256)
void bn_stats512bf(const unsigned short* __restrict__ X, int M, float* __restrict__ sums)
{
    __shared__ float red[4][512];
    int cg = threadIdx.x & 63, rg = threadIdx.x >> 6;
    float s[8] = {}, q[8] = {};
    for (int r = blockIdx.x * 4 + rg; r < M; r += gridDim.x * 4) {
        ushort8_t v = *(const ushort8_t*)(X + (size_t)r * 512 + cg * 8);
        #pragma unroll
        for (int t = 0; t < 8; ++t) { float f = bf2f(v[t]); s[t] += f; q[t] += f * f; }
    }
    #pragma unroll
    for (int t = 0; t < 8; ++t) red[rg][cg * 8 + t] = s[t];
    __syncthreads();
    if (rg == 0)
        #pragma unroll
        for (int t = 0; t < 8; ++t) {
            int c = cg * 8 + t;
            atomicAdd(&sums[c], red[0][c] + red[1][c] + red[2][c] + red[3][c]);
        }
    __syncthreads();
    #pragma unroll
    for (int t = 0; t < 8; ++t) red[rg][cg * 8 + t] = q[t];
    __syncthreads();
    if (rg == 0)
        #pragma unroll
        for (int t = 0; t < 8; ++t) {
            int c = cg * 8 + t;
            atomicAdd(&sums[512 + c], red[0][c] + red[1][c] + red[2][c] + red[3][c]);
        }
}

// ---------------- fold BN1 into w1: w1p = bf16(w1*a), b1p = b1 + w1@b ----------------
__global__ __launch_bounds__(256)
void fold_w1(const float* __restrict__ w1, const float* __restrict__ ab1,
             const float* __restrict__ b1, unsigned short* __restrict__ w1p,
             float* __restrict__ b1p)
{
    int n = blockIdx.x * 4 + (threadIdx.x >> 6);
    int lane = threadIdx.x & 63;
    const float* wrow = w1 + (size_t)n * 512 + lane * 8;
    float p = 0.f;
    ushort8_t o;
    #pragma unroll
    for (int t = 0; t < 8; ++t) {
        float w = wrow[t];
        o[t] = f2bf(w * ab1[lane * 8 + t]);
        p = fmaf(w, ab1[512 + lane * 8 + t], p);
    }
    *(ushort8_t*)(w1p + (size_t)n * 512 + lane * 8) = o;
    #pragma unroll
    for (int d = 1; d < 64; d <<= 1) p += __shfl_xor(p, d);
    if (lane == 0) b1p[n] = b1[n] + p;
}

// ---------------- misc ----------------
__global__ void init_out_bias(float* __restrict__ o, const float* __restrict__ b, int total) {
    int idx = blockIdx.x * 256 + threadIdx.x;
    if (idx < total) o[idx] = b[idx & 63];
}
__global__ void cvt_f32_bf16(const float* __restrict__ s, unsigned short* __restrict__ d, int n) {
    int i = blockIdx.x * 256 + threadIdx.x;
    if (i < n) d[i] = f2bf(s[i]);
}

__global__ __launch_bounds__(256)
void bn_stats64(const float* __restrict__ X, int M, float* __restrict__ sums)
{
    __shared__ float ls[256], lq[256];
    int c = threadIdx.x & 63, g = threadIdx.x >> 6;
    float s = 0.f, q = 0.f;
    for (int r = blockIdx.x * 4 + g; r < M; r += gridDim.x * 4) {
        float v = X[(size_t)r * 64 + c];
        s += v; q += v * v;
    }
    ls[threadIdx.x] = s; lq[threadIdx.x] = q;
    __syncthreads();
    if (g == 0) {
        s = ls[c] + ls[64 + c] + ls[128 + c] + ls[192 + c];
        q = lq[c] + lq[64 + c] + lq[128 + c] + lq[192 + c];
        atomicAdd(&sums[c], s);
        atomicAdd(&sums[64 + c], q);
    }
}

__global__ void bn_finalize(const float* __restrict__ sums, const float* __restrict__ gamma,
                            const float* __restrict__ beta, float* __restrict__ ab,
                            int C, float invM)
{
    int c = blockIdx.x * blockDim.x + threadIdx.x;
    if (c >= C) return;
    float mu = sums[c] * invM;
    float var = sums[C + c] * invM - mu * mu;
    float a = gamma[c] * rsqrtf(var + BN_EPS);
    ab[c] = a;
    ab[C + c] = beta[c] - a * mu;
}

__global__ __launch_bounds__(256)
void bn_apply64(float* __restrict__ X, const float* __restrict__ ab, int total)
{
    int idx = blockIdx.x * 256 + threadIdx.x;
    if (idx >= total) return;
    int c = idx & 63;
    X[idx] = fmaf(ab[c], X[idx], ab[64 + c]);
}

extern "C" void kernel_launch(void* const* d_in, const int* in_sizes, int n_in,
                              void* d_out, int out_size, void* d_ws, size_t ws_size,
                              hipStream_t stream)
{
    const float* x         = (const float*)d_in[0];
    const int*   src       = (const int*)d_in[1];
    const int*   dst       = (const int*)d_in[2];
    const float* fc_w      = (const float*)d_in[3];
    const float* attn_l    = (const float*)d_in[4];
    const float* attn_r    = (const float*)d_in[5];
    const float* gat_bias  = (const float*)d_in[6];
    const float* bn1_gamma = (const float*)d_in[7];
    const float* bn1_beta  = (const float*)d_in[8];
    const float* b1        = (const float*)d_in[10];
    const float* w1        = (const float*)d_in[9];
    const float* w2        = (const float*)d_in[11];
    const float* b2        = (const float*)d_in[12];
    const float* bn2_gamma = (const float*)d_in[13];
    const float* bn2_beta  = (const float*)d_in[14];
    float* out = (float*)d_out;

    const int D = 64, HD = 512, HID = 1024;
    const int N = in_sizes[0] / D;      // 50000
    const int E = in_sizes[1];          // 400000
    const int NH = N * 8;
    const int NB = (N + 255) / 256;
    const int Mpad = ((N + 127) / 128) * 128 + 128;  // 50176: safe for unguarded gload_lds

    size_t off = 0;
    auto alloc = [&](size_t bytes) -> void* {
        void* p = (char*)d_ws + off;
        off += (bytes + 255) & ~(size_t)255;
        return p;
    };
    // Region A: feat bf16 [N,512] (dead after gat_aggregate), reused as h1 bf16 [N,1024]
    void* regionA = alloc((size_t)N * HID * 2);
    unsigned short* feat = (unsigned short*)regionA;
    unsigned short* h1   = (unsigned short*)regionA;
    unsigned short* hbf  = (unsigned short*)alloc((size_t)Mpad * HD * 2);
    unsigned short* xbf  = (unsigned short*)alloc((size_t)Mpad * D * 2);
    unsigned short* fcwbf = (unsigned short*)alloc((size_t)HD * D * 2);
    unsigned short* w1p  = (unsigned short*)alloc((size_t)HID * HD * 2);
    unsigned short* w2bf = (unsigned short*)alloc((size_t)D * HID * 2);
    float* b1p   = (float*)alloc(HID * 4);
    float* el    = (float*)alloc((size_t)NH * 4);
    float* er    = (float*)alloc((size_t)NH * 4);
    int* counts  = (int*)alloc((size_t)N * 4);
    int* incl    = (int*)alloc((size_t)N * 4);
    int* row_ptr = (int*)alloc((size_t)(N + 1) * 4);
    int* cursor  = (int*)alloc((size_t)N * 4);
    int* bsum    = (int*)alloc(256 * 4);
    int* esrc    = (int*)alloc((size_t)E * 4);
    float* sums1 = (float*)alloc(2 * 512 * 4);
    float* ab1   = (float*)alloc(2 * 512 * 4);
    float* sums2 = (float*)alloc(2 * 64 * 4);
    float* ab2   = (float*)alloc(2 * 64 * 4);
    (void)ws_size; (void)n_in; (void)out_size;

    // ---- CSR build ----
    hipMemsetAsync(counts, 0, (size_t)N * 4, stream);
    hist_kernel<<<(E + 255) / 256, 256, 0, stream>>>(dst, counts, E);
    scan1<<<NB, 256, 0, stream>>>(counts, incl, bsum, N);
    scan2<<<1, 256, 0, stream>>>(bsum, NB);
    scan3<<<NB, 256, 0, stream>>>(incl, bsum, row_ptr, N);
    hipMemcpyAsync(cursor, row_ptr, (size_t)N * 4, hipMemcpyDeviceToDevice, stream);
    scatter_edges<<<(E + 255) / 256, 256, 0, stream>>>(src, dst, cursor, esrc, E);

    // ---- conversions ----
    cvt_f32_bf16<<<(N * D + 255) / 256, 256, 0, stream>>>(x, xbf, N * D);
    cvt_f32_bf16<<<(HD * D + 255) / 256, 256, 0, stream>>>(fc_w, fcwbf, HD * D);
    cvt_f32_bf16<<<(D * HID + 255) / 256, 256, 0, stream>>>(w2, w2bf, D * HID);

    // ---- GEMM1 (MFMA): feat = x @ fc_w^T -> bf16 ----
    {
        dim3 grid((N + 127) / 128, HD / 128);   // 391 x 4
        gemm1_mfma<<<grid, 256, 0, stream>>>(xbf, fcwbf, feat, N);
    }
    el_er_kernel<<<(NH + 255) / 256, 256, 0, stream>>>(feat, attn_l, attn_r, el, er, NH);

    // ---- fused GAT softmax + aggregate -> bf16 h ----
    gat_aggregate<<<(N + 3) / 4, 256, 0, stream>>>(row_ptr, esrc, el, er, feat,
                                                   gat_bias, hbf, N);

    // ---- BN1 stats + fold into w1 ----
    hipMemsetAsync(sums1, 0, 2 * 512 * 4, stream);
    bn_stats512bf<<<256, 256, 0, stream>>>(hbf, N, sums1);
    bn_finalize<<<2, 256, 0, stream>>>(sums1, bn1_gamma, bn1_beta, ab1, HD, 1.f / N);
    fold_w1<<<HID / 4, 256, 0, stream>>>(w1, ab1, b1, w1p, b1p);

    // ---- GEMM2 (MFMA pure bf16): h1 = relu(hbf @ w1p^T + b1p) ----
    {
        int nwg = ((N + 127) / 128) * (HID / 128);  // 3128
        gemm2_mfma<<<nwg, 256, 0, stream>>>(hbf, w1p, h1, N, b1p);
    }

    // ---- GEMM3 (MFMA, split-K): out = h1 @ w2bf^T + b2 ----
    init_out_bias<<<((N * D) + 255) / 256, 256, 0, stream>>>(out, b2, N * D);
    {
        dim3 grid((N + 127) / 128, 4);
        gemm3_mfma<<<grid, 256, 0, stream>>>(h1, w2bf, out, N);
    }

    // ---- BN2 ----
    hipMemsetAsync(sums2, 0, 2 * 64 * 4, stream);
    bn_stats64<<<256, 256, 0, stream>>>(out, N, sums2);
    bn_finalize<<<1, 64, 0, stream>>>(sums2, bn2_gamma, bn2_beta, ab2, D, 1.f / N);
    bn_apply64<<<((N * D) + 255) / 256, 256, 0, stream>>>(out, ab2, N * D);
}

// Round 7
// 401.869 us; speedup vs baseline: 4.9689x; 1.1915x over previous
//
#include <hip/hip_runtime.h>

#define NEG_SLOPE 0.2f
#define BN_EPS 1e-5f

typedef __bf16 bf16x8 __attribute__((ext_vector_type(8)));
typedef float  f32x4  __attribute__((ext_vector_type(4)));
typedef unsigned short ushort8_t __attribute__((ext_vector_type(8)));

__device__ __forceinline__ unsigned short f2bf(float f) {  // RNE f32->bf16
    unsigned int u = __float_as_uint(f);
    unsigned int r = u + 0x7FFFu + ((u >> 16) & 1u);
    return (unsigned short)(r >> 16);
}
__device__ __forceinline__ float bf2f(unsigned short u) {
    return __uint_as_float(((unsigned int)u) << 16);
}
__device__ __forceinline__ void gload16(const void* g, void* l) {
    __builtin_amdgcn_global_load_lds(
        (const __attribute__((address_space(1))) unsigned int*)g,
        (__attribute__((address_space(3))) unsigned int*)l, 16, 0, 0);
}

// ---------------- GEMM1 (MFMA): feat_bf16[M,512] = x_bf @ fc_w_bf^T, K=64 ----
// Fused epilogue: el[n,h], er[n,h] from fp32 accumulators (each wave owns 64 rows x 1 head).
__global__ __launch_bounds__(256)
void gemm1_mfma(const unsigned short* __restrict__ Ax, const unsigned short* __restrict__ Bw,
                unsigned short* __restrict__ C,
                const float* __restrict__ attn_l, const float* __restrict__ attn_r,
                float* __restrict__ el, float* __restrict__ er, int M)
{
    __shared__ alignas(16) char Asm[128 * 64 * 2];
    __shared__ alignas(16) char Bsm[128 * 64 * 2];
    const int tid = threadIdx.x, lane = tid & 63, wave = tid >> 6;
    const int wr = wave >> 1, wc = wave & 1;
    const int bm = blockIdx.x * 128, bn = blockIdx.y * 128;
    const int lr = lane >> 3, lk = ((lane & 7) ^ (lane >> 3)) * 8; // inverse-swizzled src col

    #pragma unroll
    for (int it = 0; it < 4; ++it) {
        int seg = wave * 4 + it;
        gload16(Ax + (size_t)(bm + seg * 8 + lr) * 64 + lk, Asm + seg * 1024);
        gload16(Bw + (size_t)(bn + seg * 8 + lr) * 64 + lk, Bsm + seg * 1024);
    }
    __syncthreads();

    f32x4 acc[4][4] = {};
    #pragma unroll
    for (int kk = 0; kk < 2; ++kk) {
        int kg = kk * 4 + (lane >> 4);
        bf16x8 a[4], b[4];
        #pragma unroll
        for (int i = 0; i < 4; ++i) {
            int row = wr * 64 + i * 16 + (lane & 15);
            a[i] = *(const bf16x8*)(Asm + row * 128 + ((kg ^ (row & 7)) << 4));
        }
        #pragma unroll
        for (int j = 0; j < 4; ++j) {
            int row = wc * 64 + j * 16 + (lane & 15);
            b[j] = *(const bf16x8*)(Bsm + row * 128 + ((kg ^ (row & 7)) << 4));
        }
        #pragma unroll
        for (int i = 0; i < 4; ++i)
            #pragma unroll
            for (int j = 0; j < 4; ++j)
                acc[i][j] = __builtin_amdgcn_mfma_f32_16x16x32_bf16(a[i], b[j], acc[i][j], 0, 0, 0);
    }

    // feat store
    #pragma unroll
    for (int j = 0; j < 4; ++j) {
        int gn = bn + wc * 64 + j * 16 + (lane & 15);
        #pragma unroll
        for (int i = 0; i < 4; ++i)
            #pragma unroll
            for (int r = 0; r < 4; ++r) {
                int gm = bm + wr * 64 + i * 16 + (lane >> 4) * 4 + r;
                if (gm < M) C[(size_t)gm * 512 + gn] = f2bf(acc[i][j][r]);
            }
    }

    // fused el/er: wave covers head = bn/64 + wc, cols within head = j*16 + (lane&15)
    const int head = (bn >> 6) + wc;
    float al[4], ar[4];
    #pragma unroll
    for (int j = 0; j < 4; ++j) {
        int c = j * 16 + (lane & 15);
        al[j] = attn_l[head * 64 + c];
        ar[j] = attn_r[head * 64 + c];
    }
    #pragma unroll
    for (int i = 0; i < 4; ++i)
        #pragma unroll
        for (int r = 0; r < 4; ++r) {
            int gm = bm + wr * 64 + i * 16 + (lane >> 4) * 4 + r;
            float sl = 0.f, sr = 0.f;
            #pragma unroll
            for (int j = 0; j < 4; ++j) {
                sl = fmaf(acc[i][j][r], al[j], sl);
                sr = fmaf(acc[i][j][r], ar[j], sr);
            }
            sl += __shfl_xor(sl, 1); sr += __shfl_xor(sr, 1);
            sl += __shfl_xor(sl, 2); sr += __shfl_xor(sr, 2);
            sl += __shfl_xor(sl, 4); sr += __shfl_xor(sr, 4);
            sl += __shfl_xor(sl, 8); sr += __shfl_xor(sr, 8);
            if ((lane & 15) == 0 && gm < M) {
                el[gm * 8 + head] = sl;
                er[gm * 8 + head] = sr;
            }
        }
}

// ---------------- GEMM2 (MFMA, bf16, A-dbuf pipeline): h1 = relu(hbf @ w1p^T + b1p) ----
__global__ __launch_bounds__(256)
void gemm2_mfma(const unsigned short* __restrict__ A, const unsigned short* __restrict__ B,
                unsigned short* __restrict__ C, int M, const float* __restrict__ b1p)
{
    __shared__ alignas(16) char Asm[2][128 * 64 * 2];
    __shared__ alignas(16) char Bsm[128 * 64 * 2];
    const int tid = threadIdx.x, lane = tid & 63, wave = tid >> 6;
    const int wr = wave >> 1, wc = wave & 1;
    const int lr = lane >> 3, lk = ((lane & 7) ^ (lane >> 3)) * 8;

    int bid = blockIdx.x;
    int wgid = (bid & 7) * 391 + (bid >> 3);   // nwg = 3128 = 8*391, bijective
    const int bm = (wgid >> 3) * 128;
    const int bn = (wgid & 7) * 128;

    // prologue: stage A tile 0 (4 loads/wave, in flight)
    #pragma unroll
    for (int it = 0; it < 4; ++it) {
        int seg = wave * 4 + it;
        gload16(A + (size_t)(bm + seg * 8 + lr) * 512 + lk, Asm[0] + seg * 1024);
    }

    f32x4 acc[4][4] = {};
    #pragma unroll
    for (int t = 0; t < 8; ++t) {
        const int k0 = t * 64;
        // stage B(t) into single buffer (safe: previous end-barrier passed)
        #pragma unroll
        for (int it = 0; it < 4; ++it) {
            int seg = wave * 4 + it;
            gload16(B + (size_t)(bn + seg * 8 + lr) * 512 + k0 + lk, Bsm + seg * 1024);
        }
        if (t < 7) {
            // stage A(t+1) into the other buffer — stays in flight across the barrier
            #pragma unroll
            for (int it = 0; it < 4; ++it) {
                int seg = wave * 4 + it;
                gload16(A + (size_t)(bm + seg * 8 + lr) * 512 + (k0 + 64) + lk,
                        Asm[(t + 1) & 1] + seg * 1024);
            }
            asm volatile("s_waitcnt vmcnt(4)" ::: "memory"); // A(t)+B(t) done; A(t+1) in flight
        } else {
            asm volatile("s_waitcnt vmcnt(0)" ::: "memory");
        }
        __builtin_amdgcn_s_barrier();
        __builtin_amdgcn_sched_barrier(0);
        const char* Ab = Asm[t & 1];
        #pragma unroll
        for (int kk = 0; kk < 2; ++kk) {
            int kg = kk * 4 + (lane >> 4);
            bf16x8 a[4], b[4];
            #pragma unroll
            for (int i = 0; i < 4; ++i) {
                int row = wr * 64 + i * 16 + (lane & 15);
                a[i] = *(const bf16x8*)(Ab + row * 128 + ((kg ^ (row & 7)) << 4));
            }
            #pragma unroll
            for (int j = 0; j < 4; ++j) {
                int row = wc * 64 + j * 16 + (lane & 15);
                b[j] = *(const bf16x8*)(Bsm + row * 128 + ((kg ^ (row & 7)) << 4));
            }
            #pragma unroll
            for (int i = 0; i < 4; ++i)
                #pragma unroll
                for (int j = 0; j < 4; ++j)
                    acc[i][j] = __builtin_amdgcn_mfma_f32_16x16x32_bf16(a[i], b[j], acc[i][j], 0, 0, 0);
        }
        __builtin_amdgcn_sched_barrier(0);
        __builtin_amdgcn_s_barrier();   // compute done before next iter overwrites Bsm / Asm[t&1]
        __builtin_amdgcn_sched_barrier(0);
    }

    #pragma unroll
    for (int j = 0; j < 4; ++j) {
        int gn = bn + wc * 64 + j * 16 + (lane & 15);
        float bs = b1p[gn];
        #pragma unroll
        for (int i = 0; i < 4; ++i)
            #pragma unroll
            for (int r = 0; r < 4; ++r) {
                int gm = bm + wr * 64 + i * 16 + (lane >> 4) * 4 + r;
                if (gm < M) C[(size_t)gm * 1024 + gn] = f2bf(fmaxf(acc[i][j][r] + bs, 0.f));
            }
    }
}

// ---------------- GEMM3 (MFMA, split-K, partial slices — no atomics) ----------------
__global__ __launch_bounds__(256)
void gemm3_mfma(const unsigned short* __restrict__ A, const unsigned short* __restrict__ Bw,
                float* __restrict__ P, int M)
{
    __shared__ alignas(16) char Asm[128 * 64 * 2];
    __shared__ alignas(16) char Bsm[64 * 64 * 2];
    const int tid = threadIdx.x;
    const int lane = tid & 63;
    const int wave = tid >> 6;
    const int wr = wave >> 1, wc = wave & 1;
    const int bm = blockIdx.x * 128;
    const int kbase = blockIdx.y * 256;
    float* Pout = P + (size_t)blockIdx.y * M * 64;

    f32x4 acc[4][2] = {};

    for (int k0 = kbase; k0 < kbase + 256; k0 += 64) {
        __syncthreads();
        #pragma unroll
        for (int it = 0; it < 4; ++it) {
            int seg = wave * 256 + it * 64 + lane;
            int row = seg >> 3, sub = seg & 7;
            int gm = bm + row;
            uint4 w = {0u, 0u, 0u, 0u};
            if (gm < M) w = *(const uint4*)&A[(size_t)gm * 1024 + k0 + sub * 8];
            *(uint4*)(Asm + row * 128 + ((sub ^ (row & 7)) << 4)) = w;
        }
        #pragma unroll
        for (int it = 0; it < 2; ++it) {
            int seg = it * 256 + tid;
            int row = seg >> 3, sub = seg & 7;
            uint4 w = *(const uint4*)&Bw[(size_t)row * 1024 + k0 + sub * 8];
            *(uint4*)(Bsm + row * 128 + ((sub ^ (row & 7)) << 4)) = w;
        }
        __syncthreads();
        #pragma unroll
        for (int kk = 0; kk < 2; ++kk) {
            int kg = kk * 4 + (lane >> 4);
            bf16x8 a[4], b[2];
            #pragma unroll
            for (int i = 0; i < 4; ++i) {
                int row = wr * 64 + i * 16 + (lane & 15);
                a[i] = *(const bf16x8*)(Asm + row * 128 + ((kg ^ (row & 7)) << 4));
            }
            #pragma unroll
            for (int j = 0; j < 2; ++j) {
                int row = wc * 32 + j * 16 + (lane & 15);
                b[j] = *(const bf16x8*)(Bsm + row * 128 + ((kg ^ (row & 7)) << 4));
            }
            #pragma unroll
            for (int i = 0; i < 4; ++i)
                #pragma unroll
                for (int j = 0; j < 2; ++j)
                    acc[i][j] = __builtin_amdgcn_mfma_f32_16x16x32_bf16(a[i], b[j], acc[i][j], 0, 0, 0);
        }
    }
    #pragma unroll
    for (int i = 0; i < 4; ++i)
        #pragma unroll
        for (int j = 0; j < 2; ++j)
            #pragma unroll
            for (int r = 0; r < 4; ++r) {
                int gm = bm + wr * 64 + i * 16 + (lane >> 4) * 4 + r;
                int gn = wc * 32 + j * 16 + (lane & 15);
                if (gm < M) Pout[(size_t)gm * 64 + gn] = acc[i][j][r];
            }
}

// ---------------- reduce partials + b2 -> out, fused BN2 stats ----------------
__global__ __launch_bounds__(256)
void reduce_bn2(const float* __restrict__ P, const float* __restrict__ b2,
                float* __restrict__ out, int M, float* __restrict__ sums)
{
    __shared__ float ls[256], lq[256];
    int c = threadIdx.x & 63, g = threadIdx.x >> 6;
    const size_t S = (size_t)M * 64;
    float bias = b2[c];
    float s = 0.f, q = 0.f;
    for (int r = blockIdx.x * 4 + g; r < M; r += gridDim.x * 4) {
        size_t idx = (size_t)r * 64 + c;
        float v = P[idx] + P[S + idx] + P[2 * S + idx] + P[3 * S + idx] + bias;
        out[idx] = v;
        s += v; q += v * v;
    }
    ls[threadIdx.x] = s; lq[threadIdx.x] = q;
    __syncthreads();
    if (g == 0) {
        s = ls[c] + ls[64 + c] + ls[128 + c] + ls[192 + c];
        q = lq[c] + lq[64 + c] + lq[128 + c] + lq[192 + c];
        atomicAdd(&sums[c], s);
        atomicAdd(&sums[64 + c], q);
    }
}

// ---------------- CSR build ----------------
__global__ void hist_kernel(const int* __restrict__ dst, int* __restrict__ counts, int E) {
    int i = blockIdx.x * 256 + threadIdx.x;
    if (i < E) atomicAdd(&counts[dst[i]], 1);
}
__global__ void scan1(const int* __restrict__ counts, int* __restrict__ incl,
                      int* __restrict__ bsum, int N) {
    __shared__ int sm[256];
    int i = blockIdx.x * 256 + threadIdx.x;
    int v = (i < N) ? counts[i] : 0;
    sm[threadIdx.x] = v;
    __syncthreads();
    #pragma unroll
    for (int d = 1; d < 256; d <<= 1) {
        int t = (threadIdx.x >= d) ? sm[threadIdx.x - d] : 0;
        __syncthreads();
        sm[threadIdx.x] += t;
        __syncthreads();
    }
    if (i < N) incl[i] = sm[threadIdx.x];
    if (threadIdx.x == 255) bsum[blockIdx.x] = sm[255];
}
__global__ void scan2(int* __restrict__ bsum, int nb) {
    __shared__ int sm[256];
    int v = (threadIdx.x < nb) ? bsum[threadIdx.x] : 0;
    sm[threadIdx.x] = v;
    __syncthreads();
    #pragma unroll
    for (int d = 1; d < 256; d <<= 1) {
        int t = (threadIdx.x >= d) ? sm[threadIdx.x - d] : 0;
        __syncthreads();
        sm[threadIdx.x] += t;
        __syncthreads();
    }
    if (threadIdx.x < nb) bsum[threadIdx.x] = sm[threadIdx.x] - v;
}
__global__ void scan3(const int* __restrict__ incl, const int* __restrict__ bsum,
                      int* __restrict__ row_ptr, int N) {
    int i = blockIdx.x * 256 + threadIdx.x;
    if (i < N) row_ptr[i + 1] = incl[i] + bsum[blockIdx.x];
    if (i == 0) row_ptr[0] = 0;
}
__global__ void scatter_edges(const int* __restrict__ src, const int* __restrict__ dst,
                              int* __restrict__ cursor, int* __restrict__ esrc, int E) {
    int e = blockIdx.x * 256 + threadIdx.x;
    if (e < E) {
        int p = atomicAdd(&cursor[dst[e]], 1);
        esrc[p] = src[e];
    }
}

// ---------------- fused GAT: softmax + weighted aggregate -> bf16 h ----------------
__global__ __launch_bounds__(256)
void gat_aggregate(const int* __restrict__ row_ptr, const int* __restrict__ esrc,
                   const float* __restrict__ el, const float* __restrict__ er,
                   const unsigned short* __restrict__ feat, const float* __restrict__ gat_bias,
                   unsigned short* __restrict__ hout, int N)
{
    int node = blockIdx.x * 4 + (threadIdx.x >> 6);
    if (node >= N) return;
    const int lane = threadIdx.x & 63;
    const int h = lane >> 3, j = lane & 7;
    const int beg = row_ptr[node], end = row_ptr[node + 1];
    const float er_n = er[node * 8 + h];

    float m = -INFINITY;
    for (int k = beg + j; k < end; k += 8) {
        int s = esrc[k];
        float v = el[s * 8 + h] + er_n;
        v = (v > 0.f) ? v : NEG_SLOPE * v;
        m = fmaxf(m, v);
    }
    m = fmaxf(m, __shfl_xor(m, 1));
    m = fmaxf(m, __shfl_xor(m, 2));
    m = fmaxf(m, __shfl_xor(m, 4));

    float denom = 0.f;
    float a[8] = {};
    for (int k = beg; k < end; ++k) {
        int s = esrc[k];
        float v = el[s * 8 + h] + er_n;
        v = (v > 0.f) ? v : NEG_SLOPE * v;
        float z = __expf(v - m);
        denom += z;
        ushort8_t fv = *(const ushort8_t*)(feat + (size_t)s * 512 + lane * 8);
        #pragma unroll
        for (int t = 0; t < 8; ++t) a[t] = fmaf(z, bf2f(fv[t]), a[t]);
    }
    float inv = (end > beg) ? 1.f / denom : 0.f;
    ushort8_t o;
    #pragma unroll
    for (int t = 0; t < 8; ++t) o[t] = f2bf(fmaf(a[t], inv, gat_bias[lane * 8 + t]));
    *(ushort8_t*)(hout + (size_t)node * 512 + lane * 8) = o;
}

// ---------------- BN1 stats over bf16 h ----------------
__global__ __launch_bounds__(256)
void bn_stats512bf(const unsigned short* __restrict__ X, int M, float* __restrict__ sums)
{
    __shared__ float red[4][512];
    int cg = threadIdx.x & 63, rg = threadIdx.x >> 6;
    float s[8] = {}, q[8] = {};
    for (int r = blockIdx.x * 4 + rg; r < M; r += gridDim.x * 4) {
        ushort8_t v = *(const ushort8_t*)(X + (size_t)r * 512 + cg * 8);
        #pragma unroll
        for (int t = 0; t < 8; ++t) { float f = bf2f(v[t]); s[t] += f; q[t] += f * f; }
    }
    #pragma unroll
    for (int t = 0; t < 8; ++t) red[rg][cg * 8 + t] = s[t];
    __syncthreads();
    if (rg == 0)
        #pragma unroll
        for (int t = 0; t < 8; ++t) {
            int c = cg * 8 + t;
            atomicAdd(&sums[c], red[0][c] + red[1][c] + red[2][c] + red[3][c]);
        }
    __syncthreads();
    #pragma unroll
    for (int t = 0; t < 8; ++t) red[rg][cg * 8 + t] = q[t];
    __syncthreads();
    if (rg == 0)
        #pragma unroll
        for (int t = 0; t < 8; ++t) {
            int c = cg * 8 + t;
            atomicAdd(&sums[512 + c], red[0][c] + red[1][c] + red[2][c] + red[3][c]);
        }
}

// ---------------- fold BN1 into w1: w1p = bf16(w1*a), b1p = b1 + w1@b ----------------
__global__ __launch_bounds__(256)
void fold_w1(const float* __restrict__ w1, const float* __restrict__ ab1,
             const float* __restrict__ b1, unsigned short* __restrict__ w1p,
             float* __restrict__ b1p)
{
    int n = blockIdx.x * 4 + (threadIdx.x >> 6);
    int lane = threadIdx.x & 63;
    const float* wrow = w1 + (size_t)n * 512 + lane * 8;
    float p = 0.f;
    ushort8_t o;
    #pragma unroll
    for (int t = 0; t < 8; ++t) {
        float w = wrow[t];
        o[t] = f2bf(w * ab1[lane * 8 + t]);
        p = fmaf(w, ab1[512 + lane * 8 + t], p);
    }
    *(ushort8_t*)(w1p + (size_t)n * 512 + lane * 8) = o;
    #pragma unroll
    for (int d = 1; d < 64; d <<= 1) p += __shfl_xor(p, d);
    if (lane == 0) b1p[n] = b1[n] + p;
}

// ---------------- misc ----------------
__global__ void cvt_f32_bf16(const float* __restrict__ s, unsigned short* __restrict__ d, int n) {
    int i = blockIdx.x * 256 + threadIdx.x;
    if (i < n) d[i] = f2bf(s[i]);
}

__global__ void bn_finalize(const float* __restrict__ sums, const float* __restrict__ gamma,
                            const float* __restrict__ beta, float* __restrict__ ab,
                            int C, float invM)
{
    int c = blockIdx.x * blockDim.x + threadIdx.x;
    if (c >= C) return;
    float mu = sums[c] * invM;
    float var = sums[C + c] * invM - mu * mu;
    float a = gamma[c] * rsqrtf(var + BN_EPS);
    ab[c] = a;
    ab[C + c] = beta[c] - a * mu;
}

__global__ __launch_bounds__(256)
void bn_apply64(float* __restrict__ X, const float* __restrict__ ab, int total)
{
    int idx = blockIdx.x * 256 + threadIdx.x;
    if (idx >= total) return;
    int c = idx & 63;
    X[idx] = fmaf(ab[c], X[idx], ab[64 + c]);
}

extern "C" void kernel_launch(void* const* d_in, const int* in_sizes, int n_in,
                              void* d_out, int out_size, void* d_ws, size_t ws_size,
                              hipStream_t stream)
{
    const float* x         = (const float*)d_in[0];
    const int*   src       = (const int*)d_in[1];
    const int*   dst       = (const int*)d_in[2];
    const float* fc_w      = (const float*)d_in[3];
    const float* attn_l    = (const float*)d_in[4];
    const float* attn_r    = (const float*)d_in[5];
    const float* gat_bias  = (const float*)d_in[6];
    const float* bn1_gamma = (const float*)d_in[7];
    const float* bn1_beta  = (const float*)d_in[8];
    const float* w1        = (const float*)d_in[9];
    const float* b1        = (const float*)d_in[10];
    const float* w2        = (const float*)d_in[11];
    const float* b2        = (const float*)d_in[12];
    const float* bn2_gamma = (const float*)d_in[13];
    const float* bn2_beta  = (const float*)d_in[14];
    float* out = (float*)d_out;

    const int D = 64, HD = 512, HID = 1024;
    const int N = in_sizes[0] / D;      // 50000
    const int E = in_sizes[1];          // 400000
    const int NH = N * 8;
    const int NB = (N + 255) / 256;
    const int Mpad = ((N + 127) / 128) * 128 + 128;  // 50176: safe for unguarded gload_lds

    size_t off = 0;
    auto alloc = [&](size_t bytes) -> void* {
        void* p = (char*)d_ws + off;
        off += (bytes + 255) & ~(size_t)255;
        return p;
    };
    // Region A: feat bf16 [N,512] (dead after gat_aggregate), reused as h1 bf16 [N,1024]
    void* regionA = alloc((size_t)N * HID * 2);
    unsigned short* feat = (unsigned short*)regionA;
    unsigned short* h1   = (unsigned short*)regionA;
    // Region B: hbf bf16 [Mpad,512] (dead after gemm2), reused as gemm3 partials f32 [4][N,64]
    void* regionB = alloc((size_t)Mpad * HD * 2);
    unsigned short* hbf = (unsigned short*)regionB;
    float* gemm3P = (float*)regionB;                 // 4*N*64*4 = 51.2MB <= 51.4MB
    unsigned short* xbf  = (unsigned short*)alloc((size_t)Mpad * D * 2);
    unsigned short* fcwbf = (unsigned short*)alloc((size_t)HD * D * 2);
    unsigned short* w1p  = (unsigned short*)alloc((size_t)HID * HD * 2);
    unsigned short* w2bf = (unsigned short*)alloc((size_t)D * HID * 2);
    float* b1p   = (float*)alloc(HID * 4);
    float* el    = (float*)alloc((size_t)NH * 4);
    float* er    = (float*)alloc((size_t)NH * 4);
    int* counts  = (int*)alloc((size_t)N * 4);
    int* incl    = (int*)alloc((size_t)N * 4);
    int* row_ptr = (int*)alloc((size_t)(N + 1) * 4);
    int* cursor  = (int*)alloc((size_t)N * 4);
    int* bsum    = (int*)alloc(256 * 4);
    int* esrc    = (int*)alloc((size_t)E * 4);
    float* sums1 = (float*)alloc(2 * 512 * 4);
    float* ab1   = (float*)alloc(2 * 512 * 4);
    float* sums2 = (float*)alloc(2 * 64 * 4);
    float* ab2   = (float*)alloc(2 * 64 * 4);
    (void)ws_size; (void)n_in; (void)out_size;

    // ---- CSR build ----
    hipMemsetAsync(counts, 0, (size_t)N * 4, stream);
    hist_kernel<<<(E + 255) / 256, 256, 0, stream>>>(dst, counts, E);
    scan1<<<NB, 256, 0, stream>>>(counts, incl, bsum, N);
    scan2<<<1, 256, 0, stream>>>(bsum, NB);
    scan3<<<NB, 256, 0, stream>>>(incl, bsum, row_ptr, N);
    hipMemcpyAsync(cursor, row_ptr, (size_t)N * 4, hipMemcpyDeviceToDevice, stream);
    scatter_edges<<<(E + 255) / 256, 256, 0, stream>>>(src, dst, cursor, esrc, E);

    // ---- conversions ----
    cvt_f32_bf16<<<(N * D + 255) / 256, 256, 0, stream>>>(x, xbf, N * D);
    cvt_f32_bf16<<<(HD * D + 255) / 256, 256, 0, stream>>>(fc_w, fcwbf, HD * D);
    cvt_f32_bf16<<<(D * HID + 255) / 256, 256, 0, stream>>>(w2, w2bf, D * HID);

    // ---- GEMM1 (MFMA) + fused el/er ----
    {
        dim3 grid((N + 127) / 128, HD / 128);   // 391 x 4
        gemm1_mfma<<<grid, 256, 0, stream>>>(xbf, fcwbf, feat, attn_l, attn_r, el, er, N);
    }

    // ---- fused GAT softmax + aggregate -> bf16 h ----
    gat_aggregate<<<(N + 3) / 4, 256, 0, stream>>>(row_ptr, esrc, el, er, feat,
                                                   gat_bias, hbf, N);

    // ---- BN1 stats + fold into w1 ----
    hipMemsetAsync(sums1, 0, 2 * 512 * 4, stream);
    bn_stats512bf<<<256, 256, 0, stream>>>(hbf, N, sums1);
    bn_finalize<<<2, 256, 0, stream>>>(sums1, bn1_gamma, bn1_beta, ab1, HD, 1.f / N);
    fold_w1<<<HID / 4, 256, 0, stream>>>(w1, ab1, b1, w1p, b1p);

    // ---- GEMM2 (MFMA bf16, A-dbuf counted-vmcnt): h1 = relu(hbf @ w1p^T + b1p) ----
    {
        int nwg = ((N + 127) / 128) * (HID / 128);  // 3128
        gemm2_mfma<<<nwg, 256, 0, stream>>>(hbf, w1p, h1, N, b1p);
    }

    // ---- GEMM3 (MFMA, split-K partials into regionB; hbf is dead) ----
    {
        dim3 grid((N + 127) / 128, 4);
        gemm3_mfma<<<grid, 256, 0, stream>>>(h1, w2bf, gemm3P, N);
    }

    // ---- reduce partials + b2 -> out, fused BN2 stats ----
    hipMemsetAsync(sums2, 0, 2 * 64 * 4, stream);
    reduce_bn2<<<256, 256, 0, stream>>>(gemm3P, b2, out, N, sums2);
    bn_finalize<<<1, 64, 0, stream>>>(sums2, bn2_gamma, bn2_beta, ab2, D, 1.f / N);
    bn_apply64<<<((N * D) + 255) / 256, 256, 0, stream>>>(out, ab2, N * D);
}

// Round 8
// 391.773 us; speedup vs baseline: 5.0970x; 1.0258x over previous
//
#include <hip/hip_runtime.h>

#define NEG_SLOPE 0.2f
#define BN_EPS 1e-5f

typedef __bf16 bf16x8 __attribute__((ext_vector_type(8)));
typedef float  f32x4  __attribute__((ext_vector_type(4)));
typedef unsigned short ushort8_t __attribute__((ext_vector_type(8)));

__device__ __forceinline__ unsigned short f2bf(float f) {  // RNE f32->bf16
    unsigned int u = __float_as_uint(f);
    unsigned int r = u + 0x7FFFu + ((u >> 16) & 1u);
    return (unsigned short)(r >> 16);
}
__device__ __forceinline__ float bf2f(unsigned short u) {
    return __uint_as_float(((unsigned int)u) << 16);
}
__device__ __forceinline__ void gload16(const void* g, void* l) {
    __builtin_amdgcn_global_load_lds(
        (const __attribute__((address_space(1))) unsigned int*)g,
        (__attribute__((address_space(3))) unsigned int*)l, 16, 0, 0);
}

// ---------------- GEMM1 (MFMA): feat_bf16[M,512] = x_bf @ fc_w_bf^T, K=64 ----
// Fused epilogue: el[n,h], er[n,h] from fp32 accumulators.
__global__ __launch_bounds__(256)
void gemm1_mfma(const unsigned short* __restrict__ Ax, const unsigned short* __restrict__ Bw,
                unsigned short* __restrict__ C,
                const float* __restrict__ attn_l, const float* __restrict__ attn_r,
                float* __restrict__ el, float* __restrict__ er, int M)
{
    __shared__ alignas(16) char Asm[128 * 64 * 2];
    __shared__ alignas(16) char Bsm[128 * 64 * 2];
    const int tid = threadIdx.x, lane = tid & 63, wave = tid >> 6;
    const int wr = wave >> 1, wc = wave & 1;
    const int bm = blockIdx.x * 128, bn = blockIdx.y * 128;
    const int lr = lane >> 3, lk = ((lane & 7) ^ (lane >> 3)) * 8;

    #pragma unroll
    for (int it = 0; it < 4; ++it) {
        int seg = wave * 4 + it;
        gload16(Ax + (size_t)(bm + seg * 8 + lr) * 64 + lk, Asm + seg * 1024);
        gload16(Bw + (size_t)(bn + seg * 8 + lr) * 64 + lk, Bsm + seg * 1024);
    }
    __syncthreads();

    f32x4 acc[4][4] = {};
    #pragma unroll
    for (int kk = 0; kk < 2; ++kk) {
        int kg = kk * 4 + (lane >> 4);
        bf16x8 a[4], b[4];
        #pragma unroll
        for (int i = 0; i < 4; ++i) {
            int row = wr * 64 + i * 16 + (lane & 15);
            a[i] = *(const bf16x8*)(Asm + row * 128 + ((kg ^ (row & 7)) << 4));
        }
        #pragma unroll
        for (int j = 0; j < 4; ++j) {
            int row = wc * 64 + j * 16 + (lane & 15);
            b[j] = *(const bf16x8*)(Bsm + row * 128 + ((kg ^ (row & 7)) << 4));
        }
        #pragma unroll
        for (int i = 0; i < 4; ++i)
            #pragma unroll
            for (int j = 0; j < 4; ++j)
                acc[i][j] = __builtin_amdgcn_mfma_f32_16x16x32_bf16(a[i], b[j], acc[i][j], 0, 0, 0);
    }

    #pragma unroll
    for (int j = 0; j < 4; ++j) {
        int gn = bn + wc * 64 + j * 16 + (lane & 15);
        #pragma unroll
        for (int i = 0; i < 4; ++i)
            #pragma unroll
            for (int r = 0; r < 4; ++r) {
                int gm = bm + wr * 64 + i * 16 + (lane >> 4) * 4 + r;
                if (gm < M) C[(size_t)gm * 512 + gn] = f2bf(acc[i][j][r]);
            }
    }

    const int head = (bn >> 6) + wc;
    float al[4], ar[4];
    #pragma unroll
    for (int j = 0; j < 4; ++j) {
        int c = j * 16 + (lane & 15);
        al[j] = attn_l[head * 64 + c];
        ar[j] = attn_r[head * 64 + c];
    }
    #pragma unroll
    for (int i = 0; i < 4; ++i)
        #pragma unroll
        for (int r = 0; r < 4; ++r) {
            int gm = bm + wr * 64 + i * 16 + (lane >> 4) * 4 + r;
            float sl = 0.f, sr = 0.f;
            #pragma unroll
            for (int j = 0; j < 4; ++j) {
                sl = fmaf(acc[i][j][r], al[j], sl);
                sr = fmaf(acc[i][j][r], ar[j], sr);
            }
            sl += __shfl_xor(sl, 1); sr += __shfl_xor(sr, 1);
            sl += __shfl_xor(sl, 2); sr += __shfl_xor(sr, 2);
            sl += __shfl_xor(sl, 4); sr += __shfl_xor(sr, 4);
            sl += __shfl_xor(sl, 8); sr += __shfl_xor(sr, 8);
            if ((lane & 15) == 0 && gm < M) {
                el[gm * 8 + head] = sl;
                er[gm * 8 + head] = sr;
            }
        }
}

// ---------------- fused GEMM2+GEMM3: out = (relu(hbf@w1p^T+b1p)) @ w2^T + b2 ----
// BM=64 rows/block; t-loop over 8 col-tiles of h1; h1 tile lives only in LDS.
// Also accumulates BN2 stats into sums2.
__global__ __launch_bounds__(256)
void gemm23_fused(const unsigned short* __restrict__ A,   // hbf [Mpad,512]
                  const unsigned short* __restrict__ B,   // w1p [1024,512]
                  const unsigned short* __restrict__ W2,  // w2bf [64,1024]
                  const float* __restrict__ b1p,          // [1024]
                  const float* __restrict__ b2,           // [64]
                  float* __restrict__ out,                // [N,64]
                  float* __restrict__ sums2,              // [128]
                  int M)
{
    __shared__ alignas(16) char smem[49152];
    char* Abuf0 = smem;                 // 8KB  A tile dbuf
    char* Abuf1 = smem + 8192;          // 8KB
    char* Bbuf  = smem + 16384;         // 16KB B tile; reused as TR (h1 tile) in epilogue
    char* Wbuf  = smem + 32768;         // 16KB w2 slice
    char* TR = Bbuf;
    __shared__ float reds[4][64], redq[4][64];

    const int tid = threadIdx.x, lane = tid & 63, wave = tid >> 6;
    const int wr = wave >> 1, wc = wave & 1;
    const int lr = lane >> 3;
    const int lk = ((lane & 7) ^ lr) * 8;
    const int bm = blockIdx.x * 64;

    // prologue: stage A slice 0
    #pragma unroll
    for (int it = 0; it < 2; ++it) {
        int seg = wave * 2 + it;
        gload16(A + (size_t)(bm + seg * 8 + lr) * 512 + lk, Abuf0 + seg * 1024);
    }

    f32x4 oacc[4] = {};   // out rows wave*16.., cols j*16+(lane&15)

    for (int t = 0; t < 8; ++t) {
        f32x4 acc[2][4] = {};
        #pragma unroll
        for (int k0s = 0; k0s < 8; ++k0s) {
            const int k0 = k0s * 64;
            // stage B(t,k0)
            #pragma unroll
            for (int it = 0; it < 4; ++it) {
                int seg = wave * 4 + it;
                gload16(B + (size_t)(t * 128 + seg * 8 + lr) * 512 + k0 + lk, Bbuf + seg * 1024);
            }
            // prefetch next A slice (wraps to slice 0 for next t — same data)
            {
                const int kn = ((k0s + 1) & 7) * 64;
                char* An = ((k0s + 1) & 1) ? Abuf1 : Abuf0;
                #pragma unroll
                for (int it = 0; it < 2; ++it) {
                    int seg = wave * 2 + it;
                    gload16(A + (size_t)(bm + seg * 8 + lr) * 512 + kn + lk, An + seg * 1024);
                }
            }
            asm volatile("s_waitcnt vmcnt(2)" ::: "memory");
            __builtin_amdgcn_s_barrier();
            __builtin_amdgcn_sched_barrier(0);
            const char* Ac = (k0s & 1) ? Abuf1 : Abuf0;
            #pragma unroll
            for (int kk = 0; kk < 2; ++kk) {
                int kg = kk * 4 + (lane >> 4);
                bf16x8 a[2], b[4];
                #pragma unroll
                for (int i = 0; i < 2; ++i) {
                    int row = wr * 32 + i * 16 + (lane & 15);
                    a[i] = *(const bf16x8*)(Ac + row * 128 + ((kg ^ (row & 7)) << 4));
                }
                #pragma unroll
                for (int j = 0; j < 4; ++j) {
                    int row = wc * 64 + j * 16 + (lane & 15);
                    b[j] = *(const bf16x8*)(Bbuf + row * 128 + ((kg ^ (row & 7)) << 4));
                }
                #pragma unroll
                for (int i = 0; i < 2; ++i)
                    #pragma unroll
                    for (int j = 0; j < 4; ++j)
                        acc[i][j] = __builtin_amdgcn_mfma_f32_16x16x32_bf16(a[i], b[j], acc[i][j], 0, 0, 0);
            }
            __builtin_amdgcn_sched_barrier(0);
            __builtin_amdgcn_s_barrier();
            __builtin_amdgcn_sched_barrier(0);
        }
        // ---- t epilogue: h1 tile -> TR (bias+relu+bf16, XOR-swizzled 16-group rows) ----
        #pragma unroll
        for (int j = 0; j < 4; ++j) {
            int c = wc * 64 + j * 16 + (lane & 15);
            float bs = b1p[t * 128 + c];
            #pragma unroll
            for (int i = 0; i < 2; ++i) {
                #pragma unroll
                for (int r = 0; r < 4; ++r) {
                    int rw = wr * 32 + i * 16 + (lane >> 4) * 4 + r;
                    float v = fmaxf(acc[i][j][r] + bs, 0.f);
                    *(unsigned short*)(TR + rw * 256 + ((((c >> 3) ^ (rw & 15))) << 4) + (c & 7) * 2) = f2bf(v);
                }
            }
        }
        // stage w2 slice t: [64][128] bf16, 16-group XOR swizzle (inverse-swizzled source)
        #pragma unroll
        for (int it = 0; it < 4; ++it) {
            int seg = wave * 4 + it;               // 16 segs of 1024B = 4 rows each
            int oc = seg * 4 + (lane >> 4);
            int g = (lane & 15) ^ (oc & 15);
            gload16(W2 + (size_t)oc * 1024 + t * 128 + g * 8, Wbuf + seg * 1024);
        }
        asm volatile("s_waitcnt vmcnt(0) lgkmcnt(0)" ::: "memory");
        __builtin_amdgcn_s_barrier();
        __builtin_amdgcn_sched_barrier(0);
        // ---- gemm3 partial: oacc += h1tile(64x128) @ w2slice(64x128)^T ----
        #pragma unroll
        for (int ks = 0; ks < 4; ++ks) {
            int kg2 = ks * 4 + (lane >> 4);
            int row = wave * 16 + (lane & 15);
            bf16x8 av = *(const bf16x8*)(TR + row * 256 + ((kg2 ^ (row & 15)) << 4));
            #pragma unroll
            for (int j = 0; j < 4; ++j) {
                int oc = j * 16 + (lane & 15);
                bf16x8 bv = *(const bf16x8*)(Wbuf + oc * 256 + ((kg2 ^ (oc & 15)) << 4));
                oacc[j] = __builtin_amdgcn_mfma_f32_16x16x32_bf16(av, bv, oacc[j], 0, 0, 0);
            }
        }
        __builtin_amdgcn_sched_barrier(0);
        __builtin_amdgcn_s_barrier();   // TR/Wbuf about to be overwritten next t
        __builtin_amdgcn_sched_barrier(0);
    }

    // ---- final epilogue: +b2, store out, fused BN2 stats ----
    float s4[4] = {}, q4[4] = {};
    #pragma unroll
    for (int j = 0; j < 4; ++j) {
        int col = j * 16 + (lane & 15);
        float bias = b2[col];
        #pragma unroll
        for (int r = 0; r < 4; ++r) {
            int gm = bm + wave * 16 + (lane >> 4) * 4 + r;
            float v = oacc[j][r] + bias;
            if (gm < M) {
                out[(size_t)gm * 64 + col] = v;
                s4[j] += v; q4[j] += v * v;
            }
        }
    }
    #pragma unroll
    for (int j = 0; j < 4; ++j) {
        s4[j] += __shfl_xor(s4[j], 16); q4[j] += __shfl_xor(q4[j], 16);
        s4[j] += __shfl_xor(s4[j], 32); q4[j] += __shfl_xor(q4[j], 32);
    }
    if (lane < 16) {
        #pragma unroll
        for (int j = 0; j < 4; ++j) {
            reds[wave][j * 16 + lane] = s4[j];
            redq[wave][j * 16 + lane] = q4[j];
        }
    }
    __syncthreads();
    if (wave == 0 && lane < 16) {
        #pragma unroll
        for (int j = 0; j < 4; ++j) {
            int c = j * 16 + lane;
            atomicAdd(&sums2[c], reds[0][c] + reds[1][c] + reds[2][c] + reds[3][c]);
            atomicAdd(&sums2[64 + c], redq[0][c] + redq[1][c] + redq[2][c] + redq[3][c]);
        }
    }
}

// ---------------- CSR build ----------------
__global__ void hist_kernel(const int* __restrict__ dst, int* __restrict__ counts, int E) {
    int i = blockIdx.x * 256 + threadIdx.x;
    if (i < E) atomicAdd(&counts[dst[i]], 1);
}
__global__ void scan1(const int* __restrict__ counts, int* __restrict__ incl,
                      int* __restrict__ bsum, int N) {
    __shared__ int sm[256];
    int i = blockIdx.x * 256 + threadIdx.x;
    int v = (i < N) ? counts[i] : 0;
    sm[threadIdx.x] = v;
    __syncthreads();
    #pragma unroll
    for (int d = 1; d < 256; d <<= 1) {
        int t = (threadIdx.x >= d) ? sm[threadIdx.x - d] : 0;
        __syncthreads();
        sm[threadIdx.x] += t;
        __syncthreads();
    }
    if (i < N) incl[i] = sm[threadIdx.x];
    if (threadIdx.x == 255) bsum[blockIdx.x] = sm[255];
}
__global__ void scan2(int* __restrict__ bsum, int nb) {
    __shared__ int sm[256];
    int v = (threadIdx.x < nb) ? bsum[threadIdx.x] : 0;
    sm[threadIdx.x] = v;
    __syncthreads();
    #pragma unroll
    for (int d = 1; d < 256; d <<= 1) {
        int t = (threadIdx.x >= d) ? sm[threadIdx.x - d] : 0;
        __syncthreads();
        sm[threadIdx.x] += t;
        __syncthreads();
    }
    if (threadIdx.x < nb) bsum[threadIdx.x] = sm[threadIdx.x] - v;
}
__global__ void scan3(const int* __restrict__ incl, const int* __restrict__ bsum,
                      int* __restrict__ row_ptr, int N) {
    int i = blockIdx.x * 256 + threadIdx.x;
    if (i < N) row_ptr[i + 1] = incl[i] + bsum[blockIdx.x];
    if (i == 0) row_ptr[0] = 0;
}
__global__ void scatter_edges(const int* __restrict__ src, const int* __restrict__ dst,
                              int* __restrict__ cursor, int* __restrict__ esrc, int E) {
    int e = blockIdx.x * 256 + threadIdx.x;
    if (e < E) {
        int p = atomicAdd(&cursor[dst[e]], 1);
        esrc[p] = src[e];
    }
}

// ---------------- fused GAT: softmax + weighted aggregate -> bf16 h ----------------
__global__ __launch_bounds__(256)
void gat_aggregate(const int* __restrict__ row_ptr, const int* __restrict__ esrc,
                   const float* __restrict__ el, const float* __restrict__ er,
                   const unsigned short* __restrict__ feat, const float* __restrict__ gat_bias,
                   unsigned short* __restrict__ hout, int N)
{
    int node = blockIdx.x * 4 + (threadIdx.x >> 6);
    if (node >= N) return;
    const int lane = threadIdx.x & 63;
    const int h = lane >> 3, j = lane & 7;
    const int beg = row_ptr[node], end = row_ptr[node + 1];
    const float er_n = er[node * 8 + h];

    float m = -INFINITY;
    for (int k = beg + j; k < end; k += 8) {
        int s = esrc[k];
        float v = el[s * 8 + h] + er_n;
        v = (v > 0.f) ? v : NEG_SLOPE * v;
        m = fmaxf(m, v);
    }
    m = fmaxf(m, __shfl_xor(m, 1));
    m = fmaxf(m, __shfl_xor(m, 2));
    m = fmaxf(m, __shfl_xor(m, 4));

    float denom = 0.f;
    float a[8] = {};
    for (int k = beg; k < end; ++k) {
        int s = esrc[k];
        float v = el[s * 8 + h] + er_n;
        v = (v > 0.f) ? v : NEG_SLOPE * v;
        float z = __expf(v - m);
        denom += z;
        ushort8_t fv = *(const ushort8_t*)(feat + (size_t)s * 512 + lane * 8);
        #pragma unroll
        for (int t = 0; t < 8; ++t) a[t] = fmaf(z, bf2f(fv[t]), a[t]);
    }
    float inv = (end > beg) ? 1.f / denom : 0.f;
    ushort8_t o;
    #pragma unroll
    for (int t = 0; t < 8; ++t) o[t] = f2bf(fmaf(a[t], inv, gat_bias[lane * 8 + t]));
    *(ushort8_t*)(hout + (size_t)node * 512 + lane * 8) = o;
}

// ---------------- BN1 stats over bf16 h ----------------
__global__ __launch_bounds__(256)
void bn_stats512bf(const unsigned short* __restrict__ X, int M, float* __restrict__ sums)
{
    __shared__ float red[4][512];
    int cg = threadIdx.x & 63, rg = threadIdx.x >> 6;
    float s[8] = {}, q[8] = {};
    for (int r = blockIdx.x * 4 + rg; r < M; r += gridDim.x * 4) {
        ushort8_t v = *(const ushort8_t*)(X + (size_t)r * 512 + cg * 8);
        #pragma unroll
        for (int t = 0; t < 8; ++t) { float f = bf2f(v[t]); s[t] += f; q[t] += f * f; }
    }
    #pragma unroll
    for (int t = 0; t < 8; ++t) red[rg][cg * 8 + t] = s[t];
    __syncthreads();
    if (rg == 0)
        #pragma unroll
        for (int t = 0; t < 8; ++t) {
            int c = cg * 8 + t;
            atomicAdd(&sums[c], red[0][c] + red[1][c] + red[2][c] + red[3][c]);
        }
    __syncthreads();
    #pragma unroll
    for (int t = 0; t < 8; ++t) red[rg][cg * 8 + t] = q[t];
    __syncthreads();
    if (rg == 0)
        #pragma unroll
        for (int t = 0; t < 8; ++t) {
            int c = cg * 8 + t;
            atomicAdd(&sums[512 + c], red[0][c] + red[1][c] + red[2][c] + red[3][c]);
        }
}

// ---------------- fold BN1 into w1: w1p = bf16(w1*a), b1p = b1 + w1@b ----------------
__global__ __launch_bounds__(256)
void fold_w1(const float* __restrict__ w1, const float* __restrict__ ab1,
             const float* __restrict__ b1, unsigned short* __restrict__ w1p,
             float* __restrict__ b1p)
{
    int n = blockIdx.x * 4 + (threadIdx.x >> 6);
    int lane = threadIdx.x & 63;
    const float* wrow = w1 + (size_t)n * 512 + lane * 8;
    float p = 0.f;
    ushort8_t o;
    #pragma unroll
    for (int t = 0; t < 8; ++t) {
        float w = wrow[t];
        o[t] = f2bf(w * ab1[lane * 8 + t]);
        p = fmaf(w, ab1[512 + lane * 8 + t], p);
    }
    *(ushort8_t*)(w1p + (size_t)n * 512 + lane * 8) = o;
    #pragma unroll
    for (int d = 1; d < 64; d <<= 1) p += __shfl_xor(p, d);
    if (lane == 0) b1p[n] = b1[n] + p;
}

// ---------------- misc ----------------
__global__ void cvt_f32_bf16(const float* __restrict__ s, unsigned short* __restrict__ d, int n) {
    int i = blockIdx.x * 256 + threadIdx.x;
    if (i < n) d[i] = f2bf(s[i]);
}

__global__ void bn_finalize(const float* __restrict__ sums, const float* __restrict__ gamma,
                            const float* __restrict__ beta, float* __restrict__ ab,
                            int C, float invM)
{
    int c = blockIdx.x * blockDim.x + threadIdx.x;
    if (c >= C) return;
    float mu = sums[c] * invM;
    float var = sums[C + c] * invM - mu * mu;
    float a = gamma[c] * rsqrtf(var + BN_EPS);
    ab[c] = a;
    ab[C + c] = beta[c] - a * mu;
}

__global__ __launch_bounds__(256)
void bn_apply64(float* __restrict__ X, const float* __restrict__ ab, int total)
{
    int idx = blockIdx.x * 256 + threadIdx.x;
    if (idx >= total) return;
    int c = idx & 63;
    X[idx] = fmaf(ab[c], X[idx], ab[64 + c]);
}

extern "C" void kernel_launch(void* const* d_in, const int* in_sizes, int n_in,
                              void* d_out, int out_size, void* d_ws, size_t ws_size,
                              hipStream_t stream)
{
    const float* x         = (const float*)d_in[0];
    const int*   src       = (const int*)d_in[1];
    const int*   dst       = (const int*)d_in[2];
    const float* fc_w      = (const float*)d_in[3];
    const float* attn_l    = (const float*)d_in[4];
    const float* attn_r    = (const float*)d_in[5];
    const float* gat_bias  = (const float*)d_in[6];
    const float* bn1_gamma = (const float*)d_in[7];
    const float* bn1_beta  = (const float*)d_in[8];
    const float* w1        = (const float*)d_in[9];
    const float* b1        = (const float*)d_in[10];
    const float* w2        = (const float*)d_in[11];
    const float* b2        = (const float*)d_in[12];
    const float* bn2_gamma = (const float*)d_in[13];
    const float* bn2_beta  = (const float*)d_in[14];
    float* out = (float*)d_out;

    const int D = 64, HD = 512, HID = 1024;
    const int N = in_sizes[0] / D;      // 50000
    const int E = in_sizes[1];          // 400000
    const int NH = N * 8;
    const int NB = (N + 255) / 256;
    const int Mpad = ((N + 127) / 128) * 128 + 128;  // 50176

    size_t off = 0;
    auto alloc = [&](size_t bytes) -> void* {
        void* p = (char*)d_ws + off;
        off += (bytes + 255) & ~(size_t)255;
        return p;
    };
    unsigned short* feat = (unsigned short*)alloc((size_t)N * HD * 2);
    unsigned short* hbf  = (unsigned short*)alloc((size_t)Mpad * HD * 2);
    unsigned short* xbf  = (unsigned short*)alloc((size_t)Mpad * D * 2);
    unsigned short* fcwbf = (unsigned short*)alloc((size_t)HD * D * 2);
    unsigned short* w1p  = (unsigned short*)alloc((size_t)HID * HD * 2);
    unsigned short* w2bf = (unsigned short*)alloc((size_t)D * HID * 2);
    float* b1p   = (float*)alloc(HID * 4);
    float* el    = (float*)alloc((size_t)NH * 4);
    float* er    = (float*)alloc((size_t)NH * 4);
    int* counts  = (int*)alloc((size_t)N * 4);
    int* incl    = (int*)alloc((size_t)N * 4);
    int* row_ptr = (int*)alloc((size_t)(N + 1) * 4);
    int* cursor  = (int*)alloc((size_t)N * 4);
    int* bsum    = (int*)alloc(256 * 4);
    int* esrc    = (int*)alloc((size_t)E * 4);
    float* sums1 = (float*)alloc(2 * 512 * 4);
    float* ab1   = (float*)alloc(2 * 512 * 4);
    float* sums2 = (float*)alloc(2 * 64 * 4);
    float* ab2   = (float*)alloc(2 * 64 * 4);
    (void)ws_size; (void)n_in; (void)out_size;

    // ---- CSR build ----
    hipMemsetAsync(counts, 0, (size_t)N * 4, stream);
    hist_kernel<<<(E + 255) / 256, 256, 0, stream>>>(dst, counts, E);
    scan1<<<NB, 256, 0, stream>>>(counts, incl, bsum, N);
    scan2<<<1, 256, 0, stream>>>(bsum, NB);
    scan3<<<NB, 256, 0, stream>>>(incl, bsum, row_ptr, N);
    hipMemcpyAsync(cursor, row_ptr, (size_t)N * 4, hipMemcpyDeviceToDevice, stream);
    scatter_edges<<<(E + 255) / 256, 256, 0, stream>>>(src, dst, cursor, esrc, E);

    // ---- conversions ----
    cvt_f32_bf16<<<(N * D + 255) / 256, 256, 0, stream>>>(x, xbf, N * D);
    cvt_f32_bf16<<<(HD * D + 255) / 256, 256, 0, stream>>>(fc_w, fcwbf, HD * D);
    cvt_f32_bf16<<<(D * HID + 255) / 256, 256, 0, stream>>>(w2, w2bf, D * HID);

    // ---- GEMM1 (MFMA) + fused el/er ----
    {
        dim3 grid((N + 127) / 128, HD / 128);
        gemm1_mfma<<<grid, 256, 0, stream>>>(xbf, fcwbf, feat, attn_l, attn_r, el, er, N);
    }

    // ---- fused GAT softmax + aggregate -> bf16 h ----
    gat_aggregate<<<(N + 3) / 4, 256, 0, stream>>>(row_ptr, esrc, el, er, feat,
                                                   gat_bias, hbf, N);

    // ---- BN1 stats + fold into w1 ----
    hipMemsetAsync(sums1, 0, 2 * 512 * 4, stream);
    bn_stats512bf<<<256, 256, 0, stream>>>(hbf, N, sums1);
    bn_finalize<<<2, 256, 0, stream>>>(sums1, bn1_gamma, bn1_beta, ab1, HD, 1.f / N);
    fold_w1<<<HID / 4, 256, 0, stream>>>(w1, ab1, b1, w1p, b1p);

    // ---- fused GEMM2+GEMM3 (+b2, +BN2 stats) ----
    hipMemsetAsync(sums2, 0, 2 * 64 * 4, stream);
    {
        int nwg = (N + 63) / 64;   // 782
        gemm23_fused<<<nwg, 256, 0, stream>>>(hbf, w1p, w2bf, b1p, b2, out, sums2, N);
    }

    // ---- BN2 finalize + apply ----
    bn_finalize<<<1, 64, 0, stream>>>(sums2, bn2_gamma, bn2_beta, ab2, D, 1.f / N);
    bn_apply64<<<((N * D) + 255) / 256, 256, 0, stream>>>(out, ab2, N * D);
}

// Round 9
// 347.586 us; speedup vs baseline: 5.7449x; 1.1271x over previous
//
#include <hip/hip_runtime.h>

#define NEG_SLOPE 0.2f
#define BN_EPS 1e-5f

typedef __bf16 bf16x8 __attribute__((ext_vector_type(8)));
typedef float  f32x4  __attribute__((ext_vector_type(4)));
typedef unsigned short ushort8_t __attribute__((ext_vector_type(8)));

__device__ __forceinline__ unsigned short f2bf(float f) {  // RNE f32->bf16
    unsigned int u = __float_as_uint(f);
    unsigned int r = u + 0x7FFFu + ((u >> 16) & 1u);
    return (unsigned short)(r >> 16);
}
__device__ __forceinline__ float bf2f(unsigned short u) {
    return __uint_as_float(((unsigned int)u) << 16);
}
__device__ __forceinline__ void gload16(const void* g, void* l) {
    __builtin_amdgcn_global_load_lds(
        (const __attribute__((address_space(1))) unsigned int*)g,
        (__attribute__((address_space(3))) unsigned int*)l, 16, 0, 0);
}

// ---------------- GEMM1 (MFMA): feat_bf16[M,512] = x_bf @ fc_w_bf^T, K=64 ----
// Fused epilogue: el[n,h], er[n,h] from fp32 accumulators.
__global__ __launch_bounds__(256)
void gemm1_mfma(const unsigned short* __restrict__ Ax, const unsigned short* __restrict__ Bw,
                unsigned short* __restrict__ C,
                const float* __restrict__ attn_l, const float* __restrict__ attn_r,
                float* __restrict__ el, float* __restrict__ er, int M)
{
    __shared__ alignas(16) char Asm[128 * 64 * 2];
    __shared__ alignas(16) char Bsm[128 * 64 * 2];
    const int tid = threadIdx.x, lane = tid & 63, wave = tid >> 6;
    const int wr = wave >> 1, wc = wave & 1;
    const int bm = blockIdx.x * 128, bn = blockIdx.y * 128;
    const int lr = lane >> 3, lk = ((lane & 7) ^ (lane >> 3)) * 8;

    #pragma unroll
    for (int it = 0; it < 4; ++it) {
        int seg = wave * 4 + it;
        gload16(Ax + (size_t)(bm + seg * 8 + lr) * 64 + lk, Asm + seg * 1024);
        gload16(Bw + (size_t)(bn + seg * 8 + lr) * 64 + lk, Bsm + seg * 1024);
    }
    __syncthreads();

    f32x4 acc[4][4] = {};
    #pragma unroll
    for (int kk = 0; kk < 2; ++kk) {
        int kg = kk * 4 + (lane >> 4);
        bf16x8 a[4], b[4];
        #pragma unroll
        for (int i = 0; i < 4; ++i) {
            int row = wr * 64 + i * 16 + (lane & 15);
            a[i] = *(const bf16x8*)(Asm + row * 128 + ((kg ^ (row & 7)) << 4));
        }
        #pragma unroll
        for (int j = 0; j < 4; ++j) {
            int row = wc * 64 + j * 16 + (lane & 15);
            b[j] = *(const bf16x8*)(Bsm + row * 128 + ((kg ^ (row & 7)) << 4));
        }
        #pragma unroll
        for (int i = 0; i < 4; ++i)
            #pragma unroll
            for (int j = 0; j < 4; ++j)
                acc[i][j] = __builtin_amdgcn_mfma_f32_16x16x32_bf16(a[i], b[j], acc[i][j], 0, 0, 0);
    }

    #pragma unroll
    for (int j = 0; j < 4; ++j) {
        int gn = bn + wc * 64 + j * 16 + (lane & 15);
        #pragma unroll
        for (int i = 0; i < 4; ++i)
            #pragma unroll
            for (int r = 0; r < 4; ++r) {
                int gm = bm + wr * 64 + i * 16 + (lane >> 4) * 4 + r;
                if (gm < M) C[(size_t)gm * 512 + gn] = f2bf(acc[i][j][r]);
            }
    }

    const int head = (bn >> 6) + wc;
    float al[4], ar[4];
    #pragma unroll
    for (int j = 0; j < 4; ++j) {
        int c = j * 16 + (lane & 15);
        al[j] = attn_l[head * 64 + c];
        ar[j] = attn_r[head * 64 + c];
    }
    #pragma unroll
    for (int i = 0; i < 4; ++i)
        #pragma unroll
        for (int r = 0; r < 4; ++r) {
            int gm = bm + wr * 64 + i * 16 + (lane >> 4) * 4 + r;
            float sl = 0.f, sr = 0.f;
            #pragma unroll
            for (int j = 0; j < 4; ++j) {
                sl = fmaf(acc[i][j][r], al[j], sl);
                sr = fmaf(acc[i][j][r], ar[j], sr);
            }
            sl += __shfl_xor(sl, 1); sr += __shfl_xor(sr, 1);
            sl += __shfl_xor(sl, 2); sr += __shfl_xor(sr, 2);
            sl += __shfl_xor(sl, 4); sr += __shfl_xor(sr, 4);
            sl += __shfl_xor(sl, 8); sr += __shfl_xor(sr, 8);
            if ((lane & 15) == 0 && gm < M) {
                el[gm * 8 + head] = sl;
                er[gm * 8 + head] = sr;
            }
        }
}

// ---------------- GEMM2+partial-GEMM3: per block (bm,t): h1tile=relu(hbf@w1p^T+b1p),
// then P[t][bm..bm+128][0..64) = h1tile @ w2[:, t*128..+128)^T (bf16, coalesced).
__global__ __launch_bounds__(256)
void gemm2p(const unsigned short* __restrict__ A,   // hbf [Mpad,512]
            const unsigned short* __restrict__ B,   // w1p [1024,512]
            const unsigned short* __restrict__ W2,  // w2bf [64,1024]
            const float* __restrict__ b1p,          // [1024]
            unsigned short* __restrict__ P,         // [8][M][64] bf16 partials
            int M)
{
    __shared__ alignas(16) char smem[49152];
    char* Abuf0 = smem;                 // 16KB A dbuf
    char* Abuf1 = smem + 16384;         // 16KB
    char* Bbuf  = smem + 32768;         // 16KB B tile
    char* TR   = smem;                  // epilogue: h1 tile [128][128] bf16 (32KB, over Abuf)
    char* Wbuf = smem + 32768;          // epilogue: w2 slice [64][128] bf16 (16KB, over Bbuf)
    char* PK   = smem + 32768;          // epilogue2: out tile [128][64] bf16 (16KB)

    const int tid = threadIdx.x, lane = tid & 63, wave = tid >> 6;
    const int wr = wave >> 1, wc = wave & 1;
    const int lr = lane >> 3, lk = ((lane & 7) ^ lr) * 8;

    int bid = blockIdx.x;
    int wgid = (bid & 7) * 391 + (bid >> 3);   // nwg = 3128 = 8*391, bijective
    const int bm = (wgid >> 3) * 128;
    const int t  = wgid & 7;
    const int bn = t * 128;

    // prologue: stage A tile 0
    #pragma unroll
    for (int it = 0; it < 4; ++it) {
        int seg = wave * 4 + it;
        gload16(A + (size_t)(bm + seg * 8 + lr) * 512 + lk, Abuf0 + seg * 1024);
    }

    f32x4 acc[4][4] = {};
    #pragma unroll
    for (int ks = 0; ks < 8; ++ks) {
        const int k0 = ks * 64;
        #pragma unroll
        for (int it = 0; it < 4; ++it) {
            int seg = wave * 4 + it;
            gload16(B + (size_t)(bn + seg * 8 + lr) * 512 + k0 + lk, Bbuf + seg * 1024);
        }
        if (ks < 7) {
            char* An = (ks & 1) ? Abuf0 : Abuf1;
            #pragma unroll
            for (int it = 0; it < 4; ++it) {
                int seg = wave * 4 + it;
                gload16(A + (size_t)(bm + seg * 8 + lr) * 512 + (k0 + 64) + lk, An + seg * 1024);
            }
            asm volatile("s_waitcnt vmcnt(4)" ::: "memory");
        } else {
            asm volatile("s_waitcnt vmcnt(0)" ::: "memory");
        }
        __builtin_amdgcn_s_barrier();
        __builtin_amdgcn_sched_barrier(0);
        const char* Ac = (ks & 1) ? Abuf1 : Abuf0;
        #pragma unroll
        for (int kk = 0; kk < 2; ++kk) {
            int kg = kk * 4 + (lane >> 4);
            bf16x8 a[4], b[4];
            #pragma unroll
            for (int i = 0; i < 4; ++i) {
                int row = wr * 64 + i * 16 + (lane & 15);
                a[i] = *(const bf16x8*)(Ac + row * 128 + ((kg ^ (row & 7)) << 4));
            }
            #pragma unroll
            for (int j = 0; j < 4; ++j) {
                int row = wc * 64 + j * 16 + (lane & 15);
                b[j] = *(const bf16x8*)(Bbuf + row * 128 + ((kg ^ (row & 7)) << 4));
            }
            #pragma unroll
            for (int i = 0; i < 4; ++i)
                #pragma unroll
                for (int j = 0; j < 4; ++j)
                    acc[i][j] = __builtin_amdgcn_mfma_f32_16x16x32_bf16(a[i], b[j], acc[i][j], 0, 0, 0);
        }
        __builtin_amdgcn_sched_barrier(0);
        __builtin_amdgcn_s_barrier();
        __builtin_amdgcn_sched_barrier(0);
    }

    // ---- epilogue: h1 tile (bias+relu+bf16) -> TR, swizzled ----
    #pragma unroll
    for (int j = 0; j < 4; ++j) {
        int c = wc * 64 + j * 16 + (lane & 15);
        float bs = b1p[bn + c];
        #pragma unroll
        for (int i = 0; i < 4; ++i)
            #pragma unroll
            for (int r = 0; r < 4; ++r) {
                int rw = wr * 64 + i * 16 + (lane >> 4) * 4 + r;
                float v = fmaxf(acc[i][j][r] + bs, 0.f);
                *(unsigned short*)(TR + rw * 256 + (((c >> 3) ^ (rw & 7)) << 4) + (c & 7) * 2) = f2bf(v);
            }
    }
    // stage w2 slice [64][128] into Wbuf (inverse-swizzled source)
    #pragma unroll
    for (int it = 0; it < 4; ++it) {
        int oc = wave * 16 + it * 4 + (lane >> 4);
        int g = lane & 15;
        gload16(W2 + (size_t)oc * 1024 + bn + ((g ^ (oc & 7))) * 8, Wbuf + (wave * 4 + it) * 1024);
    }
    __syncthreads();

    // ---- partial GEMM3: pacc = h1tile(128x128) @ w2slice(64x128)^T ----
    f32x4 pacc[2][4] = {};
    #pragma unroll
    for (int ks = 0; ks < 4; ++ks) {
        int kg2 = ks * 4 + (lane >> 4);
        #pragma unroll
        for (int i = 0; i < 2; ++i) {
            int arow = wave * 32 + i * 16 + (lane & 15);
            bf16x8 av = *(const bf16x8*)(TR + arow * 256 + ((kg2 ^ (arow & 7)) << 4));
            #pragma unroll
            for (int j = 0; j < 4; ++j) {
                int oc = j * 16 + (lane & 15);
                bf16x8 bv = *(const bf16x8*)(Wbuf + oc * 256 + ((kg2 ^ (oc & 7)) << 4));
                pacc[i][j] = __builtin_amdgcn_mfma_f32_16x16x32_bf16(av, bv, pacc[i][j], 0, 0, 0);
            }
        }
    }
    __syncthreads();

    // ---- pack partial tile [128][64] bf16 via LDS, then coalesced 16B stores ----
    #pragma unroll
    for (int i = 0; i < 2; ++i)
        #pragma unroll
        for (int j = 0; j < 4; ++j)
            #pragma unroll
            for (int r = 0; r < 4; ++r) {
                int row = wave * 32 + i * 16 + (lane >> 4) * 4 + r;
                int col = j * 16 + (lane & 15);
                *(unsigned short*)(PK + row * 128 + col * 2) = f2bf(pacc[i][j][r]);
            }
    __syncthreads();
    unsigned short* Pt = P + (size_t)t * M * 64;
    #pragma unroll
    for (int it = 0; it < 4; ++it) {
        int u = it * 256 + tid;     // 1024 units of 16B
        int row = u >> 3, g8 = u & 7;
        int gm = bm + row;
        if (gm < M) {
            uint4 v = *(const uint4*)(PK + row * 128 + g8 * 16);
            *(uint4*)(Pt + (size_t)gm * 64 + g8 * 8) = v;
        }
    }
}

// ---------------- reduce 8 bf16 partials + b2 -> out, fused BN2 stats ----------------
__global__ __launch_bounds__(256)
void reduce_bn2(const unsigned short* __restrict__ P, const float* __restrict__ b2,
                float* __restrict__ out, int M, float* __restrict__ sums2)
{
    __shared__ float ls[256], lq[256];
    int c = threadIdx.x & 63, g = threadIdx.x >> 6;
    const size_t S = (size_t)M * 64;
    float bias = b2[c];
    float s = 0.f, q = 0.f;
    for (int r = blockIdx.x * 4 + g; r < M; r += gridDim.x * 4) {
        size_t idx = (size_t)r * 64 + c;
        float v = bias;
        #pragma unroll
        for (int t = 0; t < 8; ++t) v += bf2f(P[t * S + idx]);
        out[idx] = v;
        s += v; q += v * v;
    }
    ls[threadIdx.x] = s; lq[threadIdx.x] = q;
    __syncthreads();
    if (g == 0) {
        s = ls[c] + ls[64 + c] + ls[128 + c] + ls[192 + c];
        q = lq[c] + lq[64 + c] + lq[128 + c] + lq[192 + c];
        atomicAdd(&sums2[c], s);
        atomicAdd(&sums2[64 + c], q);
    }
}

// ---------------- CSR build ----------------
__global__ void hist_kernel(const int* __restrict__ dst, int* __restrict__ counts, int E) {
    int i = blockIdx.x * 256 + threadIdx.x;
    if (i < E) atomicAdd(&counts[dst[i]], 1);
}
__global__ void scan1(const int* __restrict__ counts, int* __restrict__ incl,
                      int* __restrict__ bsum, int N) {
    __shared__ int sm[256];
    int i = blockIdx.x * 256 + threadIdx.x;
    int v = (i < N) ? counts[i] : 0;
    sm[threadIdx.x] = v;
    __syncthreads();
    #pragma unroll
    for (int d = 1; d < 256; d <<= 1) {
        int t = (threadIdx.x >= d) ? sm[threadIdx.x - d] : 0;
        __syncthreads();
        sm[threadIdx.x] += t;
        __syncthreads();
    }
    if (i < N) incl[i] = sm[threadIdx.x];
    if (threadIdx.x == 255) bsum[blockIdx.x] = sm[255];
}
__global__ void scan2(int* __restrict__ bsum, int nb) {
    __shared__ int sm[256];
    int v = (threadIdx.x < nb) ? bsum[threadIdx.x] : 0;
    sm[threadIdx.x] = v;
    __syncthreads();
    #pragma unroll
    for (int d = 1; d < 256; d <<= 1) {
        int t = (threadIdx.x >= d) ? sm[threadIdx.x - d] : 0;
        __syncthreads();
        sm[threadIdx.x] += t;
        __syncthreads();
    }
    if (threadIdx.x < nb) bsum[threadIdx.x] = sm[threadIdx.x] - v;
}
__global__ void scan3(const int* __restrict__ incl, const int* __restrict__ bsum,
                      int* __restrict__ row_ptr, int N) {
    int i = blockIdx.x * 256 + threadIdx.x;
    if (i < N) row_ptr[i + 1] = incl[i] + bsum[blockIdx.x];
    if (i == 0) row_ptr[0] = 0;
}
__global__ void scatter_edges(const int* __restrict__ src, const int* __restrict__ dst,
                              int* __restrict__ cursor, int* __restrict__ esrc, int E) {
    int e = blockIdx.x * 256 + threadIdx.x;
    if (e < E) {
        int p = atomicAdd(&cursor[dst[e]], 1);
        esrc[p] = src[e];
    }
}

// ---------------- fused GAT: softmax + weighted aggregate -> bf16 h ----------------
__global__ __launch_bounds__(256)
void gat_aggregate(const int* __restrict__ row_ptr, const int* __restrict__ esrc,
                   const float* __restrict__ el, const float* __restrict__ er,
                   const unsigned short* __restrict__ feat, const float* __restrict__ gat_bias,
                   unsigned short* __restrict__ hout, int N)
{
    int node = blockIdx.x * 4 + (threadIdx.x >> 6);
    if (node >= N) return;
    const int lane = threadIdx.x & 63;
    const int h = lane >> 3, j = lane & 7;
    const int beg = row_ptr[node], end = row_ptr[node + 1];
    const float er_n = er[node * 8 + h];

    float m = -INFINITY;
    for (int k = beg + j; k < end; k += 8) {
        int s = esrc[k];
        float v = el[s * 8 + h] + er_n;
        v = (v > 0.f) ? v : NEG_SLOPE * v;
        m = fmaxf(m, v);
    }
    m = fmaxf(m, __shfl_xor(m, 1));
    m = fmaxf(m, __shfl_xor(m, 2));
    m = fmaxf(m, __shfl_xor(m, 4));

    float denom = 0.f;
    float a[8] = {};
    for (int k = beg; k < end; ++k) {
        int s = esrc[k];
        float v = el[s * 8 + h] + er_n;
        v = (v > 0.f) ? v : NEG_SLOPE * v;
        float z = __expf(v - m);
        denom += z;
        ushort8_t fv = *(const ushort8_t*)(feat + (size_t)s * 512 + lane * 8);
        #pragma unroll
        for (int t = 0; t < 8; ++t) a[t] = fmaf(z, bf2f(fv[t]), a[t]);
    }
    float inv = (end > beg) ? 1.f / denom : 0.f;
    ushort8_t o;
    #pragma unroll
    for (int t = 0; t < 8; ++t) o[t] = f2bf(fmaf(a[t], inv, gat_bias[lane * 8 + t]));
    *(ushort8_t*)(hout + (size_t)node * 512 + lane * 8) = o;
}

// ---------------- BN1 stats over bf16 h ----------------
__global__ __launch_bounds__(256)
void bn_stats512bf(const unsigned short* __restrict__ X, int M, float* __restrict__ sums)
{
    __shared__ float red[4][512];
    int cg = threadIdx.x & 63, rg = threadIdx.x >> 6;
    float s[8] = {}, q[8] = {};
    for (int r = blockIdx.x * 4 + rg; r < M; r += gridDim.x * 4) {
        ushort8_t v = *(const ushort8_t*)(X + (size_t)r * 512 + cg * 8);
        #pragma unroll
        for (int t = 0; t < 8; ++t) { float f = bf2f(v[t]); s[t] += f; q[t] += f * f; }
    }
    #pragma unroll
    for (int t = 0; t < 8; ++t) red[rg][cg * 8 + t] = s[t];
    __syncthreads();
    if (rg == 0)
        #pragma unroll
        for (int t = 0; t < 8; ++t) {
            int c = cg * 8 + t;
            atomicAdd(&sums[c], red[0][c] + red[1][c] + red[2][c] + red[3][c]);
        }
    __syncthreads();
    #pragma unroll
    for (int t = 0; t < 8; ++t) red[rg][cg * 8 + t] = q[t];
    __syncthreads();
    if (rg == 0)
        #pragma unroll
        for (int t = 0; t < 8; ++t) {
            int c = cg * 8 + t;
            atomicAdd(&sums[512 + c], red[0][c] + red[1][c] + red[2][c] + red[3][c]);
        }
}

// ---------------- fold BN1 into w1 ----------------
__global__ __launch_bounds__(256)
void fold_w1(const float* __restrict__ w1, const float* __restrict__ ab1,
             const float* __restrict__ b1, unsigned short* __restrict__ w1p,
             float* __restrict__ b1p)
{
    int n = blockIdx.x * 4 + (threadIdx.x >> 6);
    int lane = threadIdx.x & 63;
    const float* wrow = w1 + (size_t)n * 512 + lane * 8;
    float p = 0.f;
    ushort8_t o;
    #pragma unroll
    for (int t = 0; t < 8; ++t) {
        float w = wrow[t];
        o[t] = f2bf(w * ab1[lane * 8 + t]);
        p = fmaf(w, ab1[512 + lane * 8 + t], p);
    }
    *(ushort8_t*)(w1p + (size_t)n * 512 + lane * 8) = o;
    #pragma unroll
    for (int d = 1; d < 64; d <<= 1) p += __shfl_xor(p, d);
    if (lane == 0) b1p[n] = b1[n] + p;
}

// ---------------- misc ----------------
__global__ void cvt_f32_bf16(const float* __restrict__ s, unsigned short* __restrict__ d, int n) {
    int i = blockIdx.x * 256 + threadIdx.x;
    if (i < n) d[i] = f2bf(s[i]);
}

__global__ void bn_finalize(const float* __restrict__ sums, const float* __restrict__ gamma,
                            const float* __restrict__ beta, float* __restrict__ ab,
                            int C, float invM)
{
    int c = blockIdx.x * blockDim.x + threadIdx.x;
    if (c >= C) return;
    float mu = sums[c] * invM;
    float var = sums[C + c] * invM - mu * mu;
    float a = gamma[c] * rsqrtf(var + BN_EPS);
    ab[c] = a;
    ab[C + c] = beta[c] - a * mu;
}

__global__ __launch_bounds__(256)
void bn_apply64(float* __restrict__ X, const float* __restrict__ ab, int total)
{
    int idx = blockIdx.x * 256 + threadIdx.x;
    if (idx >= total) return;
    int c = idx & 63;
    X[idx] = fmaf(ab[c], X[idx], ab[64 + c]);
}

extern "C" void kernel_launch(void* const* d_in, const int* in_sizes, int n_in,
                              void* d_out, int out_size, void* d_ws, size_t ws_size,
                              hipStream_t stream)
{
    const float* x         = (const float*)d_in[0];
    const int*   src       = (const int*)d_in[1];
    const int*   dst       = (const int*)d_in[2];
    const float* fc_w      = (const float*)d_in[3];
    const float* attn_l    = (const float*)d_in[4];
    const float* attn_r    = (const float*)d_in[5];
    const float* gat_bias  = (const float*)d_in[6];
    const float* bn1_gamma = (const float*)d_in[7];
    const float* bn1_beta  = (const float*)d_in[8];
    const float* w1        = (const float*)d_in[9];
    const float* b1        = (const float*)d_in[10];
    const float* w2        = (const float*)d_in[11];
    const float* b2        = (const float*)d_in[12];
    const float* bn2_gamma = (const float*)d_in[13];
    const float* bn2_beta  = (const float*)d_in[14];
    float* out = (float*)d_out;

    const int D = 64, HD = 512, HID = 1024;
    const int N = in_sizes[0] / D;      // 50000
    const int E = in_sizes[1];          // 400000
    const int NH = N * 8;
    const int NB = (N + 255) / 256;
    const int Mpad = ((N + 127) / 128) * 128 + 128;  // 50176

    size_t off = 0;
    auto alloc = [&](size_t bytes) -> void* {
        void* p = (char*)d_ws + off;
        off += (bytes + 255) & ~(size_t)255;
        return p;
    };
    // Region A: feat bf16 [N,512] (dead after gat_aggregate), reused as P bf16 [8][N][64]
    void* regionA = alloc((size_t)N * HD * 2);
    unsigned short* feat = (unsigned short*)regionA;
    unsigned short* P    = (unsigned short*)regionA;
    unsigned short* hbf  = (unsigned short*)alloc((size_t)Mpad * HD * 2);
    unsigned short* xbf  = (unsigned short*)alloc((size_t)Mpad * D * 2);
    unsigned short* fcwbf = (unsigned short*)alloc((size_t)HD * D * 2);
    unsigned short* w1p  = (unsigned short*)alloc((size_t)HID * HD * 2);
    unsigned short* w2bf = (unsigned short*)alloc((size_t)D * HID * 2);
    float* b1p   = (float*)alloc(HID * 4);
    float* el    = (float*)alloc((size_t)NH * 4);
    float* er    = (float*)alloc((size_t)NH * 4);
    int* counts  = (int*)alloc((size_t)N * 4);
    int* incl    = (int*)alloc((size_t)N * 4);
    int* row_ptr = (int*)alloc((size_t)(N + 1) * 4);
    int* cursor  = (int*)alloc((size_t)N * 4);
    int* bsum    = (int*)alloc(256 * 4);
    int* esrc    = (int*)alloc((size_t)E * 4);
    float* sums1 = (float*)alloc(2 * 512 * 4);
    float* ab1   = (float*)alloc(2 * 512 * 4);
    float* sums2 = (float*)alloc(2 * 64 * 4);
    float* ab2   = (float*)alloc(2 * 64 * 4);
    (void)ws_size; (void)n_in; (void)out_size;

    // ---- CSR build ----
    hipMemsetAsync(counts, 0, (size_t)N * 4, stream);
    hist_kernel<<<(E + 255) / 256, 256, 0, stream>>>(dst, counts, E);
    scan1<<<NB, 256, 0, stream>>>(counts, incl, bsum, N);
    scan2<<<1, 256, 0, stream>>>(bsum, NB);
    scan3<<<NB, 256, 0, stream>>>(incl, bsum, row_ptr, N);
    hipMemcpyAsync(cursor, row_ptr, (size_t)N * 4, hipMemcpyDeviceToDevice, stream);
    scatter_edges<<<(E + 255) / 256, 256, 0, stream>>>(src, dst, cursor, esrc, E);

    // ---- conversions ----
    cvt_f32_bf16<<<(N * D + 255) / 256, 256, 0, stream>>>(x, xbf, N * D);
    cvt_f32_bf16<<<(HD * D + 255) / 256, 256, 0, stream>>>(fc_w, fcwbf, HD * D);
    cvt_f32_bf16<<<(D * HID + 255) / 256, 256, 0, stream>>>(w2, w2bf, D * HID);

    // ---- GEMM1 (MFMA) + fused el/er ----
    {
        dim3 grid((N + 127) / 128, HD / 128);
        gemm1_mfma<<<grid, 256, 0, stream>>>(xbf, fcwbf, feat, attn_l, attn_r, el, er, N);
    }

    // ---- fused GAT softmax + aggregate -> bf16 h ----
    gat_aggregate<<<(N + 3) / 4, 256, 0, stream>>>(row_ptr, esrc, el, er, feat,
                                                   gat_bias, hbf, N);

    // ---- BN1 stats + fold into w1 ----
    hipMemsetAsync(sums1, 0, 2 * 512 * 4, stream);
    bn_stats512bf<<<256, 256, 0, stream>>>(hbf, N, sums1);
    bn_finalize<<<2, 256, 0, stream>>>(sums1, bn1_gamma, bn1_beta, ab1, HD, 1.f / N);
    fold_w1<<<HID / 4, 256, 0, stream>>>(w1, ab1, b1, w1p, b1p);

    // ---- GEMM2 + partial GEMM3 (feat is dead; P overlays it) ----
    {
        int nwg = ((N + 127) / 128) * 8;  // 3128
        gemm2p<<<nwg, 256, 0, stream>>>(hbf, w1p, w2bf, b1p, P, N);
    }

    // ---- reduce partials + b2 -> out, fused BN2 stats ----
    hipMemsetAsync(sums2, 0, 2 * 64 * 4, stream);
    reduce_bn2<<<256, 256, 0, stream>>>(P, b2, out, N, sums2);
    bn_finalize<<<1, 64, 0, stream>>>(sums2, bn2_gamma, bn2_beta, ab2, D, 1.f / N);
    bn_apply64<<<((N * D) + 255) / 256, 256, 0, stream>>>(out, ab2, N * D);
}

// Round 10
// 309.511 us; speedup vs baseline: 6.4516x; 1.1230x over previous
//
#include <hip/hip_runtime.h>

#define NEG_SLOPE 0.2f
#define BN_EPS 1e-5f

typedef __bf16 bf16x8 __attribute__((ext_vector_type(8)));
typedef float  f32x4  __attribute__((ext_vector_type(4)));
typedef unsigned short ushort8_t __attribute__((ext_vector_type(8)));

__device__ __forceinline__ unsigned short f2bf(float f) {  // RNE f32->bf16
    unsigned int u = __float_as_uint(f);
    unsigned int r = u + 0x7FFFu + ((u >> 16) & 1u);
    return (unsigned short)(r >> 16);
}
__device__ __forceinline__ float bf2f(unsigned short u) {
    return __uint_as_float(((unsigned int)u) << 16);
}
__device__ __forceinline__ void gload16(const void* g, void* l) {
    __builtin_amdgcn_global_load_lds(
        (const __attribute__((address_space(1))) unsigned int*)g,
        (__attribute__((address_space(3))) unsigned int*)l, 16, 0, 0);
}

// ---- proj: al_proj[h][k] = sum_d attn_l[h][d] * fc_w[h*64+d][k]; same for ar ----
__global__ void build_proj(const float* __restrict__ fc_w, const float* __restrict__ attn_l,
                           const float* __restrict__ attn_r, float* __restrict__ proj)
{
    int t = threadIdx.x;            // 512 threads: h*64+k
    int h = t >> 6, k = t & 63;
    float al = 0.f, ar = 0.f;
    for (int d = 0; d < 64; ++d) {
        float w = fc_w[(size_t)(h * 64 + d) * 64 + k];
        al = fmaf(attn_l[h * 64 + d], w, al);
        ar = fmaf(attn_r[h * 64 + d], w, ar);
    }
    proj[t] = al;
    proj[512 + t] = ar;
}

// ---- el/er[n,h] = x[n,:] . proj[h,:] ----
__global__ __launch_bounds__(256)
void elr_kernel(const float* __restrict__ x, const float* __restrict__ proj,
                float* __restrict__ el, float* __restrict__ er, int NH)
{
    int idx = blockIdx.x * 256 + threadIdx.x; // n*8 + h
    if (idx >= NH) return;
    int h = idx & 7, n = idx >> 3;
    const float4* f  = (const float4*)(x + (size_t)n * 64);
    const float4* pl = (const float4*)(proj + h * 64);
    const float4* pr = (const float4*)(proj + 512 + h * 64);
    float sl = 0.f, sr = 0.f;
    #pragma unroll
    for (int i = 0; i < 16; ++i) {
        float4 fv = f[i], lv = pl[i], rv = pr[i];
        sl += fv.x * lv.x + fv.y * lv.y + fv.z * lv.z + fv.w * lv.w;
        sr += fv.x * rv.x + fv.y * rv.y + fv.z * rv.z + fv.w * rv.w;
    }
    el[idx] = sl;
    er[idx] = sr;
}

// ---------------- CSR build ----------------
__global__ void hist_kernel(const int* __restrict__ dst, int* __restrict__ counts, int E) {
    int i = blockIdx.x * 256 + threadIdx.x;
    if (i < E) atomicAdd(&counts[dst[i]], 1);
}
__global__ void scan1(const int* __restrict__ counts, int* __restrict__ incl,
                      int* __restrict__ bsum, int N) {
    __shared__ int sm[256];
    int i = blockIdx.x * 256 + threadIdx.x;
    int v = (i < N) ? counts[i] : 0;
    sm[threadIdx.x] = v;
    __syncthreads();
    #pragma unroll
    for (int d = 1; d < 256; d <<= 1) {
        int t = (threadIdx.x >= d) ? sm[threadIdx.x - d] : 0;
        __syncthreads();
        sm[threadIdx.x] += t;
        __syncthreads();
    }
    if (i < N) incl[i] = sm[threadIdx.x];
    if (threadIdx.x == 255) bsum[blockIdx.x] = sm[255];
}
__global__ void scan2(int* __restrict__ bsum, int nb) {
    __shared__ int sm[256];
    int v = (threadIdx.x < nb) ? bsum[threadIdx.x] : 0;
    sm[threadIdx.x] = v;
    __syncthreads();
    #pragma unroll
    for (int d = 1; d < 256; d <<= 1) {
        int t = (threadIdx.x >= d) ? sm[threadIdx.x - d] : 0;
        __syncthreads();
        sm[threadIdx.x] += t;
        __syncthreads();
    }
    if (threadIdx.x < nb) bsum[threadIdx.x] = sm[threadIdx.x] - v;
}
__global__ void scan3(const int* __restrict__ incl, const int* __restrict__ bsum,
                      int* __restrict__ row_ptr, int N) {
    int i = blockIdx.x * 256 + threadIdx.x;
    if (i < N) row_ptr[i + 1] = incl[i] + bsum[blockIdx.x];
    if (i == 0) row_ptr[0] = 0;
}
__global__ void scatter_edges(const int* __restrict__ src, const int* __restrict__ dst,
                              int* __restrict__ cursor, int* __restrict__ esrc, int E) {
    int e = blockIdx.x * 256 + threadIdx.x;
    if (e < E) {
        int p = atomicAdd(&cursor[dst[e]], 1);
        esrc[p] = src[e];
    }
}

// ---- fused GAT softmax + weighted aggregate of X (64 cols): xagg[n] = sum z*x[src]/denom ----
__global__ __launch_bounds__(256)
void gat_aggregate(const int* __restrict__ row_ptr, const int* __restrict__ esrc,
                   const float* __restrict__ el, const float* __restrict__ er,
                   const unsigned short* __restrict__ xb, unsigned short* __restrict__ xagg,
                   int N)
{
    int node = blockIdx.x * 4 + (threadIdx.x >> 6);
    if (node >= N) return;
    const int lane = threadIdx.x & 63;
    const int h = lane >> 3, j = lane & 7;
    const int beg = row_ptr[node], end = row_ptr[node + 1];
    const float er_n = er[node * 8 + h];

    float m = -INFINITY;
    for (int k = beg + j; k < end; k += 8) {
        int s = esrc[k];
        float v = el[s * 8 + h] + er_n;
        v = (v > 0.f) ? v : NEG_SLOPE * v;
        m = fmaxf(m, v);
    }
    m = fmaxf(m, __shfl_xor(m, 1));
    m = fmaxf(m, __shfl_xor(m, 2));
    m = fmaxf(m, __shfl_xor(m, 4));

    float denom = 0.f;
    float a[8] = {};
    for (int k = beg; k < end; ++k) {
        int s = esrc[k];
        float v = el[s * 8 + h] + er_n;
        v = (v > 0.f) ? v : NEG_SLOPE * v;
        float z = __expf(v - m);
        denom += z;
        ushort8_t fv = *(const ushort8_t*)(xb + (size_t)s * 64 + j * 8);
        #pragma unroll
        for (int t = 0; t < 8; ++t) a[t] = fmaf(z, bf2f(fv[t]), a[t]);
    }
    float inv = (end > beg) ? 1.f / denom : 0.f;
    ushort8_t o;
    #pragma unroll
    for (int t = 0; t < 8; ++t) o[t] = f2bf(a[t] * inv);
    // xagg[node][h*64 + j*8 + t] == xagg[node][lane*8 + t]
    *(ushort8_t*)(xagg + (size_t)node * 512 + lane * 8) = o;
}

// ---- head_transform: hbf[n, h*64+d] = xagg[n,h*64:].fc_w[h*64+d,:] + gat_bias; fused BN1 stats ----
__global__ __launch_bounds__(256)
void head_transform(const unsigned short* __restrict__ Xa,  // xagg [Mpad,512]
                    const unsigned short* __restrict__ Fw,  // fcwbf [512,64]
                    const float* __restrict__ gat_bias,     // [512]
                    unsigned short* __restrict__ H,         // hbf [Mpad,512]
                    float* __restrict__ sums1,              // [1024]
                    int M)
{
    __shared__ alignas(16) char Asm[128 * 64 * 2];
    __shared__ alignas(16) char Bsm[64 * 64 * 2];
    __shared__ float reds[4][64], redq[4][64];
    const int tid = threadIdx.x, lane = tid & 63, wave = tid >> 6;
    const int bm = blockIdx.x * 128;
    const int head = blockIdx.y;
    const int lr = lane >> 3, lk = ((lane & 7) ^ lr) * 8;

    #pragma unroll
    for (int it = 0; it < 4; ++it) {
        int seg = wave * 4 + it;
        gload16(Xa + (size_t)(bm + seg * 8 + lr) * 512 + head * 64 + lk, Asm + seg * 1024);
    }
    #pragma unroll
    for (int it = 0; it < 2; ++it) {
        int seg = wave * 2 + it;
        gload16(Fw + (size_t)(head * 64 + seg * 8 + lr) * 64 + lk, Bsm + seg * 1024);
    }
    __syncthreads();

    f32x4 acc[2][4] = {};
    #pragma unroll
    for (int kk = 0; kk < 2; ++kk) {
        int kg = kk * 4 + (lane >> 4);
        bf16x8 a[2], b[4];
        #pragma unroll
        for (int i = 0; i < 2; ++i) {
            int row = wave * 32 + i * 16 + (lane & 15);
            a[i] = *(const bf16x8*)(Asm + row * 128 + ((kg ^ (row & 7)) << 4));
        }
        #pragma unroll
        for (int j = 0; j < 4; ++j) {
            int row = j * 16 + (lane & 15);
            b[j] = *(const bf16x8*)(Bsm + row * 128 + ((kg ^ (row & 7)) << 4));
        }
        #pragma unroll
        for (int i = 0; i < 2; ++i)
            #pragma unroll
            for (int j = 0; j < 4; ++j)
                acc[i][j] = __builtin_amdgcn_mfma_f32_16x16x32_bf16(a[i], b[j], acc[i][j], 0, 0, 0);
    }

    float s4[4] = {}, q4[4] = {};
    #pragma unroll
    for (int j = 0; j < 4; ++j) {
        int col = j * 16 + (lane & 15);
        float bias = gat_bias[head * 64 + col];
        #pragma unroll
        for (int i = 0; i < 2; ++i)
            #pragma unroll
            for (int r = 0; r < 4; ++r) {
                int gm = bm + wave * 32 + i * 16 + (lane >> 4) * 4 + r;
                if (gm < M) {
                    unsigned short hb = f2bf(acc[i][j][r] + bias);
                    H[(size_t)gm * 512 + head * 64 + col] = hb;
                    float vq = bf2f(hb);
                    s4[j] += vq; q4[j] += vq * vq;
                }
            }
    }
    #pragma unroll
    for (int j = 0; j < 4; ++j) {
        s4[j] += __shfl_xor(s4[j], 16); q4[j] += __shfl_xor(q4[j], 16);
        s4[j] += __shfl_xor(s4[j], 32); q4[j] += __shfl_xor(q4[j], 32);
    }
    if (lane < 16) {
        #pragma unroll
        for (int j = 0; j < 4; ++j) {
            reds[wave][j * 16 + lane] = s4[j];
            redq[wave][j * 16 + lane] = q4[j];
        }
    }
    __syncthreads();
    if (wave == 0 && lane < 16) {
        #pragma unroll
        for (int j = 0; j < 4; ++j) {
            int c = j * 16 + lane;
            atomicAdd(&sums1[head * 64 + c], reds[0][c] + reds[1][c] + reds[2][c] + reds[3][c]);
            atomicAdd(&sums1[512 + head * 64 + c], redq[0][c] + redq[1][c] + redq[2][c] + redq[3][c]);
        }
    }
}

// ---------------- fold BN1 into w1 ----------------
__global__ __launch_bounds__(256)
void fold_w1(const float* __restrict__ w1, const float* __restrict__ ab1,
             const float* __restrict__ b1, unsigned short* __restrict__ w1p,
             float* __restrict__ b1p)
{
    int n = blockIdx.x * 4 + (threadIdx.x >> 6);
    int lane = threadIdx.x & 63;
    const float* wrow = w1 + (size_t)n * 512 + lane * 8;
    float p = 0.f;
    ushort8_t o;
    #pragma unroll
    for (int t = 0; t < 8; ++t) {
        float w = wrow[t];
        o[t] = f2bf(w * ab1[lane * 8 + t]);
        p = fmaf(w, ab1[512 + lane * 8 + t], p);
    }
    *(ushort8_t*)(w1p + (size_t)n * 512 + lane * 8) = o;
    #pragma unroll
    for (int d = 1; d < 64; d <<= 1) p += __shfl_xor(p, d);
    if (lane == 0) b1p[n] = b1[n] + p;
}

// ---------------- GEMM2+partial-GEMM3 ----------------
__global__ __launch_bounds__(256)
void gemm2p(const unsigned short* __restrict__ A,   // hbf [Mpad,512]
            const unsigned short* __restrict__ B,   // w1p [1024,512]
            const unsigned short* __restrict__ W2,  // w2bf [64,1024]
            const float* __restrict__ b1p,          // [1024]
            unsigned short* __restrict__ P,         // [8][M][64] bf16 partials
            int M)
{
    __shared__ alignas(16) char smem[49152];
    char* Abuf0 = smem;
    char* Abuf1 = smem + 16384;
    char* Bbuf  = smem + 32768;
    char* TR   = smem;
    char* Wbuf = smem + 32768;
    char* PK   = smem + 32768;

    const int tid = threadIdx.x, lane = tid & 63, wave = tid >> 6;
    const int wr = wave >> 1, wc = wave & 1;
    const int lr = lane >> 3, lk = ((lane & 7) ^ lr) * 8;

    int bid = blockIdx.x;
    int wgid = (bid & 7) * 391 + (bid >> 3);
    const int bm = (wgid >> 3) * 128;
    const int t  = wgid & 7;
    const int bn = t * 128;

    #pragma unroll
    for (int it = 0; it < 4; ++it) {
        int seg = wave * 4 + it;
        gload16(A + (size_t)(bm + seg * 8 + lr) * 512 + lk, Abuf0 + seg * 1024);
    }

    f32x4 acc[4][4] = {};
    #pragma unroll
    for (int ks = 0; ks < 8; ++ks) {
        const int k0 = ks * 64;
        #pragma unroll
        for (int it = 0; it < 4; ++it) {
            int seg = wave * 4 + it;
            gload16(B + (size_t)(bn + seg * 8 + lr) * 512 + k0 + lk, Bbuf + seg * 1024);
        }
        if (ks < 7) {
            char* An = (ks & 1) ? Abuf0 : Abuf1;
            #pragma unroll
            for (int it = 0; it < 4; ++it) {
                int seg = wave * 4 + it;
                gload16(A + (size_t)(bm + seg * 8 + lr) * 512 + (k0 + 64) + lk, An + seg * 1024);
            }
            asm volatile("s_waitcnt vmcnt(4)" ::: "memory");
        } else {
            asm volatile("s_waitcnt vmcnt(0)" ::: "memory");
        }
        __builtin_amdgcn_s_barrier();
        __builtin_amdgcn_sched_barrier(0);
        const char* Ac = (ks & 1) ? Abuf1 : Abuf0;
        #pragma unroll
        for (int kk = 0; kk < 2; ++kk) {
            int kg = kk * 4 + (lane >> 4);
            bf16x8 a[4], b[4];
            #pragma unroll
            for (int i = 0; i < 4; ++i) {
                int row = wr * 64 + i * 16 + (lane & 15);
                a[i] = *(const bf16x8*)(Ac + row * 128 + ((kg ^ (row & 7)) << 4));
            }
            #pragma unroll
            for (int j = 0; j < 4; ++j) {
                int row = wc * 64 + j * 16 + (lane & 15);
                b[j] = *(const bf16x8*)(Bbuf + row * 128 + ((kg ^ (row & 7)) << 4));
            }
            #pragma unroll
            for (int i = 0; i < 4; ++i)
                #pragma unroll
                for (int j = 0; j < 4; ++j)
                    acc[i][j] = __builtin_amdgcn_mfma_f32_16x16x32_bf16(a[i], b[j], acc[i][j], 0, 0, 0);
        }
        __builtin_amdgcn_sched_barrier(0);
        __builtin_amdgcn_s_barrier();
        __builtin_amdgcn_sched_barrier(0);
    }

    #pragma unroll
    for (int j = 0; j < 4; ++j) {
        int c = wc * 64 + j * 16 + (lane & 15);
        float bs = b1p[bn + c];
        #pragma unroll
        for (int i = 0; i < 4; ++i)
            #pragma unroll
            for (int r = 0; r < 4; ++r) {
                int rw = wr * 64 + i * 16 + (lane >> 4) * 4 + r;
                float v = fmaxf(acc[i][j][r] + bs, 0.f);
                *(unsigned short*)(TR + rw * 256 + (((c >> 3) ^ (rw & 7)) << 4) + (c & 7) * 2) = f2bf(v);
            }
    }
    #pragma unroll
    for (int it = 0; it < 4; ++it) {
        int oc = wave * 16 + it * 4 + (lane >> 4);
        int g = lane & 15;
        gload16(W2 + (size_t)oc * 1024 + bn + ((g ^ (oc & 7))) * 8, Wbuf + (wave * 4 + it) * 1024);
    }
    __syncthreads();

    f32x4 pacc[2][4] = {};
    #pragma unroll
    for (int ks = 0; ks < 4; ++ks) {
        int kg2 = ks * 4 + (lane >> 4);
        #pragma unroll
        for (int i = 0; i < 2; ++i) {
            int arow = wave * 32 + i * 16 + (lane & 15);
            bf16x8 av = *(const bf16x8*)(TR + arow * 256 + ((kg2 ^ (arow & 7)) << 4));
            #pragma unroll
            for (int j = 0; j < 4; ++j) {
                int oc = j * 16 + (lane & 15);
                bf16x8 bv = *(const bf16x8*)(Wbuf + oc * 256 + ((kg2 ^ (oc & 7)) << 4));
                pacc[i][j] = __builtin_amdgcn_mfma_f32_16x16x32_bf16(av, bv, pacc[i][j], 0, 0, 0);
            }
        }
    }
    __syncthreads();

    #pragma unroll
    for (int i = 0; i < 2; ++i)
        #pragma unroll
        for (int j = 0; j < 4; ++j)
            #pragma unroll
            for (int r = 0; r < 4; ++r) {
                int row = wave * 32 + i * 16 + (lane >> 4) * 4 + r;
                int col = j * 16 + (lane & 15);
                *(unsigned short*)(PK + row * 128 + col * 2) = f2bf(pacc[i][j][r]);
            }
    __syncthreads();
    unsigned short* Pt = P + (size_t)t * M * 64;
    #pragma unroll
    for (int it = 0; it < 4; ++it) {
        int u = it * 256 + tid;
        int row = u >> 3, g8 = u & 7;
        int gm = bm + row;
        if (gm < M) {
            uint4 v = *(const uint4*)(PK + row * 128 + g8 * 16);
            *(uint4*)(Pt + (size_t)gm * 64 + g8 * 8) = v;
        }
    }
}

// ---------------- reduce 8 bf16 partials + b2 -> out, fused BN2 stats ----------------
__global__ __launch_bounds__(256)
void reduce_bn2(const unsigned short* __restrict__ P, const float* __restrict__ b2,
                float* __restrict__ out, int M, float* __restrict__ sums2)
{
    __shared__ float ls[256], lq[256];
    int c = threadIdx.x & 63, g = threadIdx.x >> 6;
    const size_t S = (size_t)M * 64;
    float bias = b2[c];
    float s = 0.f, q = 0.f;
    for (int r = blockIdx.x * 4 + g; r < M; r += gridDim.x * 4) {
        size_t idx = (size_t)r * 64 + c;
        float v = bias;
        #pragma unroll
        for (int t = 0; t < 8; ++t) v += bf2f(P[t * S + idx]);
        out[idx] = v;
        s += v; q += v * v;
    }
    ls[threadIdx.x] = s; lq[threadIdx.x] = q;
    __syncthreads();
    if (g == 0) {
        s = ls[c] + ls[64 + c] + ls[128 + c] + ls[192 + c];
        q = lq[c] + lq[64 + c] + lq[128 + c] + lq[192 + c];
        atomicAdd(&sums2[c], s);
        atomicAdd(&sums2[64 + c], q);
    }
}

// ---------------- misc ----------------
__global__ void cvt_f32_bf16(const float* __restrict__ s, unsigned short* __restrict__ d, int n) {
    int i = blockIdx.x * 256 + threadIdx.x;
    if (i < n) d[i] = f2bf(s[i]);
}

__global__ void bn_finalize(const float* __restrict__ sums, const float* __restrict__ gamma,
                            const float* __restrict__ beta, float* __restrict__ ab,
                            int C, float invM)
{
    int c = blockIdx.x * blockDim.x + threadIdx.x;
    if (c >= C) return;
    float mu = sums[c] * invM;
    float var = sums[C + c] * invM - mu * mu;
    float a = gamma[c] * rsqrtf(var + BN_EPS);
    ab[c] = a;
    ab[C + c] = beta[c] - a * mu;
}

__global__ __launch_bounds__(256)
void bn_apply64(float* __restrict__ X, const float* __restrict__ ab, int total)
{
    int idx = blockIdx.x * 256 + threadIdx.x;
    if (idx >= total) return;
    int c = idx & 63;
    X[idx] = fmaf(ab[c], X[idx], ab[64 + c]);
}

extern "C" void kernel_launch(void* const* d_in, const int* in_sizes, int n_in,
                              void* d_out, int out_size, void* d_ws, size_t ws_size,
                              hipStream_t stream)
{
    const float* x         = (const float*)d_in[0];
    const int*   src       = (const int*)d_in[1];
    const int*   dst       = (const int*)d_in[2];
    const float* fc_w      = (const float*)d_in[3];
    const float* attn_l    = (const float*)d_in[4];
    const float* attn_r    = (const float*)d_in[5];
    const float* gat_bias  = (const float*)d_in[6];
    const float* bn1_gamma = (const float*)d_in[7];
    const float* bn1_beta  = (const float*)d_in[8];
    const float* w1        = (const float*)d_in[9];
    const float* b1        = (const float*)d_in[10];
    const float* w2        = (const float*)d_in[11];
    const float* b2        = (const float*)d_in[12];
    const float* bn2_gamma = (const float*)d_in[13];
    const float* bn2_beta  = (const float*)d_in[14];
    float* out = (float*)d_out;

    const int D = 64, HD = 512, HID = 1024;
    const int N = in_sizes[0] / D;      // 50000
    const int E = in_sizes[1];          // 400000
    const int NH = N * 8;
    const int NB = (N + 255) / 256;
    const int Mpad = ((N + 127) / 128) * 128 + 128;  // 50176

    size_t off = 0;
    auto alloc = [&](size_t bytes) -> void* {
        void* p = (char*)d_ws + off;
        off += (bytes + 255) & ~(size_t)255;
        return p;
    };
    // Region A: xagg bf16 [Mpad,512] (dead after head_transform), reused as P bf16 [8][N][64]
    void* regionA = alloc((size_t)Mpad * HD * 2);
    unsigned short* xagg = (unsigned short*)regionA;
    unsigned short* P    = (unsigned short*)regionA;
    unsigned short* hbf  = (unsigned short*)alloc((size_t)Mpad * HD * 2);
    unsigned short* xbf  = (unsigned short*)alloc((size_t)N * D * 2);
    unsigned short* fcwbf = (unsigned short*)alloc((size_t)HD * D * 2);
    unsigned short* w1p  = (unsigned short*)alloc((size_t)HID * HD * 2);
    unsigned short* w2bf = (unsigned short*)alloc((size_t)D * HID * 2);
    float* b1p   = (float*)alloc(HID * 4);
    float* proj  = (float*)alloc(2 * 512 * 4);
    float* el    = (float*)alloc((size_t)NH * 4);
    float* er    = (float*)alloc((size_t)NH * 4);
    int* counts  = (int*)alloc((size_t)N * 4);
    int* incl    = (int*)alloc((size_t)N * 4);
    int* row_ptr = (int*)alloc((size_t)(N + 1) * 4);
    int* cursor  = (int*)alloc((size_t)N * 4);
    int* bsum    = (int*)alloc(256 * 4);
    int* esrc    = (int*)alloc((size_t)E * 4);
    float* sums1 = (float*)alloc(2 * 512 * 4);
    float* ab1   = (float*)alloc(2 * 512 * 4);
    float* sums2 = (float*)alloc(2 * 64 * 4);
    float* ab2   = (float*)alloc(2 * 64 * 4);
    (void)ws_size; (void)n_in; (void)out_size;

    // ---- CSR build ----
    hipMemsetAsync(counts, 0, (size_t)N * 4, stream);
    hist_kernel<<<(E + 255) / 256, 256, 0, stream>>>(dst, counts, E);
    scan1<<<NB, 256, 0, stream>>>(counts, incl, bsum, N);
    scan2<<<1, 256, 0, stream>>>(bsum, NB);
    scan3<<<NB, 256, 0, stream>>>(incl, bsum, row_ptr, N);
    hipMemcpyAsync(cursor, row_ptr, (size_t)N * 4, hipMemcpyDeviceToDevice, stream);
    scatter_edges<<<(E + 255) / 256, 256, 0, stream>>>(src, dst, cursor, esrc, E);

    // ---- conversions + projections ----
    cvt_f32_bf16<<<(N * D + 255) / 256, 256, 0, stream>>>(x, xbf, N * D);
    cvt_f32_bf16<<<(HD * D + 255) / 256, 256, 0, stream>>>(fc_w, fcwbf, HD * D);
    cvt_f32_bf16<<<(D * HID + 255) / 256, 256, 0, stream>>>(w2, w2bf, D * HID);
    build_proj<<<1, 512, 0, stream>>>(fc_w, attn_l, attn_r, proj);
    elr_kernel<<<(NH + 255) / 256, 256, 0, stream>>>(x, proj, el, er, NH);

    // ---- fused GAT softmax + aggregate of x -> xagg bf16 ----
    gat_aggregate<<<(N + 3) / 4, 256, 0, stream>>>(row_ptr, esrc, el, er, xbf, xagg, N);

    // ---- head transform: hbf = blockdiag(xagg @ fc_w^T) + gat_bias, fused BN1 stats ----
    hipMemsetAsync(sums1, 0, 2 * 512 * 4, stream);
    {
        dim3 grid((N + 127) / 128, 8);
        head_transform<<<grid, 256, 0, stream>>>(xagg, fcwbf, gat_bias, hbf, sums1, N);
    }
    bn_finalize<<<2, 256, 0, stream>>>(sums1, bn1_gamma, bn1_beta, ab1, HD, 1.f / N);
    fold_w1<<<HID / 4, 256, 0, stream>>>(w1, ab1, b1, w1p, b1p);

    // ---- GEMM2 + partial GEMM3 (xagg dead; P overlays it) ----
    {
        int nwg = ((N + 127) / 128) * 8;  // 3128
        gemm2p<<<nwg, 256, 0, stream>>>(hbf, w1p, w2bf, b1p, P, N);
    }

    // ---- reduce partials + b2 -> out, fused BN2 stats ----
    hipMemsetAsync(sums2, 0, 2 * 64 * 4, stream);
    reduce_bn2<<<256, 256, 0, stream>>>(P, b2, out, N, sums2);
    bn_finalize<<<1, 64, 0, stream>>>(sums2, bn2_gamma, bn2_beta, ab2, D, 1.f / N);
    bn_apply64<<<((N * D) + 255) / 256, 256, 0, stream>>>(out, ab2, N * D);
}

// Round 11
// 293.000 us; speedup vs baseline: 6.8152x; 1.0564x over previous
//
#include <hip/hip_runtime.h>

#define NEG_SLOPE 0.2f
#define BN_EPS 1e-5f

typedef __bf16 bf16x8 __attribute__((ext_vector_type(8)));
typedef float  f32x4  __attribute__((ext_vector_type(4)));
typedef unsigned short ushort8_t __attribute__((ext_vector_type(8)));

__device__ __forceinline__ unsigned short f2bf(float f) {  // RNE f32->bf16
    unsigned int u = __float_as_uint(f);
    unsigned int r = u + 0x7FFFu + ((u >> 16) & 1u);
    return (unsigned short)(r >> 16);
}
__device__ __forceinline__ float bf2f(unsigned short u) {
    return __uint_as_float(((unsigned int)u) << 16);
}
__device__ __forceinline__ void gload16(const void* g, void* l) {
    __builtin_amdgcn_global_load_lds(
        (const __attribute__((address_space(1))) unsigned int*)g,
        (__attribute__((address_space(3))) unsigned int*)l, 16, 0, 0);
}

// ---------------- prep: multi-role (cvt_x | hist | cvt_fcw | cvt_w2 | build_proj) ----
__global__ __launch_bounds__(256)
void prep(const float* __restrict__ x, const int* __restrict__ dst,
          const float* __restrict__ fc_w, const float* __restrict__ w2,
          const float* __restrict__ attn_l, const float* __restrict__ attn_r,
          unsigned short* __restrict__ xbf, unsigned short* __restrict__ fcwbf,
          unsigned short* __restrict__ w2bf, float* __restrict__ proj,
          int* __restrict__ counts, int totX4, int E,
          int bCvtx, int bHist, int bFcw, int bW2)
{
    const int bid = blockIdx.x, tid = threadIdx.x;
    if (bid < bCvtx) {
        int i4 = bid * 256 + tid;
        if (i4 < totX4) {
            float4 v = *(const float4*)(x + (size_t)i4 * 4);
            ushort4 o = {f2bf(v.x), f2bf(v.y), f2bf(v.z), f2bf(v.w)};
            *(ushort4*)(xbf + (size_t)i4 * 4) = o;
        }
    } else if (bid < bHist) {
        int base = (bid - bCvtx) * 1024 + tid;
        #pragma unroll
        for (int k = 0; k < 4; ++k) {
            int e = base + k * 256;
            if (e < E) atomicAdd(&counts[dst[e]], 1);
        }
    } else if (bid < bFcw) {
        int i4 = (bid - bHist) * 256 + tid;       // 512*64/4 = 8192
        if (i4 < 8192) {
            float4 v = *(const float4*)(fc_w + (size_t)i4 * 4);
            ushort4 o = {f2bf(v.x), f2bf(v.y), f2bf(v.z), f2bf(v.w)};
            *(ushort4*)(fcwbf + (size_t)i4 * 4) = o;
        }
    } else if (bid < bW2) {
        int i4 = (bid - bFcw) * 256 + tid;        // 64*1024/4 = 16384
        if (i4 < 16384) {
            float4 v = *(const float4*)(w2 + (size_t)i4 * 4);
            ushort4 o = {f2bf(v.x), f2bf(v.y), f2bf(v.z), f2bf(v.w)};
            *(ushort4*)(w2bf + (size_t)i4 * 4) = o;
        }
    } else {
        // build_proj: proj[h*64+k] = sum_d attn_l[h][d]*fc_w[h*64+d][k]
        for (int t2 = tid; t2 < 512; t2 += 256) {
            int h = t2 >> 6, k = t2 & 63;
            float al = 0.f, ar = 0.f;
            for (int d = 0; d < 64; ++d) {
                float w = fc_w[(size_t)(h * 64 + d) * 64 + k];
                al = fmaf(attn_l[h * 64 + d], w, al);
                ar = fmaf(attn_r[h * 64 + d], w, ar);
            }
            proj[t2] = al;
            proj[512 + t2] = ar;
        }
    }
}

// ---------------- scan1 + elr multi-role ----------------
__global__ __launch_bounds__(256)
void scan1_elr(const int* __restrict__ counts, int* __restrict__ incl,
               int* __restrict__ bsum, int N, int NB,
               const float* __restrict__ x, const float* __restrict__ proj,
               float* __restrict__ el, float* __restrict__ er, int NH)
{
    __shared__ int sm[256];
    if ((int)blockIdx.x < NB) {
        int i = blockIdx.x * 256 + threadIdx.x;
        int v = (i < N) ? counts[i] : 0;
        sm[threadIdx.x] = v;
        __syncthreads();
        #pragma unroll
        for (int d = 1; d < 256; d <<= 1) {
            int t = (threadIdx.x >= d) ? sm[threadIdx.x - d] : 0;
            __syncthreads();
            sm[threadIdx.x] += t;
            __syncthreads();
        }
        if (i < N) incl[i] = sm[threadIdx.x];
        if (threadIdx.x == 255) bsum[blockIdx.x] = sm[255];
    } else {
        int idx = (blockIdx.x - NB) * 256 + threadIdx.x; // n*8 + h
        if (idx >= NH) return;
        int h = idx & 7, n = idx >> 3;
        const float4* f  = (const float4*)(x + (size_t)n * 64);
        const float4* pl = (const float4*)(proj + h * 64);
        const float4* pr = (const float4*)(proj + 512 + h * 64);
        float sl = 0.f, sr = 0.f;
        #pragma unroll
        for (int i = 0; i < 16; ++i) {
            float4 fv = f[i], lv = pl[i], rv = pr[i];
            sl += fv.x * lv.x + fv.y * lv.y + fv.z * lv.z + fv.w * lv.w;
            sr += fv.x * rv.x + fv.y * rv.y + fv.z * rv.z + fv.w * rv.w;
        }
        el[idx] = sl;
        er[idx] = sr;
    }
}

__global__ void scan2(int* __restrict__ bsum, int nb) {
    __shared__ int sm[256];
    int v = (threadIdx.x < nb) ? bsum[threadIdx.x] : 0;
    sm[threadIdx.x] = v;
    __syncthreads();
    #pragma unroll
    for (int d = 1; d < 256; d <<= 1) {
        int t = (threadIdx.x >= d) ? sm[threadIdx.x - d] : 0;
        __syncthreads();
        sm[threadIdx.x] += t;
        __syncthreads();
    }
    if (threadIdx.x < nb) bsum[threadIdx.x] = sm[threadIdx.x] - v;
}
__global__ void scan3(const int* __restrict__ incl, const int* __restrict__ bsum,
                      int* __restrict__ row_ptr, int* __restrict__ cursor, int N) {
    int i = blockIdx.x * 256 + threadIdx.x;
    if (i < N) {
        int v = incl[i] + bsum[blockIdx.x];
        row_ptr[i + 1] = v;
        cursor[i + 1] = v;
    }
    if (i == 0) { row_ptr[0] = 0; cursor[0] = 0; }
}
__global__ void scatter_edges(const int* __restrict__ src, const int* __restrict__ dst,
                              int* __restrict__ cursor, int* __restrict__ esrc, int E) {
    int e = blockIdx.x * 256 + threadIdx.x;
    if (e < E) {
        int p = atomicAdd(&cursor[dst[e]], 1);
        esrc[p] = src[e];
    }
}

// ---- fused GAT softmax + weighted aggregate of X: single pass (softmax shift-invariant) ----
__global__ __launch_bounds__(256)
void gat_aggregate(const int* __restrict__ row_ptr, const int* __restrict__ esrc,
                   const float* __restrict__ el, const float* __restrict__ er,
                   const unsigned short* __restrict__ xb, unsigned short* __restrict__ xagg,
                   int N)
{
    int node = blockIdx.x * 4 + (threadIdx.x >> 6);
    if (node >= N) return;
    const int lane = threadIdx.x & 63;
    const int h = lane >> 3, j = lane & 7;
    const int beg = row_ptr[node], end = row_ptr[node + 1];
    const float er_n = er[node * 8 + h];

    float denom = 0.f;
    float a[8] = {};
    for (int k = beg; k < end; ++k) {
        int s = esrc[k];
        float v = el[s * 8 + h] + er_n;
        v = (v > 0.f) ? v : NEG_SLOPE * v;
        float z = __expf(v);
        denom += z;
        ushort8_t fv = *(const ushort8_t*)(xb + (size_t)s * 64 + j * 8);
        #pragma unroll
        for (int t = 0; t < 8; ++t) a[t] = fmaf(z, bf2f(fv[t]), a[t]);
    }
    float inv = (end > beg) ? 1.f / denom : 0.f;
    ushort8_t o;
    #pragma unroll
    for (int t = 0; t < 8; ++t) o[t] = f2bf(a[t] * inv);
    *(ushort8_t*)(xagg + (size_t)node * 512 + lane * 8) = o;
}

// ---- head_transform: hbf[n, h*64+d] = xagg_h . fcw + gat_bias; fused BN1 stats ----
__global__ __launch_bounds__(256)
void head_transform(const unsigned short* __restrict__ Xa,
                    const unsigned short* __restrict__ Fw,
                    const float* __restrict__ gat_bias,
                    unsigned short* __restrict__ H,
                    float* __restrict__ sums1, int M)
{
    __shared__ alignas(16) char Asm[128 * 64 * 2];
    __shared__ alignas(16) char Bsm[64 * 64 * 2];
    __shared__ float reds[4][64], redq[4][64];
    const int tid = threadIdx.x, lane = tid & 63, wave = tid >> 6;
    const int bm = blockIdx.x * 128;
    const int head = blockIdx.y;
    const int lr = lane >> 3, lk = ((lane & 7) ^ lr) * 8;

    #pragma unroll
    for (int it = 0; it < 4; ++it) {
        int seg = wave * 4 + it;
        gload16(Xa + (size_t)(bm + seg * 8 + lr) * 512 + head * 64 + lk, Asm + seg * 1024);
    }
    #pragma unroll
    for (int it = 0; it < 2; ++it) {
        int seg = wave * 2 + it;
        gload16(Fw + (size_t)(head * 64 + seg * 8 + lr) * 64 + lk, Bsm + seg * 1024);
    }
    __syncthreads();

    f32x4 acc[2][4] = {};
    #pragma unroll
    for (int kk = 0; kk < 2; ++kk) {
        int kg = kk * 4 + (lane >> 4);
        bf16x8 a[2], b[4];
        #pragma unroll
        for (int i = 0; i < 2; ++i) {
            int row = wave * 32 + i * 16 + (lane & 15);
            a[i] = *(const bf16x8*)(Asm + row * 128 + ((kg ^ (row & 7)) << 4));
        }
        #pragma unroll
        for (int j = 0; j < 4; ++j) {
            int row = j * 16 + (lane & 15);
            b[j] = *(const bf16x8*)(Bsm + row * 128 + ((kg ^ (row & 7)) << 4));
        }
        #pragma unroll
        for (int i = 0; i < 2; ++i)
            #pragma unroll
            for (int j = 0; j < 4; ++j)
                acc[i][j] = __builtin_amdgcn_mfma_f32_16x16x32_bf16(a[i], b[j], acc[i][j], 0, 0, 0);
    }

    float s4[4] = {}, q4[4] = {};
    #pragma unroll
    for (int j = 0; j < 4; ++j) {
        int col = j * 16 + (lane & 15);
        float bias = gat_bias[head * 64 + col];
        #pragma unroll
        for (int i = 0; i < 2; ++i)
            #pragma unroll
            for (int r = 0; r < 4; ++r) {
                int gm = bm + wave * 32 + i * 16 + (lane >> 4) * 4 + r;
                if (gm < M) {
                    unsigned short hb = f2bf(acc[i][j][r] + bias);
                    H[(size_t)gm * 512 + head * 64 + col] = hb;
                    float vq = bf2f(hb);
                    s4[j] += vq; q4[j] += vq * vq;
                }
            }
    }
    #pragma unroll
    for (int j = 0; j < 4; ++j) {
        s4[j] += __shfl_xor(s4[j], 16); q4[j] += __shfl_xor(q4[j], 16);
        s4[j] += __shfl_xor(s4[j], 32); q4[j] += __shfl_xor(q4[j], 32);
    }
    if (lane < 16) {
        #pragma unroll
        for (int j = 0; j < 4; ++j) {
            reds[wave][j * 16 + lane] = s4[j];
            redq[wave][j * 16 + lane] = q4[j];
        }
    }
    __syncthreads();
    if (wave == 0 && lane < 16) {
        #pragma unroll
        for (int j = 0; j < 4; ++j) {
            int c = j * 16 + lane;
            atomicAdd(&sums1[head * 64 + c], reds[0][c] + reds[1][c] + reds[2][c] + reds[3][c]);
            atomicAdd(&sums1[512 + head * 64 + c], redq[0][c] + redq[1][c] + redq[2][c] + redq[3][c]);
        }
    }
}

// ---------------- fold BN1 into w1 (BN finalize inlined) ----------------
__global__ __launch_bounds__(256)
void fold_w1(const float* __restrict__ w1, const float* __restrict__ sums1,
             const float* __restrict__ gamma, const float* __restrict__ beta,
             const float* __restrict__ b1, unsigned short* __restrict__ w1p,
             float* __restrict__ b1p, float invM)
{
    __shared__ float sa[512], sb[512];
    for (int c = threadIdx.x; c < 512; c += 256) {
        float mu = sums1[c] * invM;
        float var = sums1[512 + c] * invM - mu * mu;
        float a = gamma[c] * rsqrtf(var + BN_EPS);
        sa[c] = a;
        sb[c] = beta[c] - a * mu;
    }
    __syncthreads();
    int n = blockIdx.x * 4 + (threadIdx.x >> 6);
    int lane = threadIdx.x & 63;
    const float* wrow = w1 + (size_t)n * 512 + lane * 8;
    float p = 0.f;
    ushort8_t o;
    #pragma unroll
    for (int t = 0; t < 8; ++t) {
        float w = wrow[t];
        o[t] = f2bf(w * sa[lane * 8 + t]);
        p = fmaf(w, sb[lane * 8 + t], p);
    }
    *(ushort8_t*)(w1p + (size_t)n * 512 + lane * 8) = o;
    #pragma unroll
    for (int d = 1; d < 64; d <<= 1) p += __shfl_xor(p, d);
    if (lane == 0) b1p[n] = b1[n] + p;
}

// ---------------- GEMM2+partial-GEMM3 (unchanged) ----------------
__global__ __launch_bounds__(256)
void gemm2p(const unsigned short* __restrict__ A,
            const unsigned short* __restrict__ B,
            const unsigned short* __restrict__ W2,
            const float* __restrict__ b1p,
            unsigned short* __restrict__ P, int M)
{
    __shared__ alignas(16) char smem[49152];
    char* Abuf0 = smem;
    char* Abuf1 = smem + 16384;
    char* Bbuf  = smem + 32768;
    char* TR   = smem;
    char* Wbuf = smem + 32768;
    char* PK   = smem + 32768;

    const int tid = threadIdx.x, lane = tid & 63, wave = tid >> 6;
    const int wr = wave >> 1, wc = wave & 1;
    const int lr = lane >> 3, lk = ((lane & 7) ^ lr) * 8;

    int bid = blockIdx.x;
    int wgid = (bid & 7) * 391 + (bid >> 3);
    const int bm = (wgid >> 3) * 128;
    const int t  = wgid & 7;
    const int bn = t * 128;

    #pragma unroll
    for (int it = 0; it < 4; ++it) {
        int seg = wave * 4 + it;
        gload16(A + (size_t)(bm + seg * 8 + lr) * 512 + lk, Abuf0 + seg * 1024);
    }

    f32x4 acc[4][4] = {};
    #pragma unroll
    for (int ks = 0; ks < 8; ++ks) {
        const int k0 = ks * 64;
        #pragma unroll
        for (int it = 0; it < 4; ++it) {
            int seg = wave * 4 + it;
            gload16(B + (size_t)(bn + seg * 8 + lr) * 512 + k0 + lk, Bbuf + seg * 1024);
        }
        if (ks < 7) {
            char* An = (ks & 1) ? Abuf0 : Abuf1;
            #pragma unroll
            for (int it = 0; it < 4; ++it) {
                int seg = wave * 4 + it;
                gload16(A + (size_t)(bm + seg * 8 + lr) * 512 + (k0 + 64) + lk, An + seg * 1024);
            }
            asm volatile("s_waitcnt vmcnt(4)" ::: "memory");
        } else {
            asm volatile("s_waitcnt vmcnt(0)" ::: "memory");
        }
        __builtin_amdgcn_s_barrier();
        __builtin_amdgcn_sched_barrier(0);
        const char* Ac = (ks & 1) ? Abuf1 : Abuf0;
        #pragma unroll
        for (int kk = 0; kk < 2; ++kk) {
            int kg = kk * 4 + (lane >> 4);
            bf16x8 a[4], b[4];
            #pragma unroll
            for (int i = 0; i < 4; ++i) {
                int row = wr * 64 + i * 16 + (lane & 15);
                a[i] = *(const bf16x8*)(Ac + row * 128 + ((kg ^ (row & 7)) << 4));
            }
            #pragma unroll
            for (int j = 0; j < 4; ++j) {
                int row = wc * 64 + j * 16 + (lane & 15);
                b[j] = *(const bf16x8*)(Bbuf + row * 128 + ((kg ^ (row & 7)) << 4));
            }
            #pragma unroll
            for (int i = 0; i < 4; ++i)
                #pragma unroll
                for (int j = 0; j < 4; ++j)
                    acc[i][j] = __builtin_amdgcn_mfma_f32_16x16x32_bf16(a[i], b[j], acc[i][j], 0, 0, 0);
        }
        __builtin_amdgcn_sched_barrier(0);
        __builtin_amdgcn_s_barrier();
        __builtin_amdgcn_sched_barrier(0);
    }

    #pragma unroll
    for (int j = 0; j < 4; ++j) {
        int c = wc * 64 + j * 16 + (lane & 15);
        float bs = b1p[bn + c];
        #pragma unroll
        for (int i = 0; i < 4; ++i)
            #pragma unroll
            for (int r = 0; r < 4; ++r) {
                int rw = wr * 64 + i * 16 + (lane >> 4) * 4 + r;
                float v = fmaxf(acc[i][j][r] + bs, 0.f);
                *(unsigned short*)(TR + rw * 256 + (((c >> 3) ^ (rw & 7)) << 4) + (c & 7) * 2) = f2bf(v);
            }
    }
    #pragma unroll
    for (int it = 0; it < 4; ++it) {
        int oc = wave * 16 + it * 4 + (lane >> 4);
        int g = lane & 15;
        gload16(W2 + (size_t)oc * 1024 + bn + ((g ^ (oc & 7))) * 8, Wbuf + (wave * 4 + it) * 1024);
    }
    __syncthreads();

    f32x4 pacc[2][4] = {};
    #pragma unroll
    for (int ks = 0; ks < 4; ++ks) {
        int kg2 = ks * 4 + (lane >> 4);
        #pragma unroll
        for (int i = 0; i < 2; ++i) {
            int arow = wave * 32 + i * 16 + (lane & 15);
            bf16x8 av = *(const bf16x8*)(TR + arow * 256 + ((kg2 ^ (arow & 7)) << 4));
            #pragma unroll
            for (int j = 0; j < 4; ++j) {
                int oc = j * 16 + (lane & 15);
                bf16x8 bv = *(const bf16x8*)(Wbuf + oc * 256 + ((kg2 ^ (oc & 7)) << 4));
                pacc[i][j] = __builtin_amdgcn_mfma_f32_16x16x32_bf16(av, bv, pacc[i][j], 0, 0, 0);
            }
        }
    }
    __syncthreads();

    #pragma unroll
    for (int i = 0; i < 2; ++i)
        #pragma unroll
        for (int j = 0; j < 4; ++j)
            #pragma unroll
            for (int r = 0; r < 4; ++r) {
                int row = wave * 32 + i * 16 + (lane >> 4) * 4 + r;
                int col = j * 16 + (lane & 15);
                *(unsigned short*)(PK + row * 128 + col * 2) = f2bf(pacc[i][j][r]);
            }
    __syncthreads();
    unsigned short* Pt = P + (size_t)t * M * 64;
    #pragma unroll
    for (int it = 0; it < 4; ++it) {
        int u = it * 256 + tid;
        int row = u >> 3, g8 = u & 7;
        int gm = bm + row;
        if (gm < M) {
            uint4 v = *(const uint4*)(PK + row * 128 + g8 * 16);
            *(uint4*)(Pt + (size_t)gm * 64 + g8 * 8) = v;
        }
    }
}

// ---------------- reduce 8 bf16 partials + b2 -> out, fused BN2 stats ----------------
__global__ __launch_bounds__(256)
void reduce_bn2(const unsigned short* __restrict__ P, const float* __restrict__ b2,
                float* __restrict__ out, int M, float* __restrict__ sums2)
{
    __shared__ float ls[256], lq[256];
    int c = threadIdx.x & 63, g = threadIdx.x >> 6;
    const size_t S = (size_t)M * 64;
    float bias = b2[c];
    float s = 0.f, q = 0.f;
    for (int r = blockIdx.x * 4 + g; r < M; r += gridDim.x * 4) {
        size_t idx = (size_t)r * 64 + c;
        float v = bias;
        #pragma unroll
        for (int t = 0; t < 8; ++t) v += bf2f(P[t * S + idx]);
        out[idx] = v;
        s += v; q += v * v;
    }
    ls[threadIdx.x] = s; lq[threadIdx.x] = q;
    __syncthreads();
    if (g == 0) {
        s = ls[c] + ls[64 + c] + ls[128 + c] + ls[192 + c];
        q = lq[c] + lq[64 + c] + lq[128 + c] + lq[192 + c];
        atomicAdd(&sums2[c], s);
        atomicAdd(&sums2[64 + c], q);
    }
}

// ---------------- BN2 apply (finalize inlined per-thread) ----------------
__global__ __launch_bounds__(256)
void bn_apply64(float* __restrict__ X, const float* __restrict__ sums2,
                const float* __restrict__ gamma, const float* __restrict__ beta,
                int M, float invM)
{
    int c = threadIdx.x & 63, g = threadIdx.x >> 6;
    float mu = sums2[c] * invM;
    float var = sums2[64 + c] * invM - mu * mu;
    float a = gamma[c] * rsqrtf(var + BN_EPS);
    float b = beta[c] - a * mu;
    for (int r = blockIdx.x * 4 + g; r < M; r += gridDim.x * 4) {
        size_t i = (size_t)r * 64 + c;
        X[i] = fmaf(a, X[i], b);
    }
}

extern "C" void kernel_launch(void* const* d_in, const int* in_sizes, int n_in,
                              void* d_out, int out_size, void* d_ws, size_t ws_size,
                              hipStream_t stream)
{
    const float* x         = (const float*)d_in[0];
    const int*   src       = (const int*)d_in[1];
    const int*   dst       = (const int*)d_in[2];
    const float* fc_w      = (const float*)d_in[3];
    const float* attn_l    = (const float*)d_in[4];
    const float* attn_r    = (const float*)d_in[5];
    const float* gat_bias  = (const float*)d_in[6];
    const float* bn1_gamma = (const float*)d_in[7];
    const float* bn1_beta  = (const float*)d_in[8];
    const float* w1        = (const float*)d_in[9];
    const float* b1        = (const float*)d_in[10];
    const float* w2        = (const float*)d_in[11];
    const float* b2        = (const float*)d_in[12];
    const float* bn2_gamma = (const float*)d_in[13];
    const float* bn2_beta  = (const float*)d_in[14];
    float* out = (float*)d_out;

    const int D = 64, HD = 512, HID = 1024;
    const int N = in_sizes[0] / D;      // 50000
    const int E = in_sizes[1];          // 400000
    const int NH = N * 8;
    const int NB = (N + 255) / 256;     // 196
    const int Mpad = ((N + 127) / 128) * 128 + 128;  // 50176

    size_t off = 0;
    auto alloc = [&](size_t bytes) -> void* {
        void* p = (char*)d_ws + off;
        off += (bytes + 255) & ~(size_t)255;
        return p;
    };
    // Region A: xagg bf16 [Mpad,512] (dead after head_transform), reused as P bf16 [8][N][64]
    void* regionA = alloc((size_t)Mpad * HD * 2);
    unsigned short* xagg = (unsigned short*)regionA;
    unsigned short* P    = (unsigned short*)regionA;
    unsigned short* hbf  = (unsigned short*)alloc((size_t)Mpad * HD * 2);
    unsigned short* xbf  = (unsigned short*)alloc((size_t)N * D * 2);
    unsigned short* fcwbf = (unsigned short*)alloc((size_t)HD * D * 2);
    unsigned short* w1p  = (unsigned short*)alloc((size_t)HID * HD * 2);
    unsigned short* w2bf = (unsigned short*)alloc((size_t)D * HID * 2);
    float* b1p   = (float*)alloc(HID * 4);
    float* proj  = (float*)alloc(2 * 512 * 4);
    float* el    = (float*)alloc((size_t)NH * 4);
    float* er    = (float*)alloc((size_t)NH * 4);
    // contiguous zero region: counts | sums1 | sums2
    char* zbase  = (char*)d_ws + off;
    int* counts  = (int*)alloc((size_t)N * 4);
    float* sums1 = (float*)alloc(2 * 512 * 4);
    float* sums2 = (float*)alloc(2 * 64 * 4);
    size_t zbytes = ((char*)d_ws + off) - zbase;
    int* incl    = (int*)alloc((size_t)N * 4);
    int* row_ptr = (int*)alloc((size_t)(N + 1) * 4);
    int* cursor  = (int*)alloc((size_t)(N + 1) * 4);
    int* bsum    = (int*)alloc(256 * 4);
    int* esrc    = (int*)alloc((size_t)E * 4);
    (void)ws_size; (void)n_in; (void)out_size;

    // 1) zero counts+sums
    hipMemsetAsync(zbase, 0, zbytes, stream);

    // 2) prep: cvt_x | hist | cvt_fcw | cvt_w2 | build_proj
    {
        int totX4 = (N * D) / 4;                     // 800000
        int bCvtx = (totX4 + 255) / 256;             // 3125
        int bHist = bCvtx + (E + 1023) / 1024;       // +391
        int bFcw  = bHist + 32;
        int bW2   = bFcw + 64;
        int grid  = bW2 + 1;
        prep<<<grid, 256, 0, stream>>>(x, dst, fc_w, w2, attn_l, attn_r,
                                       xbf, fcwbf, w2bf, proj, counts,
                                       totX4, E, bCvtx, bHist, bFcw, bW2);
    }

    // 3) scan1 + elr
    scan1_elr<<<NB + (NH + 255) / 256, 256, 0, stream>>>(counts, incl, bsum, N, NB,
                                                         x, proj, el, er, NH);
    // 4-5) scan finish (+cursor init)
    scan2<<<1, 256, 0, stream>>>(bsum, NB);
    scan3<<<NB, 256, 0, stream>>>(incl, bsum, row_ptr, cursor, N);
    // 6) CSR scatter
    scatter_edges<<<(E + 255) / 256, 256, 0, stream>>>(src, dst, cursor, esrc, E);

    // 7) fused GAT softmax + aggregate of x -> xagg bf16
    gat_aggregate<<<(N + 3) / 4, 256, 0, stream>>>(row_ptr, esrc, el, er, xbf, xagg, N);

    // 8) head transform + BN1 stats
    {
        dim3 grid((N + 127) / 128, 8);
        head_transform<<<grid, 256, 0, stream>>>(xagg, fcwbf, gat_bias, hbf, sums1, N);
    }
    // 9) fold BN1 into w1 (finalize inlined)
    fold_w1<<<HID / 4, 256, 0, stream>>>(w1, sums1, bn1_gamma, bn1_beta, b1, w1p, b1p, 1.f / N);

    // 10) GEMM2 + partial GEMM3 (xagg dead; P overlays it)
    {
        int nwg = ((N + 127) / 128) * 8;  // 3128
        gemm2p<<<nwg, 256, 0, stream>>>(hbf, w1p, w2bf, b1p, P, N);
    }

    // 11) reduce partials + b2 -> out, BN2 stats
    reduce_bn2<<<1024, 256, 0, stream>>>(P, b2, out, N, sums2);
    // 12) BN2 apply (finalize inlined)
    bn_apply64<<<1024, 256, 0, stream>>>(out, sums2, bn2_gamma, bn2_beta, N, 1.f / N);
}